// Round 9
// baseline (72504.559 us; speedup 1.0000x reference)
//
#include <hip/hip_runtime.h>
#include <hip/hip_bf16.h>
#include <cstddef>

using bf16 = __hip_bfloat16;

// ---------------- diagnostic constant fill (f32 output now) ----------------
__global__ __launch_bounds__(256) void fill_const(float* out, int n, float v) {
    int i = blockIdx.x * 256 + threadIdx.x;
    if (i < n) out[i] = v;
}

// ---------------- adj: x @ w_adj + b_adj : (Bc,1798)@(1798,2048) -> f32 ----------------
__global__ __launch_bounds__(256) void adj_naive(
    const float* __restrict__ x, const float* __restrict__ w,
    const float* __restrict__ bias, float* __restrict__ out)
{
    int id = blockIdx.x * 256 + threadIdx.x;   // Bc*2048 threads
    int j = id & 2047;
    int b = id >> 11;
    float acc = bias[j];
    const float* xr = x + (size_t)b * 1798;
    for (int k = 0; k < 1798; ++k)
        acc += xr[k] * w[(size_t)k * 2048 + j];
    out[id] = acc;
}

// ---------------- c0: conv1d (1->64, K=15, s=2, p=7) + BN + ReLU ----------------
__global__ __launch_bounds__(256) void c0_naive(
    const float* __restrict__ in,   // [Bc,2048]
    const float* __restrict__ w,    // [64,15]
    const float* __restrict__ cb, const float* __restrict__ g,
    const float* __restrict__ bb, const float* __restrict__ m,
    const float* __restrict__ vv, float* __restrict__ out) // [Bc,64,1024]
{
    int idx = blockIdx.x * 256 + threadIdx.x;  // Bc*64*1024
    int l = idx & 1023;
    int co = (idx >> 10) & 63;
    int b = idx >> 16;
    float acc = 0.f;
    int p0 = 2 * l - 7;
    for (int k = 0; k < 15; ++k) {
        int pos = p0 + k;
        if (pos >= 0 && pos < 2048)
            acc += in[(size_t)b * 2048 + pos] * w[co * 15 + k];
    }
    float s = g[co] * rsqrtf(vv[co] + 1e-5f);
    out[idx] = fmaxf((acc + cb[co] - m[co]) * s + bb[co], 0.f);
}

// ---------------- generic conv1d stride-1 + BN + ReLU (naive, correlation) ----------------
template <int CIN, int K, int PAD, int COUT>
__global__ __launch_bounds__(256) void conv_naive(
    const float* __restrict__ in,   // [Bc,CIN,1024]
    const float* __restrict__ w,    // [COUT,CIN,K]
    const float* __restrict__ cb, const float* __restrict__ g,
    const float* __restrict__ bb, const float* __restrict__ m,
    const float* __restrict__ vv, float* __restrict__ out)  // [Bc,COUT,1024]
{
    int idx = blockIdx.x * 256 + threadIdx.x;   // Bc*COUT*1024
    int l = idx & 1023;
    int bc = idx >> 10;
    int co = bc % COUT;
    int b = bc / COUT;
    float acc = 0.f;
    const float* wr = w + co * (CIN * K);
    const float* ib = in + (size_t)b * CIN * 1024;
    for (int ci = 0; ci < CIN; ++ci) {
        const float* ir = ib + ci * 1024;
        const float* wk = wr + ci * K;
#pragma unroll
        for (int k = 0; k < K; ++k) {
            int pos = l + k - PAD;
            if (pos >= 0 && pos < 1024)
                acc += ir[pos] * wk[k];
        }
    }
    float s = g[co] * rsqrtf(vv[co] + 1e-5f);
    out[idx] = fmaxf((acc + cb[co] - m[co]) * s + bb[co], 0.f);
}

// ---------------- pe: conv1d (256->192, K=8, s=8) over concat[c0,c3] -> (Bc,128,192) ----------------
__global__ __launch_bounds__(256) void pe_naive(
    const float* __restrict__ c0b,  // [Bc,64,1024]
    const float* __restrict__ c3b,  // [Bc,192,1024]
    const float* __restrict__ w,    // [192,256,8]
    const float* __restrict__ bias,
    float* __restrict__ out)        // [Bc,128,192]
{
    int id = blockIdx.x * 256 + threadIdx.x;   // Bc*128*192
    int co = id % 192;
    int n = (id / 192) % 128;
    int b = id / (192 * 128);
    float acc = bias[co];
    const float* wr = w + co * 2048;
    for (int ci = 0; ci < 256; ++ci) {
        const float* src = (ci < 64) ? (c0b + ((size_t)b * 64 + ci) * 1024)
                                     : (c3b + ((size_t)b * 192 + (ci - 64)) * 1024);
        const float* wk = wr + ci * 8;
#pragma unroll
        for (int k = 0; k < 8; ++k)
            acc += src[n * 8 + k] * wk[k];
    }
    out[((size_t)b * 128 + n) * 192 + co] = acc;
}

// ---------------- simplified transformer (naive) ----------------
__global__ __launch_bounds__(256) void transformer_naive(
    const float* __restrict__ src,   // [Bc,128,192]
    const float* __restrict__ wqk,   // [192,384]
    const float* __restrict__ bqk,   // [384]
    float* __restrict__ qkb,         // [Bc,32,384] scratch
    float* __restrict__ attnb,       // [Bc,4,32,32] scratch
    float* __restrict__ dst)         // [Bc,128,192]
{
    __shared__ float feat[6144];
    const int b = blockIdx.x, tid = threadIdx.x;
    float* qk = qkb + (size_t)b * 12288;
    float* attn = attnb + (size_t)b * 4096;
    for (int i = 0; i < 4; ++i) {
        const float* srow = src + ((size_t)b * 128 + i * 32) * 192;
        for (int idx = tid; idx < 6144; idx += 256)
            feat[idx] = (i == 0) ? srow[idx] : feat[idx] + srow[idx];
        __syncthreads();
        for (int idx = tid; idx < 12288; idx += 256) {
            int n = idx / 384, j = idx % 384;
            float acc = bqk[j];
            for (int c = 0; c < 192; ++c)
                acc += feat[n * 192 + c] * wqk[c * 384 + j];
            qk[idx] = acc;
        }
        __syncthreads();
        for (int idx = tid; idx < 4096; idx += 256) {
            int h = idx >> 10, r = idx & 1023, qi = r >> 5, kj = r & 31;
            float acc = 0.f;
            for (int c = 0; c < 48; ++c)
                acc += qk[qi * 384 + h * 48 + c] * qk[kj * 384 + 192 + h * 48 + c];
            attn[idx] = acc * 0.14433756729740643f;  // 48^-0.5
        }
        __syncthreads();
        if (tid < 128) {
            int h = tid >> 5, qi = tid & 31;
            float* row = attn + h * 1024 + qi * 32;
            float mx = row[0];
            for (int k2 = 1; k2 < 32; ++k2) mx = fmaxf(mx, row[k2]);
            float sum = 0.f;
            for (int k2 = 0; k2 < 32; ++k2) { row[k2] = expf(row[k2] - mx); sum += row[k2]; }
            float inv = 1.f / sum;
            for (int k2 = 0; k2 < 32; ++k2) row[k2] *= inv;
        }
        __syncthreads();
        float regout[24];
        int cnt = 0;
        for (int idx = tid; idx < 6144; idx += 256, ++cnt) {
            int n = idx / 192, cc = idx % 192, h = cc / 48;
            float acc = 0.f;
            for (int j = 0; j < 32; ++j)
                acc += attn[h * 1024 + n * 32 + j] * feat[j * 192 + cc];
            regout[cnt] = acc;
        }
        __syncthreads();
        float* drow = dst + ((size_t)b * 128 + i * 32) * 192;
        cnt = 0;
        for (int idx = tid; idx < 6144; idx += 256, ++cnt) {
            feat[idx] = regout[cnt];
            drow[idx] = regout[cnt];
        }
        __syncthreads();
    }
}

// ---------------- MLP part 1: h1 = gelu(x @ w_fc1 + b_fc1) ----------------
__global__ __launch_bounds__(256) void mlp1_naive(
    const float* __restrict__ x,    // [Bc*128,192]
    const float* __restrict__ w1, const float* __restrict__ b1,  // [192,264]
    float* __restrict__ h1)         // [Bc*128,264]
{
    int id = blockIdx.x * 256 + threadIdx.x;
    int j = id % 264;
    int t = id / 264;
    float acc = b1[j];
    const float* xr = x + (size_t)t * 192;
    for (int c = 0; c < 192; ++c)
        acc += xr[c] * w1[c * 264 + j];
    h1[id] = 0.5f * acc * (1.f + erff(acc * 0.70710678118654752f));
}

// ---------------- MLP part 2 + residual + LayerNorm (block per token) ----------------
__global__ __launch_bounds__(192) void mlp2ln_naive(
    const float* __restrict__ h1,   // [Bc*128,264]
    const float* __restrict__ a,    // [Bc*128,192] transformer2 out
    const float* __restrict__ w2, const float* __restrict__ b2,  // [264,192]
    const float* __restrict__ lng, const float* __restrict__ lnb,
    float* __restrict__ out)        // [Bc*128,192]
{
    __shared__ float row[192];
    __shared__ float mu, rsd;
    const int t = blockIdx.x;
    const int c = threadIdx.x;
    float acc = b2[c];
    const float* hr = h1 + (size_t)t * 264;
    for (int k = 0; k < 264; ++k)
        acc += hr[k] * w2[k * 192 + c];
    row[c] = acc + a[(size_t)t * 192 + c];
    __syncthreads();
    if (c == 0) {
        float s = 0.f;
        for (int q = 0; q < 192; ++q) s += row[q];
        float mm = s / 192.f;
        float v = 0.f;
        for (int q = 0; q < 192; ++q) { float d = row[q] - mm; v += d * d; }
        mu = mm;
        rsd = rsqrtf(v / 192.f + 1e-5f);
    }
    __syncthreads();
    out[(size_t)t * 192 + c] = (row[c] - mu) * rsd * lng[c] + lnb[c];
}

// ---------------- mean over tokens + classifier head -> FLOAT32 output ----------------
__global__ __launch_bounds__(192) void head_naive(
    const float* __restrict__ ln,    // [Bc,128,192]
    const float* __restrict__ wcls,  // [192,3]
    const float* __restrict__ bcls,
    float* __restrict__ out)         // [Bc,3]  F32 OUTPUT
{
    __shared__ float mean[192];
    const int b = blockIdx.x;
    const int c = threadIdx.x;
    float s = 0.f;
    for (int n = 0; n < 128; ++n) s += ln[((size_t)b * 128 + n) * 192 + c];
    mean[c] = s / 128.f;
    __syncthreads();
    if (c < 3) {
        float acc = bcls[c];
        for (int k = 0; k < 192; ++k) acc += mean[k] * wcls[k * 3 + c];
        out[b * 3 + c] = acc;
    }
}

static const int SZ_DICT[41] = {
    920576, 3682304, 2048, 960, 64, 64, 64, 64, 64,
    73728, 128, 128, 128, 128, 128,
    81920, 128, 128, 128, 128, 128,
    73728, 192, 192, 192, 192, 192,
    393216, 192,
    73728, 384, 73728, 384,
    50688, 264, 50688, 192,
    192, 192, 576, 3};

extern "C" void kernel_launch(void* const* d_in, const int* in_sizes, int n_in,
                              void* d_out, int out_size, void* d_ws, size_t ws_size,
                              hipStream_t stream) {
    if (n_in != 41) {
        fill_const<<<(out_size + 255) / 256, 256, 0, stream>>>((float*)d_out, out_size, 200.f);
        return;
    }
    bool mA = true;
    for (int i = 0; i < 41; ++i) mA = mA && (in_sizes[i] == SZ_DICT[i]);
    if (!mA) {
        fill_const<<<(out_size + 255) / 256, 256, 0, stream>>>((float*)d_out, out_size, 100.f);
        return;
    }
    const float* P[41];
    for (int i = 0; i < 41; ++i) P[i] = (const float*)d_in[i];

    // per-sample fp32 scratch, no aliasing
    const size_t PER = 2699264;
    int Bc = 128;
    while (Bc > 1 && (size_t)Bc * PER + 16384 > ws_size) Bc >>= 1;
    if ((size_t)Bc * PER + 16384 > ws_size) {
        fill_const<<<(out_size + 255) / 256, 256, 0, stream>>>((float*)d_out, out_size, 50.f);
        return;
    }

    char* ws = (char*)d_ws;
    size_t off = 256;
    auto alloc = [&](size_t bytes) {
        char* p = ws + off;
        off = (off + bytes + 255) & ~(size_t)255;
        return p;
    };
    float* adjb  = (float*)alloc((size_t)Bc * 2048 * 4);
    float* c0b   = (float*)alloc((size_t)Bc * 64 * 1024 * 4);
    float* c1b   = (float*)alloc((size_t)Bc * 128 * 1024 * 4);
    float* c2b   = (float*)alloc((size_t)Bc * 128 * 1024 * 4);
    float* c3b   = (float*)alloc((size_t)Bc * 192 * 1024 * 4);
    float* peb   = (float*)alloc((size_t)Bc * 128 * 192 * 4);
    float* t1b   = (float*)alloc((size_t)Bc * 128 * 192 * 4);
    float* t2b   = (float*)alloc((size_t)Bc * 128 * 192 * 4);
    float* lnbuf = (float*)alloc((size_t)Bc * 128 * 192 * 4);
    float* qkb   = (float*)alloc((size_t)Bc * 32 * 384 * 4);
    float* attnb = (float*)alloc((size_t)Bc * 4 * 32 * 32 * 4);
    float* h1b   = (float*)alloc((size_t)Bc * 128 * 264 * 4);

    const int nchunk = 512 / Bc;
    for (int c = 0; c < nchunk; ++c) {
        const size_t b0 = (size_t)c * Bc;
        adj_naive<<<Bc * 8, 256, 0, stream>>>(P[0] + b0 * 1798, P[1], P[2], adjb);
        c0_naive<<<Bc * 256, 256, 0, stream>>>(adjb, P[3], P[4],
                                               P[5], P[6], P[7], P[8], c0b);
        conv_naive<64, 9, 4, 128><<<Bc * 512, 256, 0, stream>>>(c0b, P[9], P[10],
                                               P[11], P[12], P[13], P[14], c1b);
        conv_naive<128, 5, 2, 128><<<Bc * 512, 256, 0, stream>>>(c1b, P[15], P[16],
                                               P[17], P[18], P[19], P[20], c2b);
        conv_naive<128, 3, 1, 192><<<Bc * 768, 256, 0, stream>>>(c2b, P[21], P[22],
                                               P[23], P[24], P[25], P[26], c3b);
        pe_naive<<<Bc * 96, 256, 0, stream>>>(c0b, c3b, P[27], P[28], peb);
        transformer_naive<<<Bc, 256, 0, stream>>>(peb, P[29], P[30], qkb, attnb, t1b);
        transformer_naive<<<Bc, 256, 0, stream>>>(t1b, P[31], P[32], qkb, attnb, t2b);
        mlp1_naive<<<Bc * 132, 256, 0, stream>>>(peb, P[33], P[34], h1b);
        mlp2ln_naive<<<Bc * 128, 192, 0, stream>>>(h1b, t2b, P[35], P[36],
                                                   P[37], P[38], lnbuf);
        head_naive<<<Bc, 192, 0, stream>>>(lnbuf, P[39], P[40], (float*)d_out + b0 * 3);
    }
}

// Round 10
// 9573.473 us; speedup vs baseline: 7.5735x; 7.5735x over previous
//
#include <hip/hip_runtime.h>
#include <hip/hip_bf16.h>
#include <hip/hip_fp16.h>
#include <cstddef>

static __device__ __forceinline__ float h2f(__half v) { return __half2float(v); }

__global__ __launch_bounds__(256) void fill_const(float* out, int n, float v) {
    int i = blockIdx.x * 256 + threadIdx.x;
    if (i < n) out[i] = v;
}

// ---------------- adj: x @ w_adj + b_adj : (Bc,1798)@(1798,2048) -> fp16 ----------------
__global__ __launch_bounds__(256) void adj_kernel(
    const float* __restrict__ x, const float* __restrict__ w,
    const float* __restrict__ bias, __half* __restrict__ out)
{
    __shared__ float xs[4 * 1798];
    const int tid = threadIdx.x;
    const int jt = blockIdx.x & 7;        // 8 tiles of 256 over j
    const int b0 = (blockIdx.x >> 3) * 4; // tiles of 4 over b
    for (int idx = tid; idx < 4 * 1798; idx += 256)
        xs[idx] = x[(size_t)b0 * 1798 + idx];
    __syncthreads();
    const int j = jt * 256 + tid;
    float a0 = 0, a1 = 0, a2 = 0, a3 = 0;
    for (int k = 0; k < 1798; ++k) {
        float wv = w[(size_t)k * 2048 + j];
        a0 = fmaf(xs[k], wv, a0);
        a1 = fmaf(xs[1798 + k], wv, a1);
        a2 = fmaf(xs[2 * 1798 + k], wv, a2);
        a3 = fmaf(xs[3 * 1798 + k], wv, a3);
    }
    float bv = bias[j];
    out[(size_t)(b0 + 0) * 2048 + j] = __float2half(a0 + bv);
    out[(size_t)(b0 + 1) * 2048 + j] = __float2half(a1 + bv);
    out[(size_t)(b0 + 2) * 2048 + j] = __float2half(a2 + bv);
    out[(size_t)(b0 + 3) * 2048 + j] = __float2half(a3 + bv);
}

// ---------------- c0: conv1d (1->64, K=15, s=2, p=7) + BN + ReLU, fp16 io ----------------
__global__ __launch_bounds__(256) void c0_kernel(
    const __half* __restrict__ in,   // [Bc,2048]
    const float* __restrict__ w,     // [64,15]
    const float* __restrict__ cb, const float* __restrict__ g,
    const float* __restrict__ bb, const float* __restrict__ m,
    const float* __restrict__ vv, __half* __restrict__ out)  // [Bc,64,1024]
{
    int idx = blockIdx.x * 256 + threadIdx.x;
    int l = idx & 1023;
    int co = (idx >> 10) & 63;
    int b = idx >> 16;
    float acc = 0.f;
    int p0 = 2 * l - 7;
#pragma unroll
    for (int k = 0; k < 15; ++k) {
        int pos = p0 + k;
        if (pos >= 0 && pos < 2048)
            acc = fmaf(h2f(in[(size_t)b * 2048 + pos]), w[co * 15 + k], acc);
    }
    float s = g[co] * rsqrtf(vv[co] + 1e-5f);
    out[idx] = __float2half(fmaxf((acc + cb[co] - m[co]) * s + bb[co], 0.f));
}

// ---------------- conv1d stride-1 + BN + ReLU: LDS tile + register-blocked 8-wide ----------------
template <int CIN, int K, int PAD, int COUT>
__global__ __launch_bounds__(256) void conv_tiled(
    const __half* __restrict__ in,   // [Bc,CIN,1024] fp16
    const float* __restrict__ w,     // [COUT,CIN,K]
    const float* __restrict__ cb, const float* __restrict__ g,
    const float* __restrict__ bb, const float* __restrict__ m,
    const float* __restrict__ vv, __half* __restrict__ out)  // [Bc,COUT,1024]
{
    constexpr int L = 1024, LT = 64;
    constexpr int TW = (LT + K - 1 + 3) & ~3;         // row stride, mult of 4
    constexpr int NSPAN = (8 + K - 1 + 3) / 4;        // float4 reads per thread per ci
    __shared__ __align__(16) float tile[CIN * TW + 16];
    __shared__ float sc[COUT], sh[COUT];
    const int tid = threadIdx.x;
    const int b = blockIdx.x >> 4;
    const int l0b = (blockIdx.x & 15) * LT;
    for (int c = tid; c < COUT; c += 256) {
        float s = g[c] * rsqrtf(vv[c] + 1e-5f);
        sc[c] = s;
        sh[c] = (cb[c] - m[c]) * s + bb[c];
    }
    for (int idx = tid; idx < CIN * TW; idx += 256) {
        int ci = idx / TW, p = idx - ci * TW;
        int pos = l0b + p - PAD;
        float v = 0.f;
        if (p < LT + K - 1 && pos >= 0 && pos < L)
            v = h2f(in[((size_t)b * CIN + ci) * L + pos]);
        tile[idx] = v;
    }
    __syncthreads();
    const int l0 = (tid & 7) * 8;     // 8 l-groups of 8 outputs
    const int co0 = tid >> 3;         // 32 co slots per pass
    for (int co = co0; co < COUT; co += 32) {
        float acc[8];
#pragma unroll
        for (int j = 0; j < 8; ++j) acc[j] = 0.f;
        const float* wr = w + co * (CIN * K);
        for (int ci = 0; ci < CIN; ++ci) {
            float wk[K];
#pragma unroll
            for (int k = 0; k < K; ++k) wk[k] = wr[ci * K + k];
            const float4* tp = (const float4*)&tile[ci * TW + l0];
            float win[NSPAN * 4];
#pragma unroll
            for (int q = 0; q < NSPAN; ++q) {
                float4 v = tp[q];
                win[4 * q] = v.x; win[4 * q + 1] = v.y;
                win[4 * q + 2] = v.z; win[4 * q + 3] = v.w;
            }
#pragma unroll
            for (int k = 0; k < K; ++k)
#pragma unroll
                for (int j = 0; j < 8; ++j)
                    acc[j] = fmaf(win[k + j], wk[k], acc[j]);
        }
        float s = sc[co], hh = sh[co];
        size_t ob = ((size_t)b * COUT + co) * L + l0b + l0;
#pragma unroll
        for (int j = 0; j < 4; ++j) {
            __half2 h2 = __halves2half2(
                __float2half(fmaxf(fmaf(acc[2 * j], s, hh), 0.f)),
                __float2half(fmaxf(fmaf(acc[2 * j + 1], s, hh), 0.f)));
            *(__half2*)&out[ob + 2 * j] = h2;
        }
    }
}

// ---------------- pe: conv (256->192, K=8, s=8) over concat[c0,c3] -> (Bc,128,192) f32 ----------------
__global__ __launch_bounds__(256) void pe_kernel(
    const __half* __restrict__ c0b,  // [Bc,64,1024]
    const __half* __restrict__ c3b,  // [Bc,192,1024]
    const float* __restrict__ w,     // [192,2048]
    const float* __restrict__ bias,
    float* __restrict__ out)         // [Bc,128,192]
{
    __shared__ __align__(16) float in_t[8 * 2048];  // 64 KB
    const int tid = threadIdx.x;
    const int b = blockIdx.x >> 4;
    const int n0 = (blockIdx.x & 15) * 8;
    for (int idx = tid; idx < 16384; idx += 256) {
        int n = idx >> 11, r = idx & 2047;
        int ci = r >> 3, k = r & 7;
        int l = (n0 + n) * 8 + k;
        in_t[idx] = (ci < 64) ? h2f(c0b[(size_t)(b * 64 + ci) * 1024 + l])
                              : h2f(c3b[(size_t)(b * 192 + ci - 64) * 1024 + l]);
    }
    __syncthreads();
    if (tid < 192) {
        const int co = tid;
        float acc[8];
        float bv = bias[co];
#pragma unroll
        for (int n = 0; n < 8; ++n) acc[n] = bv;
        const float* wr = w + co * 2048;
        for (int r = 0; r < 2048; r += 8) {
            float wv[8];
#pragma unroll
            for (int q = 0; q < 8; ++q) wv[q] = wr[r + q];
#pragma unroll
            for (int n = 0; n < 8; ++n) {
                const float4* ip = (const float4*)&in_t[n * 2048 + r];
                float4 a0 = ip[0], a1 = ip[1];
                acc[n] = fmaf(a0.x, wv[0], acc[n]); acc[n] = fmaf(a0.y, wv[1], acc[n]);
                acc[n] = fmaf(a0.z, wv[2], acc[n]); acc[n] = fmaf(a0.w, wv[3], acc[n]);
                acc[n] = fmaf(a1.x, wv[4], acc[n]); acc[n] = fmaf(a1.y, wv[5], acc[n]);
                acc[n] = fmaf(a1.z, wv[6], acc[n]); acc[n] = fmaf(a1.w, wv[7], acc[n]);
            }
        }
#pragma unroll
        for (int n = 0; n < 8; ++n)
            out[((size_t)b * 128 + n0 + n) * 192 + co] = acc[n];
    }
}

// ---------------- simplified transformer: LDS-resident, one block/sample ----------------
__global__ __launch_bounds__(256) void transformer_kernel(
    const float* __restrict__ src,   // [Bc,128,192]
    const float* __restrict__ wqk,   // [192,384]
    const float* __restrict__ bqk,   // [384]
    float* __restrict__ dst)         // [Bc,128,192]
{
    __shared__ float feat[32 * 192];
    __shared__ __half qks[32 * 386];
    __shared__ __half attnS[4 * 32 * 33];
    const int b = blockIdx.x;
    const int tid = threadIdx.x;
    float regout[24];
    for (int i = 0; i < 4; ++i) {
        const float* srow = src + ((size_t)b * 128 + i * 32) * 192;
        if (i == 0) { for (int idx = tid; idx < 6144; idx += 256) feat[idx] = srow[idx]; }
        else        { for (int idx = tid; idx < 6144; idx += 256) feat[idx] += srow[idx]; }
        __syncthreads();
        for (int idx = tid; idx < 384 * 8; idx += 256) {
            int j = idx % 384;
            int n0 = (idx / 384) * 4;
            float a0 = 0, a1 = 0, a2 = 0, a3 = 0;
            for (int c = 0; c < 192; ++c) {
                float wv = wqk[c * 384 + j];
                a0 = fmaf(feat[(n0 + 0) * 192 + c], wv, a0);
                a1 = fmaf(feat[(n0 + 1) * 192 + c], wv, a1);
                a2 = fmaf(feat[(n0 + 2) * 192 + c], wv, a2);
                a3 = fmaf(feat[(n0 + 3) * 192 + c], wv, a3);
            }
            float bv = bqk[j];
            qks[(n0 + 0) * 386 + j] = __float2half(a0 + bv);
            qks[(n0 + 1) * 386 + j] = __float2half(a1 + bv);
            qks[(n0 + 2) * 386 + j] = __float2half(a2 + bv);
            qks[(n0 + 3) * 386 + j] = __float2half(a3 + bv);
        }
        __syncthreads();
        if (tid < 128) {
            int h = tid >> 5, qi = tid & 31;
            float qreg[48];
#pragma unroll
            for (int c = 0; c < 48; ++c) qreg[c] = h2f(qks[qi * 386 + h * 48 + c]);
            float logits[32];
            float mx = -1e30f;
            for (int kj = 0; kj < 32; ++kj) {
                float acc = 0;
#pragma unroll
                for (int c = 0; c < 48; ++c)
                    acc = fmaf(qreg[c], h2f(qks[kj * 386 + 192 + h * 48 + c]), acc);
                acc *= 0.14433756729740643f;  // 48^-0.5
                logits[kj] = acc;
                mx = fmaxf(mx, acc);
            }
            float sum = 0;
#pragma unroll
            for (int kj = 0; kj < 32; ++kj) { float e = __expf(logits[kj] - mx); logits[kj] = e; sum += e; }
            float inv = 1.f / sum;
#pragma unroll
            for (int kj = 0; kj < 32; ++kj)
                attnS[(h * 32 + qi) * 33 + kj] = __float2half(logits[kj] * inv);
        }
        __syncthreads();
        int cnt = 0;
        for (int idx = tid; idx < 6144; idx += 256, ++cnt) {
            int n = idx / 192, cc = idx - n * 192, h = cc / 48;
            float acc = 0;
            for (int j = 0; j < 32; ++j)
                acc = fmaf(h2f(attnS[(h * 32 + n) * 33 + j]), feat[j * 192 + cc], acc);
            regout[cnt] = acc;
        }
        __syncthreads();
        float* drow = dst + ((size_t)b * 128 + i * 32) * 192;
        cnt = 0;
        for (int idx = tid; idx < 6144; idx += 256, ++cnt) {
            feat[idx] = regout[cnt];
            drow[idx] = regout[cnt];
        }
        __syncthreads();
    }
}

// ---------------- MLP (exact gelu) + residual + LayerNorm, 32 tokens/block ----------------
__global__ __launch_bounds__(256) void mlp_ln_kernel(
    const float* __restrict__ x,   // pe out [Bc,128,192]
    const float* __restrict__ a,   // transformer2 out
    const float* __restrict__ w1, const float* __restrict__ b1,   // [192,264]
    const float* __restrict__ w2, const float* __restrict__ b2,   // [264,192]
    const float* __restrict__ lng, const float* __restrict__ lnb,
    float* __restrict__ out)
{
    __shared__ float xr[32 * 192];
    __shared__ float t[32 * 264];
    __shared__ float mu[32], rsd[32];
    const int tid = threadIdx.x;
    const int b = blockIdx.x >> 2;
    const int row0 = (blockIdx.x & 3) * 32;
    const size_t base = ((size_t)b * 128 + row0) * 192;
    for (int idx = tid; idx < 6144; idx += 256) xr[idx] = x[base + idx];
    __syncthreads();
    for (int idx = tid; idx < 32 * 264; idx += 256) {
        int n = idx / 264, j = idx - n * 264;
        float acc = b1[j];
        for (int c = 0; c < 192; ++c)
            acc = fmaf(xr[n * 192 + c], w1[c * 264 + j], acc);
        t[idx] = 0.5f * acc * (1.f + erff(acc * 0.70710678118654752f));
    }
    __syncthreads();
    for (int idx = tid; idx < 6144; idx += 256) {
        int n = idx / 192, c = idx - n * 192;
        float acc = b2[c];
        for (int k = 0; k < 264; ++k)
            acc = fmaf(t[n * 264 + k], w2[k * 192 + c], acc);
        xr[idx] = acc + a[base + idx];   // xr re-read only after barrier
    }
    __syncthreads();
    if (tid < 32) {
        float s = 0;
        for (int c = 0; c < 192; ++c) s += xr[tid * 192 + c];
        float mm = s * (1.f / 192.f);
        float v = 0;
        for (int c = 0; c < 192; ++c) { float d = xr[tid * 192 + c] - mm; v = fmaf(d, d, v); }
        mu[tid] = mm;
        rsd[tid] = rsqrtf(v * (1.f / 192.f) + 1e-5f);
    }
    __syncthreads();
    for (int idx = tid; idx < 6144; idx += 256) {
        int n = idx / 192, c = idx - n * 192;
        out[base + idx] = (xr[idx] - mu[n]) * rsd[n] * lng[c] + lnb[c];
    }
}

// ---------------- mean over tokens + classifier head -> f32 ----------------
__global__ __launch_bounds__(192) void head_kernel(
    const float* __restrict__ ln, const float* __restrict__ wcls,
    const float* __restrict__ bcls, float* __restrict__ out)
{
    __shared__ float mean[192];
    const int b = blockIdx.x;
    const int c = threadIdx.x;
    float s = 0.f;
    for (int n = 0; n < 128; ++n) s += ln[((size_t)b * 128 + n) * 192 + c];
    mean[c] = s * (1.f / 128.f);
    __syncthreads();
    if (c < 3) {
        float acc = bcls[c];
        for (int k = 0; k < 192; ++k) acc = fmaf(mean[k], wcls[k * 3 + c], acc);
        out[b * 3 + c] = acc;
    }
}

static const int SZ_DICT[41] = {
    920576, 3682304, 2048, 960, 64, 64, 64, 64, 64,
    73728, 128, 128, 128, 128, 128,
    81920, 128, 128, 128, 128, 128,
    73728, 192, 192, 192, 192, 192,
    393216, 192,
    73728, 384, 73728, 384,
    50688, 264, 50688, 192,
    192, 192, 576, 3};

extern "C" void kernel_launch(void* const* d_in, const int* in_sizes, int n_in,
                              void* d_out, int out_size, void* d_ws, size_t ws_size,
                              hipStream_t stream) {
    if (n_in != 41) {
        fill_const<<<(out_size + 255) / 256, 256, 0, stream>>>((float*)d_out, out_size, 200.f);
        return;
    }
    bool mA = true;
    for (int i = 0; i < 41; ++i) mA = mA && (in_sizes[i] == SZ_DICT[i]);
    if (!mA) {
        fill_const<<<(out_size + 255) / 256, 256, 0, stream>>>((float*)d_out, out_size, 100.f);
        return;
    }
    const float* P[41];
    for (int i = 0; i < 41; ++i) P[i] = (const float*)d_in[i];

    // ---- per-sample scratch with lifetime aliasing ----
    // c0b 64*1024*2 = 131072 | u1 192*1024*2 = 393216 | u2 128*1024*2 = 262144
    // peb 128*192*4 = 98304  -> PER = 884736
    const size_t PER = 884736;
    int Bc = 256;   // round-1 evidence: ws < 287 MB, so start at 256 (221 MB)
    while (Bc > 4 && (size_t)Bc * PER + 4096 > ws_size) Bc >>= 1;
    if ((size_t)Bc * PER + 4096 > ws_size) {
        fill_const<<<(out_size + 255) / 256, 256, 0, stream>>>((float*)d_out, out_size, 50.f);
        return;
    }

    char* ws = (char*)d_ws;
    __half* c0b = (__half*)ws;
    char*   u1  = ws + (size_t)Bc * 131072;
    char*   u2  = u1 + (size_t)Bc * 393216;
    float*  peb = (float*)(u2 + (size_t)Bc * 262144);

    __half* adjb = (__half*)u1;   // dead before c1 writes u1
    __half* c1b  = (__half*)u1;
    __half* c2b  = (__half*)u2;
    __half* c3b  = (__half*)u1;
    float*  t1b  = (float*)u2;    // after pe, c2b dead
    float*  t2b  = (float*)u1;    // after pe, c3b dead
    float*  lnbuf= (float*)u2;    // after transformer2, t1b dead

    const int nchunk = 512 / Bc;
    for (int c = 0; c < nchunk; ++c) {
        const size_t b0 = (size_t)c * Bc;
        adj_kernel<<<Bc * 2, 256, 0, stream>>>(P[0] + b0 * 1798, P[1], P[2], adjb);
        c0_kernel<<<Bc * 256, 256, 0, stream>>>(adjb, P[3], P[4],
                                                P[5], P[6], P[7], P[8], c0b);
        conv_tiled<64, 9, 4, 128><<<Bc * 16, 256, 0, stream>>>(c0b, P[9], P[10],
                                                P[11], P[12], P[13], P[14], c1b);
        conv_tiled<128, 5, 2, 128><<<Bc * 16, 256, 0, stream>>>(c1b, P[15], P[16],
                                                P[17], P[18], P[19], P[20], c2b);
        conv_tiled<128, 3, 1, 192><<<Bc * 16, 256, 0, stream>>>(c2b, P[21], P[22],
                                                P[23], P[24], P[25], P[26], c3b);
        pe_kernel<<<Bc * 16, 256, 0, stream>>>(c0b, c3b, P[27], P[28], peb);
        transformer_kernel<<<Bc, 256, 0, stream>>>(peb, P[29], P[30], t1b);
        transformer_kernel<<<Bc, 256, 0, stream>>>(t1b, P[31], P[32], t2b);
        mlp_ln_kernel<<<Bc * 4, 256, 0, stream>>>(peb, t2b, P[33], P[34], P[35], P[36],
                                                  P[37], P[38], lnbuf);
        head_kernel<<<Bc, 192, 0, stream>>>(lnbuf, P[39], P[40], (float*)d_out + b0 * 3);
    }
}

// Round 11
// 5785.685 us; speedup vs baseline: 12.5317x; 1.6547x over previous
//
#include <hip/hip_runtime.h>
#include <hip/hip_bf16.h>
#include <hip/hip_fp16.h>
#include <cstddef>

typedef _Float16 half8 __attribute__((ext_vector_type(8)));
typedef float floatx4 __attribute__((ext_vector_type(4)));

static __device__ __forceinline__ float h2f(__half v) { return __half2float(v); }

__global__ __launch_bounds__(256) void fill_const(float* out, int n, float v) {
    int i = blockIdx.x * 256 + threadIdx.x;
    if (i < n) out[i] = v;
}

// ---------------- pack conv weights into MFMA A-fragment lane order, f32 -> f16 ----------------
// frag f = (k*NCC + cc)*NT + t ; element (lane, j):
//   co = t*16 + (lane&15) ; ci = cc*32 + (lane>>4)*8 + j
__global__ __launch_bounds__(256) void pack_w(
    const float* __restrict__ w, _Float16* __restrict__ out,
    int CIN, int K, int COUT)
{
    int NT = COUT >> 4, NCC = CIN >> 5;
    int total = K * CIN * COUT;
    int idx = blockIdx.x * 256 + threadIdx.x;
    if (idx >= total) return;
    int j = idx & 7, lane = (idx >> 3) & 63, f = idx >> 9;
    int t = f % NT, cc = (f / NT) % NCC, k = f / (NT * NCC);
    int co = t * 16 + (lane & 15);
    int ci = cc * 32 + (lane >> 4) * 8 + j;
    out[idx] = (_Float16)w[(co * CIN + ci) * K + k];
}

// ---------------- adj: x @ w_adj + b_adj -> fp16 ----------------
__global__ __launch_bounds__(256) void adj_kernel(
    const float* __restrict__ x, const float* __restrict__ w,
    const float* __restrict__ bias, _Float16* __restrict__ out)
{
    __shared__ float xs[4 * 1798];
    const int tid = threadIdx.x;
    const int jt = blockIdx.x & 7;
    const int b0 = (blockIdx.x >> 3) * 4;
    for (int idx = tid; idx < 4 * 1798; idx += 256)
        xs[idx] = x[(size_t)b0 * 1798 + idx];
    __syncthreads();
    const int j = jt * 256 + tid;
    float a0 = 0, a1 = 0, a2 = 0, a3 = 0;
    for (int k = 0; k < 1798; ++k) {
        float wv = w[(size_t)k * 2048 + j];
        a0 = fmaf(xs[k], wv, a0);
        a1 = fmaf(xs[1798 + k], wv, a1);
        a2 = fmaf(xs[2 * 1798 + k], wv, a2);
        a3 = fmaf(xs[3 * 1798 + k], wv, a3);
    }
    float bv = bias[j];
    out[(size_t)(b0 + 0) * 2048 + j] = (_Float16)(a0 + bv);
    out[(size_t)(b0 + 1) * 2048 + j] = (_Float16)(a1 + bv);
    out[(size_t)(b0 + 2) * 2048 + j] = (_Float16)(a2 + bv);
    out[(size_t)(b0 + 3) * 2048 + j] = (_Float16)(a3 + bv);
}

// ---------------- c0: conv (1->64, K15, s2, p7) + BN + ReLU ----------------
__global__ __launch_bounds__(256) void c0_kernel(
    const _Float16* __restrict__ in, const float* __restrict__ w,
    const float* __restrict__ cb, const float* __restrict__ g,
    const float* __restrict__ bb, const float* __restrict__ m,
    const float* __restrict__ vv, _Float16* __restrict__ out)
{
    int idx = blockIdx.x * 256 + threadIdx.x;
    int l = idx & 1023;
    int co = (idx >> 10) & 63;
    int b = idx >> 16;
    float acc = 0.f;
    int p0 = 2 * l - 7;
#pragma unroll
    for (int k = 0; k < 15; ++k) {
        int pos = p0 + k;
        if (pos >= 0 && pos < 2048)
            acc = fmaf((float)in[(size_t)b * 2048 + pos], w[co * 15 + k], acc);
    }
    float s = g[co] * rsqrtf(vv[co] + 1e-5f);
    out[idx] = (_Float16)fmaxf((acc + cb[co] - m[co]) * s + bb[co], 0.f);
}

// ---------------- conv1d stride-1 + BN + ReLU via MFMA 16x16x32 f16 ----------------
// Out[co][l] = sum_{k,ci} W[co][ci][k] * In[ci][l+k-PAD]
// A = packed weights (m=co, kk=ci), B = LDS tile [l][ci] (kk=ci, n=l).
template <int CIN, int K, int PAD, int COUT>
__global__ __launch_bounds__(256) void conv_mfma(
    const _Float16* __restrict__ in,   // [Bc,CIN,1024]
    const _Float16* __restrict__ wp,   // packed frags
    const float* __restrict__ cb, const float* __restrict__ g,
    const float* __restrict__ bb, const float* __restrict__ m,
    const float* __restrict__ vv, _Float16* __restrict__ out)  // [Bc,COUT,1024]
{
    constexpr int STRIDE = (CIN == 64) ? 72 : 152;   // halves; 16B-aligned rows, 2-way banks max
    constexpr int SPAN = 64 + K - 1;
    constexpr int NCC = CIN / 32, NT = COUT / 16;
    __shared__ _Float16 tin[SPAN * STRIDE];
    __shared__ float sc[COUT], sh[COUT];
    const int tid = threadIdx.x;
    const int b = blockIdx.x >> 4;
    const int l0b = (blockIdx.x & 15) * 64;
    for (int c = tid; c < COUT; c += 256) {
        float s = g[c] * rsqrtf(vv[c] + 1e-5f);
        sc[c] = s;
        sh[c] = (cb[c] - m[c]) * s + bb[c];
    }
    for (int idx = tid; idx < CIN * SPAN; idx += 256) {
        int ci = idx / SPAN, p = idx - ci * SPAN;
        int pos = l0b + p - PAD;
        _Float16 v = (_Float16)0.f;
        if (pos >= 0 && pos < 1024) v = in[((size_t)b * CIN + ci) * 1024 + pos];
        tin[p * STRIDE + ci] = v;
    }
    __syncthreads();
    const int lane = tid & 63, wave = tid >> 6;
    const int quad = lane >> 4, n = lane & 15;
    const int lrow0 = wave * 16 + n;        // wave handles l-subtile [wave*16, wave*16+16)
    floatx4 acc[NT];
#pragma unroll
    for (int t = 0; t < NT; ++t) acc[t] = (floatx4){0.f, 0.f, 0.f, 0.f};
#pragma unroll
    for (int k = 0; k < K; ++k) {
#pragma unroll
        for (int cc = 0; cc < NCC; ++cc) {
            half8 bfrag = *(const half8*)&tin[(lrow0 + k) * STRIDE + cc * 32 + quad * 8];
#pragma unroll
            for (int t = 0; t < NT; ++t) {
                int f = (k * NCC + cc) * NT + t;
                half8 afrag = *(const half8*)&wp[((size_t)f * 64 + lane) * 8];
                acc[t] = __builtin_amdgcn_mfma_f32_16x16x32_f16(afrag, bfrag, acc[t], 0, 0, 0);
            }
        }
    }
    const int lg = l0b + wave * 16 + n;
#pragma unroll
    for (int t = 0; t < NT; ++t) {
#pragma unroll
        for (int r = 0; r < 4; ++r) {
            int co = t * 16 + quad * 4 + r;
            float v = fmaxf(fmaf(acc[t][r], sc[co], sh[co]), 0.f);
            out[((size_t)b * COUT + co) * 1024 + lg] = (_Float16)v;
        }
    }
}

// ---------------- pe: conv (256->192, K=8, s=8) -> (Bc,128,192) f32 ----------------
__global__ __launch_bounds__(256) void pe_kernel(
    const _Float16* __restrict__ c0b, const _Float16* __restrict__ c3b,
    const float* __restrict__ w, const float* __restrict__ bias,
    float* __restrict__ out)
{
    __shared__ __align__(16) float in_t[8 * 2048];
    const int tid = threadIdx.x;
    const int b = blockIdx.x >> 4;
    const int n0 = (blockIdx.x & 15) * 8;
    for (int idx = tid; idx < 16384; idx += 256) {
        int n = idx >> 11, r = idx & 2047;
        int ci = r >> 3, k = r & 7;
        int l = (n0 + n) * 8 + k;
        in_t[idx] = (ci < 64) ? (float)c0b[(size_t)(b * 64 + ci) * 1024 + l]
                              : (float)c3b[(size_t)(b * 192 + ci - 64) * 1024 + l];
    }
    __syncthreads();
    if (tid < 192) {
        const int co = tid;
        float acc[8];
        float bv = bias[co];
#pragma unroll
        for (int n = 0; n < 8; ++n) acc[n] = bv;
        const float* wr = w + co * 2048;
        for (int r = 0; r < 2048; r += 8) {
            float wv[8];
#pragma unroll
            for (int q = 0; q < 8; ++q) wv[q] = wr[r + q];
#pragma unroll
            for (int n = 0; n < 8; ++n) {
                const float4* ip = (const float4*)&in_t[n * 2048 + r];
                float4 a0 = ip[0], a1 = ip[1];
                acc[n] = fmaf(a0.x, wv[0], acc[n]); acc[n] = fmaf(a0.y, wv[1], acc[n]);
                acc[n] = fmaf(a0.z, wv[2], acc[n]); acc[n] = fmaf(a0.w, wv[3], acc[n]);
                acc[n] = fmaf(a1.x, wv[4], acc[n]); acc[n] = fmaf(a1.y, wv[5], acc[n]);
                acc[n] = fmaf(a1.z, wv[6], acc[n]); acc[n] = fmaf(a1.w, wv[7], acc[n]);
            }
        }
#pragma unroll
        for (int n = 0; n < 8; ++n)
            out[((size_t)b * 128 + n0 + n) * 192 + co] = acc[n];
    }
}

// ---------------- simplified transformer: LDS-resident, one block/sample ----------------
__global__ __launch_bounds__(256) void transformer_kernel(
    const float* __restrict__ src, const float* __restrict__ wqk,
    const float* __restrict__ bqk, float* __restrict__ dst)
{
    __shared__ float feat[32 * 192];
    __shared__ __half qks[32 * 386];
    __shared__ __half attnS[4 * 32 * 33];
    const int b = blockIdx.x;
    const int tid = threadIdx.x;
    float regout[24];
    for (int i = 0; i < 4; ++i) {
        const float* srow = src + ((size_t)b * 128 + i * 32) * 192;
        if (i == 0) { for (int idx = tid; idx < 6144; idx += 256) feat[idx] = srow[idx]; }
        else        { for (int idx = tid; idx < 6144; idx += 256) feat[idx] += srow[idx]; }
        __syncthreads();
        for (int idx = tid; idx < 384 * 8; idx += 256) {
            int j = idx % 384;
            int n0 = (idx / 384) * 4;
            float a0 = 0, a1 = 0, a2 = 0, a3 = 0;
            for (int c = 0; c < 192; ++c) {
                float wv = wqk[c * 384 + j];
                a0 = fmaf(feat[(n0 + 0) * 192 + c], wv, a0);
                a1 = fmaf(feat[(n0 + 1) * 192 + c], wv, a1);
                a2 = fmaf(feat[(n0 + 2) * 192 + c], wv, a2);
                a3 = fmaf(feat[(n0 + 3) * 192 + c], wv, a3);
            }
            float bv = bqk[j];
            qks[(n0 + 0) * 386 + j] = __float2half(a0 + bv);
            qks[(n0 + 1) * 386 + j] = __float2half(a1 + bv);
            qks[(n0 + 2) * 386 + j] = __float2half(a2 + bv);
            qks[(n0 + 3) * 386 + j] = __float2half(a3 + bv);
        }
        __syncthreads();
        if (tid < 128) {
            int h = tid >> 5, qi = tid & 31;
            float qreg[48];
#pragma unroll
            for (int c = 0; c < 48; ++c) qreg[c] = h2f(qks[qi * 386 + h * 48 + c]);
            float logits[32];
            float mx = -1e30f;
            for (int kj = 0; kj < 32; ++kj) {
                float acc = 0;
#pragma unroll
                for (int c = 0; c < 48; ++c)
                    acc = fmaf(qreg[c], h2f(qks[kj * 386 + 192 + h * 48 + c]), acc);
                acc *= 0.14433756729740643f;
                logits[kj] = acc;
                mx = fmaxf(mx, acc);
            }
            float sum = 0;
#pragma unroll
            for (int kj = 0; kj < 32; ++kj) { float e = __expf(logits[kj] - mx); logits[kj] = e; sum += e; }
            float inv = 1.f / sum;
#pragma unroll
            for (int kj = 0; kj < 32; ++kj)
                attnS[(h * 32 + qi) * 33 + kj] = __float2half(logits[kj] * inv);
        }
        __syncthreads();
        int cnt = 0;
        for (int idx = tid; idx < 6144; idx += 256, ++cnt) {
            int n = idx / 192, cc = idx - n * 192, h = cc / 48;
            float acc = 0;
            for (int j = 0; j < 32; ++j)
                acc = fmaf(h2f(attnS[(h * 32 + n) * 33 + j]), feat[j * 192 + cc], acc);
            regout[cnt] = acc;
        }
        __syncthreads();
        float* drow = dst + ((size_t)b * 128 + i * 32) * 192;
        cnt = 0;
        for (int idx = tid; idx < 6144; idx += 256, ++cnt) {
            feat[idx] = regout[cnt];
            drow[idx] = regout[cnt];
        }
        __syncthreads();
    }
}

// ---------------- MLP + residual + LayerNorm ----------------
__global__ __launch_bounds__(256) void mlp_ln_kernel(
    const float* __restrict__ x, const float* __restrict__ a,
    const float* __restrict__ w1, const float* __restrict__ b1,
    const float* __restrict__ w2, const float* __restrict__ b2,
    const float* __restrict__ lng, const float* __restrict__ lnb,
    float* __restrict__ out)
{
    __shared__ float xr[32 * 192];
    __shared__ float t[32 * 264];
    __shared__ float mu[32], rsd[32];
    const int tid = threadIdx.x;
    const int b = blockIdx.x >> 2;
    const int row0 = (blockIdx.x & 3) * 32;
    const size_t base = ((size_t)b * 128 + row0) * 192;
    for (int idx = tid; idx < 6144; idx += 256) xr[idx] = x[base + idx];
    __syncthreads();
    for (int idx = tid; idx < 32 * 264; idx += 256) {
        int n = idx / 264, j = idx - n * 264;
        float acc = b1[j];
        for (int c = 0; c < 192; ++c)
            acc = fmaf(xr[n * 192 + c], w1[c * 264 + j], acc);
        t[idx] = 0.5f * acc * (1.f + erff(acc * 0.70710678118654752f));
    }
    __syncthreads();
    for (int idx = tid; idx < 6144; idx += 256) {
        int n = idx / 192, c = idx - n * 192;
        float acc = b2[c];
        for (int k = 0; k < 264; ++k)
            acc = fmaf(t[n * 264 + k], w2[k * 192 + c], acc);
        xr[idx] = acc + a[base + idx];
    }
    __syncthreads();
    if (tid < 32) {
        float s = 0;
        for (int c = 0; c < 192; ++c) s += xr[tid * 192 + c];
        float mm = s * (1.f / 192.f);
        float v = 0;
        for (int c = 0; c < 192; ++c) { float d = xr[tid * 192 + c] - mm; v = fmaf(d, d, v); }
        mu[tid] = mm;
        rsd[tid] = rsqrtf(v * (1.f / 192.f) + 1e-5f);
    }
    __syncthreads();
    for (int idx = tid; idx < 6144; idx += 256) {
        int n = idx / 192, c = idx - n * 192;
        out[base + idx] = (xr[idx] - mu[n]) * rsd[n] * lng[c] + lnb[c];
    }
}

// ---------------- mean + classifier head -> f32 ----------------
__global__ __launch_bounds__(192) void head_kernel(
    const float* __restrict__ ln, const float* __restrict__ wcls,
    const float* __restrict__ bcls, float* __restrict__ out)
{
    __shared__ float mean[192];
    const int b = blockIdx.x;
    const int c = threadIdx.x;
    float s = 0.f;
    for (int n = 0; n < 128; ++n) s += ln[((size_t)b * 128 + n) * 192 + c];
    mean[c] = s * (1.f / 128.f);
    __syncthreads();
    if (c < 3) {
        float acc = bcls[c];
        for (int k = 0; k < 192; ++k) acc = fmaf(mean[k], wcls[k * 3 + c], acc);
        out[b * 3 + c] = acc;
    }
}

static const int SZ_DICT[41] = {
    920576, 3682304, 2048, 960, 64, 64, 64, 64, 64,
    73728, 128, 128, 128, 128, 128,
    81920, 128, 128, 128, 128, 128,
    73728, 192, 192, 192, 192, 192,
    393216, 192,
    73728, 384, 73728, 384,
    50688, 264, 50688, 192,
    192, 192, 576, 3};

extern "C" void kernel_launch(void* const* d_in, const int* in_sizes, int n_in,
                              void* d_out, int out_size, void* d_ws, size_t ws_size,
                              hipStream_t stream) {
    if (n_in != 41) {
        fill_const<<<(out_size + 255) / 256, 256, 0, stream>>>((float*)d_out, out_size, 200.f);
        return;
    }
    bool mA = true;
    for (int i = 0; i < 41; ++i) mA = mA && (in_sizes[i] == SZ_DICT[i]);
    if (!mA) {
        fill_const<<<(out_size + 255) / 256, 256, 0, stream>>>((float*)d_out, out_size, 100.f);
        return;
    }
    const float* P[41];
    for (int i = 0; i < 41; ++i) P[i] = (const float*)d_in[i];

    // per-sample scratch: c0b 131072 | u1 393216 | u2 262144 | peb 98304 = 884736 B
    const size_t PER = 884736;
    const size_t WPACK = 512 * 1024;   // packed conv weights region (459 KB used)
    int Bc = 256;
    while (Bc > 4 && (size_t)Bc * PER + WPACK + 4096 > ws_size) Bc >>= 1;
    if ((size_t)Bc * PER + WPACK + 4096 > ws_size) {
        fill_const<<<(out_size + 255) / 256, 256, 0, stream>>>((float*)d_out, out_size, 50.f);
        return;
    }

    char* ws = (char*)d_ws;
    _Float16* c0b = (_Float16*)ws;
    char*     u1  = ws + (size_t)Bc * 131072;
    char*     u2  = u1 + (size_t)Bc * 393216;
    float*    peb = (float*)(u2 + (size_t)Bc * 262144);
    char*     wpk = (char*)(peb + (size_t)Bc * 128 * 192);

    _Float16* adjb = (_Float16*)u1;   // dead before c1 writes u1
    _Float16* c1b  = (_Float16*)u1;
    _Float16* c2b  = (_Float16*)u2;
    _Float16* c3b  = (_Float16*)u1;
    float*    t1b  = (float*)u2;      // after pe, c2b dead
    float*    t2b  = (float*)u1;      // after pe, c3b dead
    float*    lnbuf= (float*)u2;      // after transformer2, t1b dead

    _Float16* w1p = (_Float16*)wpk;              // c1: 9*64*128  = 73728 h
    _Float16* w2p = w1p + 73728;                 // c2: 5*128*128 = 81920 h
    _Float16* w3p = w2p + 81920;                 // c3: 3*128*192 = 73728 h

    pack_w<<<288, 256, 0, stream>>>(P[9],  w1p, 64, 9, 128);
    pack_w<<<320, 256, 0, stream>>>(P[15], w2p, 128, 5, 128);
    pack_w<<<288, 256, 0, stream>>>(P[21], w3p, 128, 3, 192);

    const int nchunk = 512 / Bc;
    for (int c = 0; c < nchunk; ++c) {
        const size_t b0 = (size_t)c * Bc;
        adj_kernel<<<Bc * 2, 256, 0, stream>>>(P[0] + b0 * 1798, P[1], P[2], adjb);
        c0_kernel<<<Bc * 256, 256, 0, stream>>>(adjb, P[3], P[4],
                                                P[5], P[6], P[7], P[8], c0b);
        conv_mfma<64, 9, 4, 128><<<Bc * 16, 256, 0, stream>>>(c0b, w1p, P[10],
                                                P[11], P[12], P[13], P[14], c1b);
        conv_mfma<128, 5, 2, 128><<<Bc * 16, 256, 0, stream>>>(c1b, w2p, P[16],
                                                P[17], P[18], P[19], P[20], c2b);
        conv_mfma<128, 3, 1, 192><<<Bc * 16, 256, 0, stream>>>(c2b, w3p, P[22],
                                                P[23], P[24], P[25], P[26], c3b);
        pe_kernel<<<Bc * 16, 256, 0, stream>>>(c0b, c3b, P[27], P[28], peb);
        transformer_kernel<<<Bc, 256, 0, stream>>>(peb, P[29], P[30], t1b);
        transformer_kernel<<<Bc, 256, 0, stream>>>(t1b, P[31], P[32], t2b);
        mlp_ln_kernel<<<Bc * 4, 256, 0, stream>>>(peb, t2b, P[33], P[34], P[35], P[36],
                                                  P[37], P[38], lnbuf);
        head_kernel<<<Bc, 192, 0, stream>>>(lnbuf, P[39], P[40], (float*)d_out + b0 * 3);
    }
}

// Round 12
// 4669.620 us; speedup vs baseline: 15.5269x; 1.2390x over previous
//
#include <hip/hip_runtime.h>
#include <hip/hip_bf16.h>
#include <hip/hip_fp16.h>
#include <cstddef>

typedef _Float16 half8 __attribute__((ext_vector_type(8)));
typedef float floatx4 __attribute__((ext_vector_type(4)));

__global__ __launch_bounds__(256) void fill_const(float* out, int n, float v) {
    int i = blockIdx.x * 256 + threadIdx.x;
    if (i < n) out[i] = v;
}

// ---------------- pack conv weights into MFMA A-frag order ----------------
// f = (k*NCC + cc)*NT + t ; co = t*16 + (lane&15) ; ci = cc*32 + (lane>>4)*8 + j
__global__ __launch_bounds__(256) void pack_w(
    const float* __restrict__ w, _Float16* __restrict__ out,
    int CIN, int K, int COUT)
{
    int NT = COUT >> 4, NCC = CIN >> 5;
    int total = K * CIN * COUT;
    int idx = blockIdx.x * 256 + threadIdx.x;
    if (idx >= total) return;
    int j = idx & 7, lane = (idx >> 3) & 63, f = idx >> 9;
    int t = f % NT, cc = (f / NT) % NCC, k = f / (NT * NCC);
    int co = t * 16 + (lane & 15);
    int ci = cc * 32 + (lane >> 4) * 8 + j;
    out[idx] = (_Float16)w[(co * CIN + ci) * K + k];
}

// ---------------- pack pe weights [192][2048] -> frags f = cc*12 + t ----------------
__global__ __launch_bounds__(256) void pack_pe(
    const float* __restrict__ w, _Float16* __restrict__ out)
{
    int idx = blockIdx.x * 256 + threadIdx.x;
    if (idx >= 393216) return;
    int j = idx & 7, lane = (idx >> 3) & 63, f = idx >> 9;
    int t = f % 12, cc = f / 12;
    int co = t * 16 + (lane & 15);
    int r = cc * 32 + (lane >> 4) * 8 + j;
    out[idx] = (_Float16)w[co * 2048 + r];
}

// ---------------- pack wqk [192][384] -> B-frags f = ks*24 + ntile ----------------
__global__ __launch_bounds__(256) void pack_qk(
    const float* __restrict__ w, _Float16* __restrict__ out)
{
    int idx = blockIdx.x * 256 + threadIdx.x;
    if (idx >= 73728) return;
    int j = idx & 7, lane = (idx >> 3) & 63, f = idx >> 9;
    int nt = f % 24, ks = f / 24;
    int c = ks * 32 + (lane >> 4) * 8 + j;
    int jcol = nt * 16 + (lane & 15);
    out[idx] = (_Float16)w[c * 384 + jcol];
}

// ---------------- adj: x @ w_adj + b_adj -> fp16 ----------------
__global__ __launch_bounds__(256) void adj_kernel(
    const float* __restrict__ x, const float* __restrict__ w,
    const float* __restrict__ bias, _Float16* __restrict__ out)
{
    __shared__ float xs[4 * 1798];
    const int tid = threadIdx.x;
    const int jt = blockIdx.x & 7;
    const int b0 = (blockIdx.x >> 3) * 4;
    for (int idx = tid; idx < 4 * 1798; idx += 256)
        xs[idx] = x[(size_t)b0 * 1798 + idx];
    __syncthreads();
    const int j = jt * 256 + tid;
    float a0 = 0, a1 = 0, a2 = 0, a3 = 0;
    for (int k = 0; k < 1798; ++k) {
        float wv = w[(size_t)k * 2048 + j];
        a0 = fmaf(xs[k], wv, a0);
        a1 = fmaf(xs[1798 + k], wv, a1);
        a2 = fmaf(xs[2 * 1798 + k], wv, a2);
        a3 = fmaf(xs[3 * 1798 + k], wv, a3);
    }
    float bv = bias[j];
    out[(size_t)(b0 + 0) * 2048 + j] = (_Float16)(a0 + bv);
    out[(size_t)(b0 + 1) * 2048 + j] = (_Float16)(a1 + bv);
    out[(size_t)(b0 + 2) * 2048 + j] = (_Float16)(a2 + bv);
    out[(size_t)(b0 + 3) * 2048 + j] = (_Float16)(a3 + bv);
}

// ---------------- c0 ----------------
__global__ __launch_bounds__(256) void c0_kernel(
    const _Float16* __restrict__ in, const float* __restrict__ w,
    const float* __restrict__ cb, const float* __restrict__ g,
    const float* __restrict__ bb, const float* __restrict__ m,
    const float* __restrict__ vv, _Float16* __restrict__ out)
{
    int idx = blockIdx.x * 256 + threadIdx.x;
    int l = idx & 1023;
    int co = (idx >> 10) & 63;
    int b = idx >> 16;
    float acc = 0.f;
    int p0 = 2 * l - 7;
#pragma unroll
    for (int k = 0; k < 15; ++k) {
        int pos = p0 + k;
        if (pos >= 0 && pos < 2048)
            acc = fmaf((float)in[(size_t)b * 2048 + pos], w[co * 15 + k], acc);
    }
    float s = g[co] * rsqrtf(vv[co] + 1e-5f);
    out[idx] = (_Float16)fmaxf((acc + cb[co] - m[co]) * s + bb[co], 0.f);
}

// ---------------- conv via MFMA (unchanged from round 11) ----------------
template <int CIN, int K, int PAD, int COUT>
__global__ __launch_bounds__(256) void conv_mfma(
    const _Float16* __restrict__ in, const _Float16* __restrict__ wp,
    const float* __restrict__ cb, const float* __restrict__ g,
    const float* __restrict__ bb, const float* __restrict__ m,
    const float* __restrict__ vv, _Float16* __restrict__ out)
{
    constexpr int STRIDE = (CIN == 64) ? 72 : 152;
    constexpr int SPAN = 64 + K - 1;
    constexpr int NCC = CIN / 32, NT = COUT / 16;
    __shared__ _Float16 tin[SPAN * STRIDE];
    __shared__ float sc[COUT], sh[COUT];
    const int tid = threadIdx.x;
    const int b = blockIdx.x >> 4;
    const int l0b = (blockIdx.x & 15) * 64;
    for (int c = tid; c < COUT; c += 256) {
        float s = g[c] * rsqrtf(vv[c] + 1e-5f);
        sc[c] = s;
        sh[c] = (cb[c] - m[c]) * s + bb[c];
    }
    for (int idx = tid; idx < CIN * SPAN; idx += 256) {
        int ci = idx / SPAN, p = idx - ci * SPAN;
        int pos = l0b + p - PAD;
        _Float16 v = (_Float16)0.f;
        if (pos >= 0 && pos < 1024) v = in[((size_t)b * CIN + ci) * 1024 + pos];
        tin[p * STRIDE + ci] = v;
    }
    __syncthreads();
    const int lane = tid & 63, wave = tid >> 6;
    const int quad = lane >> 4, n = lane & 15;
    const int lrow0 = wave * 16 + n;
    floatx4 acc[NT];
#pragma unroll
    for (int t = 0; t < NT; ++t) acc[t] = (floatx4){0.f, 0.f, 0.f, 0.f};
#pragma unroll
    for (int k = 0; k < K; ++k) {
#pragma unroll
        for (int cc = 0; cc < NCC; ++cc) {
            half8 bfrag = *(const half8*)&tin[(lrow0 + k) * STRIDE + cc * 32 + quad * 8];
#pragma unroll
            for (int t = 0; t < NT; ++t) {
                int f = (k * NCC + cc) * NT + t;
                half8 afrag = *(const half8*)&wp[((size_t)f * 64 + lane) * 8];
                acc[t] = __builtin_amdgcn_mfma_f32_16x16x32_f16(afrag, bfrag, acc[t], 0, 0, 0);
            }
        }
    }
    const int lg = l0b + wave * 16 + n;
#pragma unroll
    for (int t = 0; t < NT; ++t)
#pragma unroll
        for (int r = 0; r < 4; ++r) {
            int co = t * 16 + quad * 4 + r;
            float v = fmaxf(fmaf(acc[t][r], sc[co], sh[co]), 0.f);
            out[((size_t)b * COUT + co) * 1024 + lg] = (_Float16)v;
        }
}

// ---------------- pe via MFMA: M=tokens, N=192, K=2048; B-frags direct from global ----------------
__global__ __launch_bounds__(256) void pe_mfma(
    const _Float16* __restrict__ c0b,  // [Bc,64,1024]
    const _Float16* __restrict__ c3b,  // [Bc,192,1024]
    const _Float16* __restrict__ wp,   // packed
    const float* __restrict__ bias,
    float* __restrict__ out)           // [Bc,128,192]
{
    const int tid = threadIdx.x;
    const int w = tid >> 6, lane = tid & 63, quad = lane >> 4, col = lane & 15;
    const int s = blockIdx.x >> 1;
    const int n0 = (blockIdx.x & 1) * 64;
    const int token = n0 + w * 16 + col;   // 0..127
    floatx4 acc[12];
#pragma unroll
    for (int t = 0; t < 12; ++t) acc[t] = (floatx4){0.f, 0.f, 0.f, 0.f};
    for (int cc = 0; cc < 64; ++cc) {
        int ci = cc * 4 + quad;
        const _Float16* src = (ci < 64)
            ? c0b + ((size_t)s * 64 + ci) * 1024 + token * 8
            : c3b + ((size_t)s * 192 + (ci - 64)) * 1024 + token * 8;
        half8 bf = *(const half8*)src;
#pragma unroll
        for (int t = 0; t < 12; ++t) {
            half8 af = *(const half8*)&wp[((size_t)(cc * 12 + t) * 64 + lane) * 8];
            acc[t] = __builtin_amdgcn_mfma_f32_16x16x32_f16(af, bf, acc[t], 0, 0, 0);
        }
    }
#pragma unroll
    for (int t = 0; t < 12; ++t)
#pragma unroll
        for (int r = 0; r < 4; ++r) {
            int co = t * 16 + quad * 4 + r;
            out[((size_t)s * 128 + token) * 192 + co] = acc[t][r] + bias[co];
        }
}

// ---------------- transformer: full batch, MFMA qk + MFMA S, LDS-resident ----------------
__global__ __launch_bounds__(256) void transformer_mfma(
    const float* __restrict__ src,      // [512,128,192]
    const _Float16* __restrict__ wqkp,  // packed B-frags
    const float* __restrict__ bqk,      // [384]
    float* __restrict__ dst)            // [512,128,192]
{
    __shared__ float feat[6144];        // 24576 B, f32, phases 1-6
    __shared__ _Float16 uA[6400];       // featH [32][200] (ph2) | S16 [4][32][36] (ph3-4)
    __shared__ _Float16 uB[12544];      // qks [32][392] (ph2-3) | attnS [4][32][40] (ph4-5)
    __shared__ _Float16 zerobuf[16];
    const int b = blockIdx.x;
    const int tid = threadIdx.x;
    const int w = tid >> 6, lane = tid & 63, quad = lane >> 4, col = lane & 15;
    if (tid < 16) zerobuf[tid] = (_Float16)0.f;
    float regout[24];
    for (int i = 0; i < 4; ++i) {
        // phase1: feat accumulate + f16 mirror
        const float* srow = src + ((size_t)b * 128 + i * 32) * 192;
        for (int idx = tid; idx < 6144; idx += 256) {
            float f = (i == 0) ? srow[idx] : feat[idx] + srow[idx];
            feat[idx] = f;
            int tok = idx / 192, c = idx - tok * 192;
            uA[tok * 200 + c] = (_Float16)f;
        }
        __syncthreads();
        // phase2: qk = feat @ wqk : M=32, N=384, K=192. wave w -> ntiles 6w..6w+5
        {
            floatx4 acc2[12];
#pragma unroll
            for (int t = 0; t < 12; ++t) acc2[t] = (floatx4){0.f, 0.f, 0.f, 0.f};
#pragma unroll
            for (int ks = 0; ks < 6; ++ks) {
                half8 a0 = *(const half8*)&uA[(col) * 200 + ks * 32 + quad * 8];
                half8 a1 = *(const half8*)&uA[(16 + col) * 200 + ks * 32 + quad * 8];
#pragma unroll
                for (int nl = 0; nl < 6; ++nl) {
                    int ntile = w * 6 + nl;
                    half8 bf = *(const half8*)&wqkp[((size_t)(ks * 24 + ntile) * 64 + lane) * 8];
                    acc2[nl] = __builtin_amdgcn_mfma_f32_16x16x32_f16(a0, bf, acc2[nl], 0, 0, 0);
                    acc2[6 + nl] = __builtin_amdgcn_mfma_f32_16x16x32_f16(a1, bf, acc2[6 + nl], 0, 0, 0);
                }
            }
            __syncthreads();  // uA (featH) fully consumed
#pragma unroll
            for (int mt = 0; mt < 2; ++mt)
#pragma unroll
                for (int nl = 0; nl < 6; ++nl) {
                    int j = (w * 6 + nl) * 16 + col;
                    float bv = bqk[j];
#pragma unroll
                    for (int r = 0; r < 4; ++r) {
                        int tok = mt * 16 + quad * 4 + r;
                        uB[tok * 392 + j] = (_Float16)(acc2[mt * 6 + nl][r] + bv);
                    }
                }
            __syncthreads();
        }
        // phase3: S = (q*scale) . k : per head (wave=h), M=32,N=32, K=48 padded to 64
        {
            const int h = w;
            floatx4 acc3[4];
#pragma unroll
            for (int t = 0; t < 4; ++t) acc3[t] = (floatx4){0.f, 0.f, 0.f, 0.f};
#pragma unroll
            for (int ks = 0; ks < 2; ++ks) {
                bool z = (ks == 1 && quad >= 2);
                const _Float16* pq0 = z ? zerobuf : &uB[(col) * 392 + h * 48 + ks * 32 + quad * 8];
                const _Float16* pq1 = z ? zerobuf : &uB[(16 + col) * 392 + h * 48 + ks * 32 + quad * 8];
                const _Float16* pk0 = z ? zerobuf : &uB[(col) * 392 + 192 + h * 48 + ks * 32 + quad * 8];
                const _Float16* pk1 = z ? zerobuf : &uB[(16 + col) * 392 + 192 + h * 48 + ks * 32 + quad * 8];
                half8 q0 = *(const half8*)pq0, q1 = *(const half8*)pq1;
                half8 k0 = *(const half8*)pk0, k1 = *(const half8*)pk1;
                acc3[0] = __builtin_amdgcn_mfma_f32_16x16x32_f16(q0, k0, acc3[0], 0, 0, 0);
                acc3[1] = __builtin_amdgcn_mfma_f32_16x16x32_f16(q0, k1, acc3[1], 0, 0, 0);
                acc3[2] = __builtin_amdgcn_mfma_f32_16x16x32_f16(q1, k0, acc3[2], 0, 0, 0);
                acc3[3] = __builtin_amdgcn_mfma_f32_16x16x32_f16(q1, k1, acc3[3], 0, 0, 0);
            }
            __syncthreads();  // uA free (featH dead since phase2 barrier)
#pragma unroll
            for (int mt = 0; mt < 2; ++mt)
#pragma unroll
                for (int nt = 0; nt < 2; ++nt)
#pragma unroll
                    for (int r = 0; r < 4; ++r) {
                        int q = mt * 16 + quad * 4 + r;
                        int k = nt * 16 + col;
                        uA[(h * 32 + q) * 36 + k] =
                            (_Float16)(acc3[mt * 2 + nt][r] * 0.14433756729740643f);
                    }
            __syncthreads();
        }
        // phase4: softmax rows (S16 in uA) -> attnS f16 (uB, qks dead)
        if (tid < 128) {
            int h = tid >> 5, qi = tid & 31;
            const _Float16* row = &uA[(h * 32 + qi) * 36];
            float lg[32];
            float mx = -1e30f;
#pragma unroll
            for (int k = 0; k < 32; ++k) { lg[k] = (float)row[k]; mx = fmaxf(mx, lg[k]); }
            float sum = 0.f;
#pragma unroll
            for (int k = 0; k < 32; ++k) { lg[k] = __expf(lg[k] - mx); sum += lg[k]; }
            float inv = 1.f / sum;
            _Float16* arow = &uB[(h * 32 + qi) * 40];
#pragma unroll
            for (int k = 0; k < 32; ++k) arow[k] = (_Float16)(lg[k] * inv);
        }
        __syncthreads();
        // phase5: out = attn @ v (VALU; feat f32)
        int cnt = 0;
        for (int idx = tid; idx < 6144; idx += 256, ++cnt) {
            int n = idx / 192, cc = idx - n * 192, h = cc / 48;
            const _Float16* arow = &uB[(h * 32 + n) * 40];
            float acc = 0.f;
#pragma unroll
            for (int j = 0; j < 32; ++j)
                acc = fmaf((float)arow[j], feat[j * 192 + cc], acc);
            regout[cnt] = acc;
        }
        __syncthreads();
        // phase6: feat <- out, write dst
        float* drow = dst + ((size_t)b * 128 + i * 32) * 192;
        cnt = 0;
        for (int idx = tid; idx < 6144; idx += 256, ++cnt) {
            feat[idx] = regout[cnt];
            drow[idx] = regout[cnt];
        }
        __syncthreads();
    }
}

// ---------------- MLP + residual + LayerNorm (full batch) ----------------
__global__ __launch_bounds__(256) void mlp_ln_kernel(
    const float* __restrict__ x, const float* __restrict__ a,
    const float* __restrict__ w1, const float* __restrict__ b1,
    const float* __restrict__ w2, const float* __restrict__ b2,
    const float* __restrict__ lng, const float* __restrict__ lnb,
    float* __restrict__ out)
{
    __shared__ float xr[32 * 192];
    __shared__ float t[32 * 264];
    __shared__ float mu[32], rsd[32];
    const int tid = threadIdx.x;
    const int b = blockIdx.x >> 2;
    const int row0 = (blockIdx.x & 3) * 32;
    const size_t base = ((size_t)b * 128 + row0) * 192;
    for (int idx = tid; idx < 6144; idx += 256) xr[idx] = x[base + idx];
    __syncthreads();
    for (int idx = tid; idx < 32 * 264; idx += 256) {
        int n = idx / 264, j = idx - n * 264;
        float acc = b1[j];
        for (int c = 0; c < 192; ++c)
            acc = fmaf(xr[n * 192 + c], w1[c * 264 + j], acc);
        t[idx] = 0.5f * acc * (1.f + erff(acc * 0.70710678118654752f));
    }
    __syncthreads();
    for (int idx = tid; idx < 6144; idx += 256) {
        int n = idx / 192, c = idx - n * 192;
        float acc = b2[c];
        for (int k = 0; k < 264; ++k)
            acc = fmaf(t[n * 264 + k], w2[k * 192 + c], acc);
        xr[idx] = acc + a[base + idx];
    }
    __syncthreads();
    if (tid < 32) {
        float s = 0;
        for (int c = 0; c < 192; ++c) s += xr[tid * 192 + c];
        float mm = s * (1.f / 192.f);
        float v = 0;
        for (int c = 0; c < 192; ++c) { float d = xr[tid * 192 + c] - mm; v = fmaf(d, d, v); }
        mu[tid] = mm;
        rsd[tid] = rsqrtf(v * (1.f / 192.f) + 1e-5f);
    }
    __syncthreads();
    for (int idx = tid; idx < 6144; idx += 256) {
        int n = idx / 192, c = idx - n * 192;
        out[base + idx] = (xr[idx] - mu[n]) * rsd[n] * lng[c] + lnb[c];
    }
}

// ---------------- mean + classifier head ----------------
__global__ __launch_bounds__(192) void head_kernel(
    const float* __restrict__ ln, const float* __restrict__ wcls,
    const float* __restrict__ bcls, float* __restrict__ out)
{
    __shared__ float mean[192];
    const int b = blockIdx.x;
    const int c = threadIdx.x;
    float s = 0.f;
    for (int n = 0; n < 128; ++n) s += ln[((size_t)b * 128 + n) * 192 + c];
    mean[c] = s * (1.f / 128.f);
    __syncthreads();
    if (c < 3) {
        float acc = bcls[c];
        for (int k = 0; k < 192; ++k) acc = fmaf(mean[k], wcls[k * 3 + c], acc);
        out[b * 3 + c] = acc;
    }
}

static const int SZ_DICT[41] = {
    920576, 3682304, 2048, 960, 64, 64, 64, 64, 64,
    73728, 128, 128, 128, 128, 128,
    81920, 128, 128, 128, 128, 128,
    73728, 192, 192, 192, 192, 192,
    393216, 192,
    73728, 384, 73728, 384,
    50688, 264, 50688, 192,
    192, 192, 576, 3};

extern "C" void kernel_launch(void* const* d_in, const int* in_sizes, int n_in,
                              void* d_out, int out_size, void* d_ws, size_t ws_size,
                              hipStream_t stream) {
    if (n_in != 41) {
        fill_const<<<(out_size + 255) / 256, 256, 0, stream>>>((float*)d_out, out_size, 200.f);
        return;
    }
    bool mA = true;
    for (int i = 0; i < 41; ++i) mA = mA && (in_sizes[i] == SZ_DICT[i]);
    if (!mA) {
        fill_const<<<(out_size + 255) / 256, 256, 0, stream>>>((float*)d_out, out_size, 100.f);
        return;
    }
    const float* P[41];
    for (int i = 0; i < 41; ++i) P[i] = (const float*)d_in[i];

    // layout: [peb 50.3MB][tokA 50.3MB][tokB 50.3MB][wpack 1.6MB]
    const size_t TOK = (size_t)512 * 128 * 192 * 4;  // 50,331,648
    const size_t WPACK = 1572864;
    if (3 * TOK + WPACK > ws_size) {
        fill_const<<<(out_size + 255) / 256, 256, 0, stream>>>((float*)d_out, out_size, 50.f);
        return;
    }
    char* ws = (char*)d_ws;
    float* peb = (float*)ws;
    char*  tokA = ws + TOK;
    char*  tokB = tokA + TOK;
    char*  wpk = tokB + TOK;

    const int BcC = 128;  // conv chunk; scratch = 100,663,296 B = tokA+tokB exactly
    _Float16* c0b = (_Float16*)tokA;
    char*     u1  = tokA + (size_t)BcC * 131072;
    char*     u2  = u1 + (size_t)BcC * 393216;
    _Float16* adjb = (_Float16*)u1;
    _Float16* c1b  = (_Float16*)u1;
    _Float16* c2b  = (_Float16*)u2;
    _Float16* c3b  = (_Float16*)u1;
    float* t1b = (float*)tokA;
    float* t2b = (float*)tokB;
    float* lnbuf = (float*)tokA;

    _Float16* w1p  = (_Float16*)wpk;        // 73728
    _Float16* w2p  = w1p + 73728;           // 81920
    _Float16* w3p  = w2p + 81920;           // 73728
    _Float16* wpep = w3p + 73728;           // 393216
    _Float16* wq0p = wpep + 393216;         // 73728
    _Float16* wq1p = wq0p + 73728;          // 73728

    pack_w<<<288, 256, 0, stream>>>(P[9],  w1p, 64, 9, 128);
    pack_w<<<320, 256, 0, stream>>>(P[15], w2p, 128, 5, 128);
    pack_w<<<288, 256, 0, stream>>>(P[21], w3p, 128, 3, 192);
    pack_pe<<<1536, 256, 0, stream>>>(P[27], wpep);
    pack_qk<<<288, 256, 0, stream>>>(P[29], wq0p);
    pack_qk<<<288, 256, 0, stream>>>(P[31], wq1p);

    for (int c = 0; c < 4; ++c) {
        const size_t b0 = (size_t)c * BcC;
        adj_kernel<<<BcC * 2, 256, 0, stream>>>(P[0] + b0 * 1798, P[1], P[2], adjb);
        c0_kernel<<<BcC * 256, 256, 0, stream>>>(adjb, P[3], P[4],
                                                 P[5], P[6], P[7], P[8], c0b);
        conv_mfma<64, 9, 4, 128><<<BcC * 16, 256, 0, stream>>>(c0b, w1p, P[10],
                                                 P[11], P[12], P[13], P[14], c1b);
        conv_mfma<128, 5, 2, 128><<<BcC * 16, 256, 0, stream>>>(c1b, w2p, P[16],
                                                 P[17], P[18], P[19], P[20], c2b);
        conv_mfma<128, 3, 1, 192><<<BcC * 16, 256, 0, stream>>>(c2b, w3p, P[22],
                                                 P[23], P[24], P[25], P[26], c3b);
        pe_mfma<<<BcC * 2, 256, 0, stream>>>(c0b, c3b, wpep, P[28],
                                             peb + b0 * 128 * 192);
    }
    transformer_mfma<<<512, 256, 0, stream>>>(peb, wq0p, P[30], t1b);
    transformer_mfma<<<512, 256, 0, stream>>>(t1b, wq1p, P[32], t2b);
    mlp_ln_kernel<<<2048, 256, 0, stream>>>(peb, t2b, P[33], P[34], P[35], P[36],
                                            P[37], P[38], lnbuf);
    head_kernel<<<512, 192, 0, stream>>>(lnbuf, P[39], P[40], (float*)d_out);
}

// Round 13
// 3568.999 us; speedup vs baseline: 20.3151x; 1.3084x over previous
//
#include <hip/hip_runtime.h>
#include <hip/hip_bf16.h>
#include <hip/hip_fp16.h>
#include <cstddef>

typedef _Float16 half8 __attribute__((ext_vector_type(8)));
typedef _Float16 half4 __attribute__((ext_vector_type(4)));
typedef float floatx4 __attribute__((ext_vector_type(4)));

__global__ __launch_bounds__(256) void fill_const(float* out, int n, float v) {
    int i = blockIdx.x * 256 + threadIdx.x;
    if (i < n) out[i] = v;
}

// ---------------- pack conv weights into MFMA A-frag order ----------------
__global__ __launch_bounds__(256) void pack_w(
    const float* __restrict__ w, _Float16* __restrict__ out,
    int CIN, int K, int COUT)
{
    int NT = COUT >> 4, NCC = CIN >> 5;
    int total = K * CIN * COUT;
    int idx = blockIdx.x * 256 + threadIdx.x;
    if (idx >= total) return;
    int j = idx & 7, lane = (idx >> 3) & 63, f = idx >> 9;
    int t = f % NT, cc = (f / NT) % NCC, k = f / (NT * NCC);
    int co = t * 16 + (lane & 15);
    int ci = cc * 32 + (lane >> 4) * 8 + j;
    out[idx] = (_Float16)w[(co * CIN + ci) * K + k];
}

// ---------------- pack pe weights [192][2048] -> frags f = cc*12 + t ----------------
__global__ __launch_bounds__(256) void pack_pe(
    const float* __restrict__ w, _Float16* __restrict__ out)
{
    int idx = blockIdx.x * 256 + threadIdx.x;
    if (idx >= 393216) return;
    int j = idx & 7, lane = (idx >> 3) & 63, f = idx >> 9;
    int t = f % 12, cc = f / 12;
    int co = t * 16 + (lane & 15);
    int r = cc * 32 + (lane >> 4) * 8 + j;
    out[idx] = (_Float16)w[co * 2048 + r];
}

// ---------------- pack wqk [192][384] -> B-frags f = ks*24 + ntile ----------------
__global__ __launch_bounds__(256) void pack_qk(
    const float* __restrict__ w, _Float16* __restrict__ out)
{
    int idx = blockIdx.x * 256 + threadIdx.x;
    if (idx >= 73728) return;
    int j = idx & 7, lane = (idx >> 3) & 63, f = idx >> 9;
    int nt = f % 24, ks = f / 24;
    int c = ks * 32 + (lane >> 4) * 8 + j;
    int jcol = nt * 16 + (lane & 15);
    out[idx] = (_Float16)w[c * 384 + jcol];
}

// ---------------- pack w_fc1 [192][264] -> A-frags f = ks*17 + t (N pad 272) ----------------
__global__ __launch_bounds__(256) void pack_mlp1(
    const float* __restrict__ w, _Float16* __restrict__ out)
{
    int idx = blockIdx.x * 256 + threadIdx.x;
    if (idx >= 52224) return;
    int j = idx & 7, lane = (idx >> 3) & 63, f = idx >> 9;
    int t = f % 17, ks = f / 17;
    int jcol = t * 16 + (lane & 15);
    int c = ks * 32 + (lane >> 4) * 8 + j;
    out[idx] = (jcol < 264) ? (_Float16)w[c * 264 + jcol] : (_Float16)0.f;
}

// ---------------- pack w_fc2 [264][192] -> A-frags f = ks*12 + t (K pad 288) ----------------
__global__ __launch_bounds__(256) void pack_mlp2(
    const float* __restrict__ w, _Float16* __restrict__ out)
{
    int idx = blockIdx.x * 256 + threadIdx.x;
    if (idx >= 55296) return;
    int j = idx & 7, lane = (idx >> 3) & 63, f = idx >> 9;
    int t = f % 12, ks = f / 12;
    int co = t * 16 + (lane & 15);
    int k = ks * 32 + (lane >> 4) * 8 + j;
    out[idx] = (k < 264) ? (_Float16)w[k * 192 + co] : (_Float16)0.f;
}

// ---------------- adj: x @ w_adj + b_adj -> fp16 ----------------
__global__ __launch_bounds__(256) void adj_kernel(
    const float* __restrict__ x, const float* __restrict__ w,
    const float* __restrict__ bias, _Float16* __restrict__ out)
{
    __shared__ float xs[4 * 1798];
    const int tid = threadIdx.x;
    const int jt = blockIdx.x & 7;
    const int b0 = (blockIdx.x >> 3) * 4;
    for (int idx = tid; idx < 4 * 1798; idx += 256)
        xs[idx] = x[(size_t)b0 * 1798 + idx];
    __syncthreads();
    const int j = jt * 256 + tid;
    float a0 = 0, a1 = 0, a2 = 0, a3 = 0;
    for (int k = 0; k < 1798; ++k) {
        float wv = w[(size_t)k * 2048 + j];
        a0 = fmaf(xs[k], wv, a0);
        a1 = fmaf(xs[1798 + k], wv, a1);
        a2 = fmaf(xs[2 * 1798 + k], wv, a2);
        a3 = fmaf(xs[3 * 1798 + k], wv, a3);
    }
    float bv = bias[j];
    out[(size_t)(b0 + 0) * 2048 + j] = (_Float16)(a0 + bv);
    out[(size_t)(b0 + 1) * 2048 + j] = (_Float16)(a1 + bv);
    out[(size_t)(b0 + 2) * 2048 + j] = (_Float16)(a2 + bv);
    out[(size_t)(b0 + 3) * 2048 + j] = (_Float16)(a3 + bv);
}

// ---------------- c0 ----------------
__global__ __launch_bounds__(256) void c0_kernel(
    const _Float16* __restrict__ in, const float* __restrict__ w,
    const float* __restrict__ cb, const float* __restrict__ g,
    const float* __restrict__ bb, const float* __restrict__ m,
    const float* __restrict__ vv, _Float16* __restrict__ out)
{
    int idx = blockIdx.x * 256 + threadIdx.x;
    int l = idx & 1023;
    int co = (idx >> 10) & 63;
    int b = idx >> 16;
    float acc = 0.f;
    int p0 = 2 * l - 7;
#pragma unroll
    for (int k = 0; k < 15; ++k) {
        int pos = p0 + k;
        if (pos >= 0 && pos < 2048)
            acc = fmaf((float)in[(size_t)b * 2048 + pos], w[co * 15 + k], acc);
    }
    float s = g[co] * rsqrtf(vv[co] + 1e-5f);
    out[idx] = (_Float16)fmaxf((acc + cb[co] - m[co]) * s + bb[co], 0.f);
}

// ---------------- conv via MFMA ----------------
template <int CIN, int K, int PAD, int COUT>
__global__ __launch_bounds__(256) void conv_mfma(
    const _Float16* __restrict__ in, const _Float16* __restrict__ wp,
    const float* __restrict__ cb, const float* __restrict__ g,
    const float* __restrict__ bb, const float* __restrict__ m,
    const float* __restrict__ vv, _Float16* __restrict__ out)
{
    constexpr int STRIDE = (CIN == 64) ? 72 : 152;
    constexpr int SPAN = 64 + K - 1;
    constexpr int NCC = CIN / 32, NT = COUT / 16;
    __shared__ _Float16 tin[SPAN * STRIDE];
    __shared__ float sc[COUT], sh[COUT];
    const int tid = threadIdx.x;
    const int b = blockIdx.x >> 4;
    const int l0b = (blockIdx.x & 15) * 64;
    for (int c = tid; c < COUT; c += 256) {
        float s = g[c] * rsqrtf(vv[c] + 1e-5f);
        sc[c] = s;
        sh[c] = (cb[c] - m[c]) * s + bb[c];
    }
    for (int idx = tid; idx < CIN * SPAN; idx += 256) {
        int ci = idx / SPAN, p = idx - ci * SPAN;
        int pos = l0b + p - PAD;
        _Float16 v = (_Float16)0.f;
        if (pos >= 0 && pos < 1024) v = in[((size_t)b * CIN + ci) * 1024 + pos];
        tin[p * STRIDE + ci] = v;
    }
    __syncthreads();
    const int lane = tid & 63, wave = tid >> 6;
    const int quad = lane >> 4, n = lane & 15;
    const int lrow0 = wave * 16 + n;
    floatx4 acc[NT];
#pragma unroll
    for (int t = 0; t < NT; ++t) acc[t] = (floatx4){0.f, 0.f, 0.f, 0.f};
#pragma unroll
    for (int k = 0; k < K; ++k) {
#pragma unroll
        for (int cc = 0; cc < NCC; ++cc) {
            half8 bfrag = *(const half8*)&tin[(lrow0 + k) * STRIDE + cc * 32 + quad * 8];
#pragma unroll
            for (int t = 0; t < NT; ++t) {
                int f = (k * NCC + cc) * NT + t;
                half8 afrag = *(const half8*)&wp[((size_t)f * 64 + lane) * 8];
                acc[t] = __builtin_amdgcn_mfma_f32_16x16x32_f16(afrag, bfrag, acc[t], 0, 0, 0);
            }
        }
    }
    const int lg = l0b + wave * 16 + n;
#pragma unroll
    for (int t = 0; t < NT; ++t)
#pragma unroll
        for (int r = 0; r < 4; ++r) {
            int co = t * 16 + quad * 4 + r;
            float v = fmaxf(fmaf(acc[t][r], sc[co], sh[co]), 0.f);
            out[((size_t)b * COUT + co) * 1024 + lg] = (_Float16)v;
        }
}

// ---------------- pe via MFMA; emits f32 + f16 mirror ----------------
__global__ __launch_bounds__(256) void pe_mfma(
    const _Float16* __restrict__ c0b, const _Float16* __restrict__ c3b,
    const _Float16* __restrict__ wp, const float* __restrict__ bias,
    float* __restrict__ out, _Float16* __restrict__ outh)
{
    const int tid = threadIdx.x;
    const int w = tid >> 6, lane = tid & 63, quad = lane >> 4, col = lane & 15;
    const int s = blockIdx.x >> 1;
    const int n0 = (blockIdx.x & 1) * 64;
    const int token = n0 + w * 16 + col;
    floatx4 acc[12];
#pragma unroll
    for (int t = 0; t < 12; ++t) acc[t] = (floatx4){0.f, 0.f, 0.f, 0.f};
    for (int cc = 0; cc < 64; ++cc) {
        int ci = cc * 4 + quad;
        const _Float16* src = (ci < 64)
            ? c0b + ((size_t)s * 64 + ci) * 1024 + token * 8
            : c3b + ((size_t)s * 192 + (ci - 64)) * 1024 + token * 8;
        half8 bf = *(const half8*)src;
#pragma unroll
        for (int t = 0; t < 12; ++t) {
            half8 af = *(const half8*)&wp[((size_t)(cc * 12 + t) * 64 + lane) * 8];
            acc[t] = __builtin_amdgcn_mfma_f32_16x16x32_f16(af, bf, acc[t], 0, 0, 0);
        }
    }
    const size_t tb = ((size_t)s * 128 + token) * 192;
#pragma unroll
    for (int t = 0; t < 12; ++t) {
        half4 hv;
#pragma unroll
        for (int r = 0; r < 4; ++r) {
            int co = t * 16 + quad * 4 + r;
            float v = acc[t][r] + bias[co];
            out[tb + co] = v;
            hv[r] = (_Float16)v;
        }
        *(half4*)&outh[tb + t * 16 + quad * 4] = hv;
    }
}

// ---------------- transformer: full batch, MFMA qk + MFMA S ----------------
__global__ __launch_bounds__(256) void transformer_mfma(
    const float* __restrict__ src, const _Float16* __restrict__ wqkp,
    const float* __restrict__ bqk, float* __restrict__ dst)
{
    __shared__ float feat[6144];
    __shared__ _Float16 uA[6400];
    __shared__ _Float16 uB[12544];
    __shared__ _Float16 zerobuf[16];
    const int b = blockIdx.x;
    const int tid = threadIdx.x;
    const int w = tid >> 6, lane = tid & 63, quad = lane >> 4, col = lane & 15;
    if (tid < 16) zerobuf[tid] = (_Float16)0.f;
    float regout[24];
    for (int i = 0; i < 4; ++i) {
        const float* srow = src + ((size_t)b * 128 + i * 32) * 192;
        for (int idx = tid; idx < 6144; idx += 256) {
            float f = (i == 0) ? srow[idx] : feat[idx] + srow[idx];
            feat[idx] = f;
            int tok = idx / 192, c = idx - tok * 192;
            uA[tok * 200 + c] = (_Float16)f;
        }
        __syncthreads();
        {
            floatx4 acc2[12];
#pragma unroll
            for (int t = 0; t < 12; ++t) acc2[t] = (floatx4){0.f, 0.f, 0.f, 0.f};
#pragma unroll
            for (int ks = 0; ks < 6; ++ks) {
                half8 a0 = *(const half8*)&uA[(col) * 200 + ks * 32 + quad * 8];
                half8 a1 = *(const half8*)&uA[(16 + col) * 200 + ks * 32 + quad * 8];
#pragma unroll
                for (int nl = 0; nl < 6; ++nl) {
                    int ntile = w * 6 + nl;
                    half8 bf = *(const half8*)&wqkp[((size_t)(ks * 24 + ntile) * 64 + lane) * 8];
                    acc2[nl] = __builtin_amdgcn_mfma_f32_16x16x32_f16(a0, bf, acc2[nl], 0, 0, 0);
                    acc2[6 + nl] = __builtin_amdgcn_mfma_f32_16x16x32_f16(a1, bf, acc2[6 + nl], 0, 0, 0);
                }
            }
            __syncthreads();
#pragma unroll
            for (int mt = 0; mt < 2; ++mt)
#pragma unroll
                for (int nl = 0; nl < 6; ++nl) {
                    int j = (w * 6 + nl) * 16 + col;
                    float bv = bqk[j];
#pragma unroll
                    for (int r = 0; r < 4; ++r) {
                        int tok = mt * 16 + quad * 4 + r;
                        uB[tok * 392 + j] = (_Float16)(acc2[mt * 6 + nl][r] + bv);
                    }
                }
            __syncthreads();
        }
        {
            const int h = w;
            floatx4 acc3[4];
#pragma unroll
            for (int t = 0; t < 4; ++t) acc3[t] = (floatx4){0.f, 0.f, 0.f, 0.f};
#pragma unroll
            for (int ks = 0; ks < 2; ++ks) {
                bool z = (ks == 1 && quad >= 2);
                const _Float16* pq0 = z ? zerobuf : &uB[(col) * 392 + h * 48 + ks * 32 + quad * 8];
                const _Float16* pq1 = z ? zerobuf : &uB[(16 + col) * 392 + h * 48 + ks * 32 + quad * 8];
                const _Float16* pk0 = z ? zerobuf : &uB[(col) * 392 + 192 + h * 48 + ks * 32 + quad * 8];
                const _Float16* pk1 = z ? zerobuf : &uB[(16 + col) * 392 + 192 + h * 48 + ks * 32 + quad * 8];
                half8 q0 = *(const half8*)pq0, q1 = *(const half8*)pq1;
                half8 k0 = *(const half8*)pk0, k1 = *(const half8*)pk1;
                acc3[0] = __builtin_amdgcn_mfma_f32_16x16x32_f16(q0, k0, acc3[0], 0, 0, 0);
                acc3[1] = __builtin_amdgcn_mfma_f32_16x16x32_f16(q0, k1, acc3[1], 0, 0, 0);
                acc3[2] = __builtin_amdgcn_mfma_f32_16x16x32_f16(q1, k0, acc3[2], 0, 0, 0);
                acc3[3] = __builtin_amdgcn_mfma_f32_16x16x32_f16(q1, k1, acc3[3], 0, 0, 0);
            }
            __syncthreads();
#pragma unroll
            for (int mt = 0; mt < 2; ++mt)
#pragma unroll
                for (int nt = 0; nt < 2; ++nt)
#pragma unroll
                    for (int r = 0; r < 4; ++r) {
                        int q = mt * 16 + quad * 4 + r;
                        int k = nt * 16 + col;
                        uA[(h * 32 + q) * 36 + k] =
                            (_Float16)(acc3[mt * 2 + nt][r] * 0.14433756729740643f);
                    }
            __syncthreads();
        }
        if (tid < 128) {
            int h = tid >> 5, qi = tid & 31;
            const _Float16* row = &uA[(h * 32 + qi) * 36];
            float lg[32];
            float mx = -1e30f;
#pragma unroll
            for (int k = 0; k < 32; ++k) { lg[k] = (float)row[k]; mx = fmaxf(mx, lg[k]); }
            float sum = 0.f;
#pragma unroll
            for (int k = 0; k < 32; ++k) { lg[k] = __expf(lg[k] - mx); sum += lg[k]; }
            float inv = 1.f / sum;
            _Float16* arow = &uB[(h * 32 + qi) * 40];
#pragma unroll
            for (int k = 0; k < 32; ++k) arow[k] = (_Float16)(lg[k] * inv);
        }
        __syncthreads();
        int cnt = 0;
        for (int idx = tid; idx < 6144; idx += 256, ++cnt) {
            int n = idx / 192, cc = idx - n * 192, h = cc / 48;
            const _Float16* arow = &uB[(h * 32 + n) * 40];
            float acc = 0.f;
#pragma unroll
            for (int j = 0; j < 32; ++j)
                acc = fmaf((float)arow[j], feat[j * 192 + cc], acc);
            regout[cnt] = acc;
        }
        __syncthreads();
        float* drow = dst + ((size_t)b * 128 + i * 32) * 192;
        cnt = 0;
        for (int idx = tid; idx < 6144; idx += 256, ++cnt) {
            feat[idx] = regout[cnt];
            drow[idx] = regout[cnt];
        }
        __syncthreads();
    }
}

// ---------------- MLP via MFMA + residual + LayerNorm ----------------
// 64 tokens/block; fc1: N=264(pad272),K=192; fc2: N=192,K=264(pad288)
__global__ __launch_bounds__(256) void mlp_mfma(
    const _Float16* __restrict__ xh,   // [65536,192] f16 (pe mirror)
    const float* __restrict__ a,       // [65536,192] residual (transformer2)
    const float* __restrict__ b1, const float* __restrict__ b2,
    const float* __restrict__ lng, const float* __restrict__ lnb,
    const _Float16* __restrict__ w1p, const _Float16* __restrict__ w2p,
    float* __restrict__ out)
{
    constexpr int HS = 296;   // h1 LDS row stride in halves (148 words -> 2-way banks)
    __shared__ _Float16 h1s[64 * HS];
    __shared__ float b1s[264], b2s[192], lgs[192], lbs[192];
    const int tid = threadIdx.x;
    const int w = tid >> 6, lane = tid & 63, quad = lane >> 4, col = lane & 15;
    const int tok0 = blockIdx.x * 64;
    const int tokl = w * 16 + col;            // 0..63 within block
    const size_t tokg = tok0 + tokl;
    // preload vectors + zero the K-pad region of h1s (cols 264..295 of each row)
    for (int i = tid; i < 264; i += 256) b1s[i] = b1[i];
    for (int i = tid; i < 192; i += 256) { b2s[i] = b2[i]; lgs[i] = lng[i]; lbs[i] = lnb[i]; }
    for (int i = tid; i < 64 * 32; i += 256) {
        int tk = i >> 5, cc2 = i & 31;
        h1s[tk * HS + 264 + cc2] = (_Float16)0.f;
    }
    __syncthreads();
    // stage 1: h1 = gelu(x @ w1 + b1)
    floatx4 acc1[17];
#pragma unroll
    for (int t = 0; t < 17; ++t) acc1[t] = (floatx4){0.f, 0.f, 0.f, 0.f};
#pragma unroll
    for (int ks = 0; ks < 6; ++ks) {
        half8 bf = *(const half8*)&xh[tokg * 192 + ks * 32 + quad * 8];
#pragma unroll
        for (int t = 0; t < 17; ++t) {
            half8 af = *(const half8*)&w1p[((size_t)(ks * 17 + t) * 64 + lane) * 8];
            acc1[t] = __builtin_amdgcn_mfma_f32_16x16x32_f16(af, bf, acc1[t], 0, 0, 0);
        }
    }
    // epilogue 1: bias + gelu -> h1s (C/D: row j = t*16+quad*4+r, col = token)
#pragma unroll
    for (int t = 0; t < 17; ++t) {
        int jb = t * 16 + quad * 4;
        if (jb >= 264) continue;
        half4 hv;
#pragma unroll
        for (int r = 0; r < 4; ++r) {
            int j = jb + r;
            float v = acc1[t][r] + b1s[j];
            hv[r] = (_Float16)(0.5f * v * (1.f + erff(v * 0.70710678118654752f)));
        }
        *(half4*)&h1s[tokl * HS + jb] = hv;
    }
    __syncthreads();
    // stage 2: y = h1 @ w2 + b2 + a, then LN
    floatx4 acc2[12];
#pragma unroll
    for (int t = 0; t < 12; ++t) acc2[t] = (floatx4){0.f, 0.f, 0.f, 0.f};
#pragma unroll
    for (int ks = 0; ks < 9; ++ks) {
        half8 bf = *(const half8*)&h1s[tokl * HS + ks * 32 + quad * 8];
#pragma unroll
        for (int t = 0; t < 12; ++t) {
            half8 af = *(const half8*)&w2p[((size_t)(ks * 12 + t) * 64 + lane) * 8];
            acc2[t] = __builtin_amdgcn_mfma_f32_16x16x32_f16(af, bf, acc2[t], 0, 0, 0);
        }
    }
    const size_t base = tokg * 192;
    float psum = 0.f;
#pragma unroll
    for (int t = 0; t < 12; ++t) {
        float4 av = *(const float4*)&a[base + t * 16 + quad * 4];
#pragma unroll
        for (int r = 0; r < 4; ++r) {
            float v = acc2[t][r] + b2s[t * 16 + quad * 4 + r];
            v += (r == 0 ? av.x : r == 1 ? av.y : r == 2 ? av.z : av.w);
            acc2[t][r] = v;
            psum += v;
        }
    }
    psum += __shfl_xor(psum, 16);
    psum += __shfl_xor(psum, 32);
    float mean = psum * (1.f / 192.f);
    float pvar = 0.f;
#pragma unroll
    for (int t = 0; t < 12; ++t)
#pragma unroll
        for (int r = 0; r < 4; ++r) {
            float d = acc2[t][r] - mean;
            pvar = fmaf(d, d, pvar);
        }
    pvar += __shfl_xor(pvar, 16);
    pvar += __shfl_xor(pvar, 32);
    float rsd = rsqrtf(pvar * (1.f / 192.f) + 1e-5f);
#pragma unroll
    for (int t = 0; t < 12; ++t) {
        float4 ov;
#pragma unroll
        for (int r = 0; r < 4; ++r) {
            int c = t * 16 + quad * 4 + r;
            float o = (acc2[t][r] - mean) * rsd * lgs[c] + lbs[c];
            (r == 0 ? ov.x : r == 1 ? ov.y : r == 2 ? ov.z : ov.w) = o;
        }
        *(float4*)&out[base + t * 16 + quad * 4] = ov;
    }
}

// ---------------- mean + classifier head ----------------
__global__ __launch_bounds__(192) void head_kernel(
    const float* __restrict__ ln, const float* __restrict__ wcls,
    const float* __restrict__ bcls, float* __restrict__ out)
{
    __shared__ float mean[192];
    const int b = blockIdx.x;
    const int c = threadIdx.x;
    float s = 0.f;
    for (int n = 0; n < 128; ++n) s += ln[((size_t)b * 128 + n) * 192 + c];
    mean[c] = s * (1.f / 128.f);
    __syncthreads();
    if (c < 3) {
        float acc = bcls[c];
        for (int k = 0; k < 192; ++k) acc = fmaf(mean[k], wcls[k * 3 + c], acc);
        out[b * 3 + c] = acc;
    }
}

static const int SZ_DICT[41] = {
    920576, 3682304, 2048, 960, 64, 64, 64, 64, 64,
    73728, 128, 128, 128, 128, 128,
    81920, 128, 128, 128, 128, 128,
    73728, 192, 192, 192, 192, 192,
    393216, 192,
    73728, 384, 73728, 384,
    50688, 264, 50688, 192,
    192, 192, 576, 3};

extern "C" void kernel_launch(void* const* d_in, const int* in_sizes, int n_in,
                              void* d_out, int out_size, void* d_ws, size_t ws_size,
                              hipStream_t stream) {
    if (n_in != 41) {
        fill_const<<<(out_size + 255) / 256, 256, 0, stream>>>((float*)d_out, out_size, 200.f);
        return;
    }
    bool mA = true;
    for (int i = 0; i < 41; ++i) mA = mA && (in_sizes[i] == SZ_DICT[i]);
    if (!mA) {
        fill_const<<<(out_size + 255) / 256, 256, 0, stream>>>((float*)d_out, out_size, 100.f);
        return;
    }
    const float* P[41];
    for (int i = 0; i < 41; ++i) P[i] = (const float*)d_in[i];

    // layout: [peb 50.3][tokA 50.3][tokB 50.3][pebh 25.2][wpack 2 MB]
    const size_t TOK = (size_t)512 * 128 * 192 * 4;
    const size_t TOKH = (size_t)512 * 128 * 192 * 2;
    const size_t WPACK = 2097152;
    if (3 * TOK + TOKH + WPACK > ws_size) {
        fill_const<<<(out_size + 255) / 256, 256, 0, stream>>>((float*)d_out, out_size, 50.f);
        return;
    }
    char* ws = (char*)d_ws;
    float* peb = (float*)ws;
    char*  tokA = ws + TOK;
    char*  tokB = tokA + TOK;
    _Float16* pebh = (_Float16*)(tokB + TOK);
    char*  wpk = (char*)pebh + TOKH;

    const int BcC = 128;  // conv chunk scratch = tokA+tokB exactly
    _Float16* c0b = (_Float16*)tokA;
    char*     u1  = tokA + (size_t)BcC * 131072;
    char*     u2  = u1 + (size_t)BcC * 393216;
    _Float16* adjb = (_Float16*)u1;
    _Float16* c1b  = (_Float16*)u1;
    _Float16* c2b  = (_Float16*)u2;
    _Float16* c3b  = (_Float16*)u1;
    float* t1b = (float*)tokA;
    float* t2b = (float*)tokB;
    float* lnbuf = (float*)tokA;

    _Float16* w1p  = (_Float16*)wpk;        // 73728
    _Float16* w2p  = w1p + 73728;           // 81920
    _Float16* w3p  = w2p + 81920;           // 73728
    _Float16* wpep = w3p + 73728;           // 393216
    _Float16* wq0p = wpep + 393216;         // 73728
    _Float16* wq1p = wq0p + 73728;          // 73728
    _Float16* wm1p = wq1p + 73728;          // 52224
    _Float16* wm2p = wm1p + 52224;          // 55296

    pack_w<<<288, 256, 0, stream>>>(P[9],  w1p, 64, 9, 128);
    pack_w<<<320, 256, 0, stream>>>(P[15], w2p, 128, 5, 128);
    pack_w<<<288, 256, 0, stream>>>(P[21], w3p, 128, 3, 192);
    pack_pe<<<1536, 256, 0, stream>>>(P[27], wpep);
    pack_qk<<<288, 256, 0, stream>>>(P[29], wq0p);
    pack_qk<<<288, 256, 0, stream>>>(P[31], wq1p);
    pack_mlp1<<<204, 256, 0, stream>>>(P[33], wm1p);
    pack_mlp2<<<216, 256, 0, stream>>>(P[35], wm2p);

    for (int c = 0; c < 4; ++c) {
        const size_t b0 = (size_t)c * BcC;
        adj_kernel<<<BcC * 2, 256, 0, stream>>>(P[0] + b0 * 1798, P[1], P[2], adjb);
        c0_kernel<<<BcC * 256, 256, 0, stream>>>(adjb, P[3], P[4],
                                                 P[5], P[6], P[7], P[8], c0b);
        conv_mfma<64, 9, 4, 128><<<BcC * 16, 256, 0, stream>>>(c0b, w1p, P[10],
                                                 P[11], P[12], P[13], P[14], c1b);
        conv_mfma<128, 5, 2, 128><<<BcC * 16, 256, 0, stream>>>(c1b, w2p, P[16],
                                                 P[17], P[18], P[19], P[20], c2b);
        conv_mfma<128, 3, 1, 192><<<BcC * 16, 256, 0, stream>>>(c2b, w3p, P[22],
                                                 P[23], P[24], P[25], P[26], c3b);
        pe_mfma<<<BcC * 2, 256, 0, stream>>>(c0b, c3b, wpep, P[28],
                                             peb + b0 * 128 * 192,
                                             pebh + b0 * 128 * 192);
    }
    transformer_mfma<<<512, 256, 0, stream>>>(peb, wq0p, P[30], t1b);
    transformer_mfma<<<512, 256, 0, stream>>>(t1b, wq1p, P[32], t2b);
    mlp_mfma<<<1024, 256, 0, stream>>>(pebh, t2b, P[34], P[36],
                                       P[37], P[38], wm1p, wm2p, lnbuf);
    head_kernel<<<512, 192, 0, stream>>>(lnbuf, P[39], P[40], (float*)d_out);
}

// Round 14
// 2279.495 us; speedup vs baseline: 31.8073x; 1.5657x over previous
//
#include <hip/hip_runtime.h>
#include <hip/hip_bf16.h>
#include <hip/hip_fp16.h>
#include <cstddef>

typedef _Float16 half8 __attribute__((ext_vector_type(8)));
typedef _Float16 half4 __attribute__((ext_vector_type(4)));
typedef float floatx4 __attribute__((ext_vector_type(4)));

__global__ __launch_bounds__(256) void fill_const(float* out, int n, float v) {
    int i = blockIdx.x * 256 + threadIdx.x;
    if (i < n) out[i] = v;
}

// ---------------- pack conv weights into MFMA A-frag order ----------------
__global__ __launch_bounds__(256) void pack_w(
    const float* __restrict__ w, _Float16* __restrict__ out,
    int CIN, int K, int COUT)
{
    int NT = COUT >> 4, NCC = CIN >> 5;
    int total = K * CIN * COUT;
    int idx = blockIdx.x * 256 + threadIdx.x;
    if (idx >= total) return;
    int j = idx & 7, lane = (idx >> 3) & 63, f = idx >> 9;
    int t = f % NT, cc = (f / NT) % NCC, k = f / (NT * NCC);
    int co = t * 16 + (lane & 15);
    int ci = cc * 32 + (lane >> 4) * 8 + j;
    out[idx] = (_Float16)w[(co * CIN + ci) * K + k];
}

// ---------------- pack pe weights [192][2048] -> frags f = cc*12 + t ----------------
__global__ __launch_bounds__(256) void pack_pe(
    const float* __restrict__ w, _Float16* __restrict__ out)
{
    int idx = blockIdx.x * 256 + threadIdx.x;
    if (idx >= 393216) return;
    int j = idx & 7, lane = (idx >> 3) & 63, f = idx >> 9;
    int t = f % 12, cc = f / 12;
    int co = t * 16 + (lane & 15);
    int r = cc * 32 + (lane >> 4) * 8 + j;
    out[idx] = (_Float16)w[co * 2048 + r];
}

// ---------------- pack wqk [192][384] -> B-frags f = ks*24 + ntile ----------------
__global__ __launch_bounds__(256) void pack_qk(
    const float* __restrict__ w, _Float16* __restrict__ out)
{
    int idx = blockIdx.x * 256 + threadIdx.x;
    if (idx >= 73728) return;
    int j = idx & 7, lane = (idx >> 3) & 63, f = idx >> 9;
    int nt = f % 24, ks = f / 24;
    int c = ks * 32 + (lane >> 4) * 8 + j;
    int jcol = nt * 16 + (lane & 15);
    out[idx] = (_Float16)w[c * 384 + jcol];
}

// ---------------- pack w_fc1 [192][264] -> A-frags (N pad 272) ----------------
__global__ __launch_bounds__(256) void pack_mlp1(
    const float* __restrict__ w, _Float16* __restrict__ out)
{
    int idx = blockIdx.x * 256 + threadIdx.x;
    if (idx >= 52224) return;
    int j = idx & 7, lane = (idx >> 3) & 63, f = idx >> 9;
    int t = f % 17, ks = f / 17;
    int jcol = t * 16 + (lane & 15);
    int c = ks * 32 + (lane >> 4) * 8 + j;
    out[idx] = (jcol < 264) ? (_Float16)w[c * 264 + jcol] : (_Float16)0.f;
}

// ---------------- pack w_fc2 [264][192] -> A-frags (K pad 288) ----------------
__global__ __launch_bounds__(256) void pack_mlp2(
    const float* __restrict__ w, _Float16* __restrict__ out)
{
    int idx = blockIdx.x * 256 + threadIdx.x;
    if (idx >= 55296) return;
    int j = idx & 7, lane = (idx >> 3) & 63, f = idx >> 9;
    int t = f % 12, ks = f / 12;
    int co = t * 16 + (lane & 15);
    int k = ks * 32 + (lane >> 4) * 8 + j;
    out[idx] = (k < 264) ? (_Float16)w[k * 192 + co] : (_Float16)0.f;
}

// ---------------- pack w_adj [1798][2048] -> A-frags, K pad 1824 (57 segs) ----------------
// f = ks*128 + t ; jcol = t*16 + (lane&15) ; k = ks*32 + (lane>>4)*8 + j
__global__ __launch_bounds__(256) void pack_adjw(
    const float* __restrict__ w, _Float16* __restrict__ out)
{
    int idx = blockIdx.x * 256 + threadIdx.x;
    if (idx >= 3735552) return;
    int j = idx & 7, lane = (idx >> 3) & 63, f = idx >> 9;
    int t = f & 127, ks = f >> 7;
    int jcol = t * 16 + (lane & 15);
    int k = ks * 32 + (lane >> 4) * 8 + j;
    out[idx] = (k < 1798) ? (_Float16)w[(size_t)k * 2048 + jcol] : (_Float16)0.f;
}

// ---------------- x [512][1798] f32 -> xh [512][1824] f16 (zero-padded) ----------------
__global__ __launch_bounds__(256) void pad_x(
    const float* __restrict__ x, _Float16* __restrict__ xh)
{
    int idx = blockIdx.x * 256 + threadIdx.x;
    if (idx >= 512 * 1824) return;
    int b = idx / 1824, k = idx - b * 1824;
    xh[idx] = (k < 1798) ? (_Float16)x[(size_t)b * 1798 + k] : (_Float16)0.f;
}

// ---------------- adj via MFMA: M=512 samples, N=2048, K=1824 ----------------
__global__ __launch_bounds__(256) void adj_mfma(
    const _Float16* __restrict__ xh,   // [512][1824]
    const _Float16* __restrict__ wp,   // packed A-frags
    const float* __restrict__ bias, _Float16* __restrict__ out)  // [512][2048]
{
    const int tid = threadIdx.x;
    const int w = tid >> 6, lane = tid & 63, quad = lane >> 4, col = lane & 15;
    const int bm = blockIdx.x >> 4;    // 8 m-blocks of 64 samples
    const int bn = blockIdx.x & 15;    // 16 n-blocks of 128 cols
    const int sample = bm * 64 + w * 16 + col;
    floatx4 acc[8];
#pragma unroll
    for (int t = 0; t < 8; ++t) acc[t] = (floatx4){0.f, 0.f, 0.f, 0.f};
    for (int ks = 0; ks < 57; ++ks) {
        half8 bf = *(const half8*)&xh[(size_t)sample * 1824 + ks * 32 + quad * 8];
#pragma unroll
        for (int tt = 0; tt < 8; ++tt) {
            int f = ks * 128 + bn * 8 + tt;
            half8 af = *(const half8*)&wp[((size_t)f * 64 + lane) * 8];
            acc[tt] = __builtin_amdgcn_mfma_f32_16x16x32_f16(af, bf, acc[tt], 0, 0, 0);
        }
    }
#pragma unroll
    for (int tt = 0; tt < 8; ++tt) {
        int jb = (bn * 8 + tt) * 16 + quad * 4;
        half4 hv;
#pragma unroll
        for (int r = 0; r < 4; ++r)
            hv[r] = (_Float16)(acc[tt][r] + bias[jb + r]);
        *(half4*)&out[(size_t)sample * 2048 + jb] = hv;
    }
}

// ---------------- c0: conv (1->64, K15, s2, p7) + BN + ReLU, LDS-staged ----------------
__global__ __launch_bounds__(256) void c0_tiled(
    const _Float16* __restrict__ in,   // chunk base [Bc][2048]
    const float* __restrict__ w,
    const float* __restrict__ cb, const float* __restrict__ g,
    const float* __restrict__ bb, const float* __restrict__ m,
    const float* __restrict__ vv, _Float16* __restrict__ out)  // [Bc,64,1024]
{
    __shared__ _Float16 sin[544];
    __shared__ float wf[960], sc[64], sh[64];
    const int tid = threadIdx.x;
    const int bl = blockIdx.x >> 2;
    const int l0 = (blockIdx.x & 3) * 256;
    for (int i = tid; i < 960; i += 256) wf[i] = w[i];
    if (tid < 64) {
        float s = g[tid] * rsqrtf(vv[tid] + 1e-5f);
        sc[tid] = s;
        sh[tid] = (cb[tid] - m[tid]) * s + bb[tid];
    }
    const int base = 2 * l0 - 7;
    for (int i = tid; i < 528; i += 256) {
        int pos = base + i;
        sin[i] = (pos >= 0 && pos < 2048) ? in[(size_t)bl * 2048 + pos] : (_Float16)0.f;
    }
    __syncthreads();
    const int l = l0 + tid;
    const int s0 = 2 * tid;
    for (int co = 0; co < 64; ++co) {
        const float* wk = &wf[co * 15];
        float acc = 0.f;
#pragma unroll
        for (int k = 0; k < 15; ++k)
            acc = fmaf((float)sin[s0 + k], wk[k], acc);
        out[((size_t)bl * 64 + co) * 1024 + l] = (_Float16)fmaxf(fmaf(acc, sc[co], sh[co]), 0.f);
    }
}

// ---------------- conv via MFMA ----------------
template <int CIN, int K, int PAD, int COUT>
__global__ __launch_bounds__(256) void conv_mfma(
    const _Float16* __restrict__ in, const _Float16* __restrict__ wp,
    const float* __restrict__ cb, const float* __restrict__ g,
    const float* __restrict__ bb, const float* __restrict__ m,
    const float* __restrict__ vv, _Float16* __restrict__ out)
{
    constexpr int STRIDE = (CIN == 64) ? 72 : 152;
    constexpr int SPAN = 64 + K - 1;
    constexpr int NCC = CIN / 32, NT = COUT / 16;
    __shared__ _Float16 tin[SPAN * STRIDE];
    __shared__ float sc[COUT], sh[COUT];
    const int tid = threadIdx.x;
    const int b = blockIdx.x >> 4;
    const int l0b = (blockIdx.x & 15) * 64;
    for (int c = tid; c < COUT; c += 256) {
        float s = g[c] * rsqrtf(vv[c] + 1e-5f);
        sc[c] = s;
        sh[c] = (cb[c] - m[c]) * s + bb[c];
    }
    for (int idx = tid; idx < CIN * SPAN; idx += 256) {
        int ci = idx / SPAN, p = idx - ci * SPAN;
        int pos = l0b + p - PAD;
        _Float16 v = (_Float16)0.f;
        if (pos >= 0 && pos < 1024) v = in[((size_t)b * CIN + ci) * 1024 + pos];
        tin[p * STRIDE + ci] = v;
    }
    __syncthreads();
    const int lane = tid & 63, wave = tid >> 6;
    const int quad = lane >> 4, n = lane & 15;
    const int lrow0 = wave * 16 + n;
    floatx4 acc[NT];
#pragma unroll
    for (int t = 0; t < NT; ++t) acc[t] = (floatx4){0.f, 0.f, 0.f, 0.f};
#pragma unroll
    for (int k = 0; k < K; ++k) {
#pragma unroll
        for (int cc = 0; cc < NCC; ++cc) {
            half8 bfrag = *(const half8*)&tin[(lrow0 + k) * STRIDE + cc * 32 + quad * 8];
#pragma unroll
            for (int t = 0; t < NT; ++t) {
                int f = (k * NCC + cc) * NT + t;
                half8 afrag = *(const half8*)&wp[((size_t)f * 64 + lane) * 8];
                acc[t] = __builtin_amdgcn_mfma_f32_16x16x32_f16(afrag, bfrag, acc[t], 0, 0, 0);
            }
        }
    }
    const int lg = l0b + wave * 16 + n;
#pragma unroll
    for (int t = 0; t < NT; ++t)
#pragma unroll
        for (int r = 0; r < 4; ++r) {
            int co = t * 16 + quad * 4 + r;
            float v = fmaxf(fmaf(acc[t][r], sc[co], sh[co]), 0.f);
            out[((size_t)b * COUT + co) * 1024 + lg] = (_Float16)v;
        }
}

// ---------------- pe via MFMA; emits f32 + f16 mirror ----------------
__global__ __launch_bounds__(256) void pe_mfma(
    const _Float16* __restrict__ c0b, const _Float16* __restrict__ c3b,
    const _Float16* __restrict__ wp, const float* __restrict__ bias,
    float* __restrict__ out, _Float16* __restrict__ outh)
{
    const int tid = threadIdx.x;
    const int w = tid >> 6, lane = tid & 63, quad = lane >> 4, col = lane & 15;
    const int s = blockIdx.x >> 1;
    const int n0 = (blockIdx.x & 1) * 64;
    const int token = n0 + w * 16 + col;
    floatx4 acc[12];
#pragma unroll
    for (int t = 0; t < 12; ++t) acc[t] = (floatx4){0.f, 0.f, 0.f, 0.f};
    for (int cc = 0; cc < 64; ++cc) {
        int ci = cc * 4 + quad;
        const _Float16* src = (ci < 64)
            ? c0b + ((size_t)s * 64 + ci) * 1024 + token * 8
            : c3b + ((size_t)s * 192 + (ci - 64)) * 1024 + token * 8;
        half8 bf = *(const half8*)src;
#pragma unroll
        for (int t = 0; t < 12; ++t) {
            half8 af = *(const half8*)&wp[((size_t)(cc * 12 + t) * 64 + lane) * 8];
            acc[t] = __builtin_amdgcn_mfma_f32_16x16x32_f16(af, bf, acc[t], 0, 0, 0);
        }
    }
    const size_t tb = ((size_t)s * 128 + token) * 192;
#pragma unroll
    for (int t = 0; t < 12; ++t) {
        half4 hv;
#pragma unroll
        for (int r = 0; r < 4; ++r) {
            int co = t * 16 + quad * 4 + r;
            float v = acc[t][r] + bias[co];
            out[tb + co] = v;
            hv[r] = (_Float16)v;
        }
        *(half4*)&outh[tb + t * 16 + quad * 4] = hv;
    }
}

// ---------------- transformer: full batch, MFMA qk + MFMA S ----------------
__global__ __launch_bounds__(256) void transformer_mfma(
    const float* __restrict__ src, const _Float16* __restrict__ wqkp,
    const float* __restrict__ bqk, float* __restrict__ dst)
{
    __shared__ float feat[6144];
    __shared__ _Float16 uA[6400];
    __shared__ _Float16 uB[12544];
    __shared__ _Float16 zerobuf[16];
    const int b = blockIdx.x;
    const int tid = threadIdx.x;
    const int w = tid >> 6, lane = tid & 63, quad = lane >> 4, col = lane & 15;
    if (tid < 16) zerobuf[tid] = (_Float16)0.f;
    float regout[24];
    for (int i = 0; i < 4; ++i) {
        const float* srow = src + ((size_t)b * 128 + i * 32) * 192;
        for (int idx = tid; idx < 6144; idx += 256) {
            float f = (i == 0) ? srow[idx] : feat[idx] + srow[idx];
            feat[idx] = f;
            int tok = idx / 192, c = idx - tok * 192;
            uA[tok * 200 + c] = (_Float16)f;
        }
        __syncthreads();
        {
            floatx4 acc2[12];
#pragma unroll
            for (int t = 0; t < 12; ++t) acc2[t] = (floatx4){0.f, 0.f, 0.f, 0.f};
#pragma unroll
            for (int ks = 0; ks < 6; ++ks) {
                half8 a0 = *(const half8*)&uA[(col) * 200 + ks * 32 + quad * 8];
                half8 a1 = *(const half8*)&uA[(16 + col) * 200 + ks * 32 + quad * 8];
#pragma unroll
                for (int nl = 0; nl < 6; ++nl) {
                    int ntile = w * 6 + nl;
                    half8 bf = *(const half8*)&wqkp[((size_t)(ks * 24 + ntile) * 64 + lane) * 8];
                    acc2[nl] = __builtin_amdgcn_mfma_f32_16x16x32_f16(a0, bf, acc2[nl], 0, 0, 0);
                    acc2[6 + nl] = __builtin_amdgcn_mfma_f32_16x16x32_f16(a1, bf, acc2[6 + nl], 0, 0, 0);
                }
            }
            __syncthreads();
#pragma unroll
            for (int mt = 0; mt < 2; ++mt)
#pragma unroll
                for (int nl = 0; nl < 6; ++nl) {
                    int j = (w * 6 + nl) * 16 + col;
                    float bv = bqk[j];
#pragma unroll
                    for (int r = 0; r < 4; ++r) {
                        int tok = mt * 16 + quad * 4 + r;
                        uB[tok * 392 + j] = (_Float16)(acc2[mt * 6 + nl][r] + bv);
                    }
                }
            __syncthreads();
        }
        {
            const int h = w;
            floatx4 acc3[4];
#pragma unroll
            for (int t = 0; t < 4; ++t) acc3[t] = (floatx4){0.f, 0.f, 0.f, 0.f};
#pragma unroll
            for (int ks = 0; ks < 2; ++ks) {
                bool z = (ks == 1 && quad >= 2);
                const _Float16* pq0 = z ? zerobuf : &uB[(col) * 392 + h * 48 + ks * 32 + quad * 8];
                const _Float16* pq1 = z ? zerobuf : &uB[(16 + col) * 392 + h * 48 + ks * 32 + quad * 8];
                const _Float16* pk0 = z ? zerobuf : &uB[(col) * 392 + 192 + h * 48 + ks * 32 + quad * 8];
                const _Float16* pk1 = z ? zerobuf : &uB[(16 + col) * 392 + 192 + h * 48 + ks * 32 + quad * 8];
                half8 q0 = *(const half8*)pq0, q1 = *(const half8*)pq1;
                half8 k0 = *(const half8*)pk0, k1 = *(const half8*)pk1;
                acc3[0] = __builtin_amdgcn_mfma_f32_16x16x32_f16(q0, k0, acc3[0], 0, 0, 0);
                acc3[1] = __builtin_amdgcn_mfma_f32_16x16x32_f16(q0, k1, acc3[1], 0, 0, 0);
                acc3[2] = __builtin_amdgcn_mfma_f32_16x16x32_f16(q1, k0, acc3[2], 0, 0, 0);
                acc3[3] = __builtin_amdgcn_mfma_f32_16x16x32_f16(q1, k1, acc3[3], 0, 0, 0);
            }
            __syncthreads();
#pragma unroll
            for (int mt = 0; mt < 2; ++mt)
#pragma unroll
                for (int nt = 0; nt < 2; ++nt)
#pragma unroll
                    for (int r = 0; r < 4; ++r) {
                        int q = mt * 16 + quad * 4 + r;
                        int k = nt * 16 + col;
                        uA[(h * 32 + q) * 36 + k] =
                            (_Float16)(acc3[mt * 2 + nt][r] * 0.14433756729740643f);
                    }
            __syncthreads();
        }
        if (tid < 128) {
            int h = tid >> 5, qi = tid & 31;
            const _Float16* row = &uA[(h * 32 + qi) * 36];
            float lg[32];
            float mx = -1e30f;
#pragma unroll
            for (int k = 0; k < 32; ++k) { lg[k] = (float)row[k]; mx = fmaxf(mx, lg[k]); }
            float sum = 0.f;
#pragma unroll
            for (int k = 0; k < 32; ++k) { lg[k] = __expf(lg[k] - mx); sum += lg[k]; }
            float inv = 1.f / sum;
            _Float16* arow = &uB[(h * 32 + qi) * 40];
#pragma unroll
            for (int k = 0; k < 32; ++k) arow[k] = (_Float16)(lg[k] * inv);
        }
        __syncthreads();
        int cnt = 0;
        for (int idx = tid; idx < 6144; idx += 256, ++cnt) {
            int n = idx / 192, cc = idx - n * 192, h = cc / 48;
            const _Float16* arow = &uB[(h * 32 + n) * 40];
            float acc = 0.f;
#pragma unroll
            for (int j = 0; j < 32; ++j)
                acc = fmaf((float)arow[j], feat[j * 192 + cc], acc);
            regout[cnt] = acc;
        }
        __syncthreads();
        float* drow = dst + ((size_t)b * 128 + i * 32) * 192;
        cnt = 0;
        for (int idx = tid; idx < 6144; idx += 256, ++cnt) {
            feat[idx] = regout[cnt];
            drow[idx] = regout[cnt];
        }
        __syncthreads();
    }
}

// ---------------- MLP via MFMA + residual + LayerNorm ----------------
__global__ __launch_bounds__(256) void mlp_mfma(
    const _Float16* __restrict__ xh, const float* __restrict__ a,
    const float* __restrict__ b1, const float* __restrict__ b2,
    const float* __restrict__ lng, const float* __restrict__ lnb,
    const _Float16* __restrict__ w1p, const _Float16* __restrict__ w2p,
    float* __restrict__ out)
{
    constexpr int HS = 296;
    __shared__ _Float16 h1s[64 * HS];
    __shared__ float b1s[264], b2s[192], lgs[192], lbs[192];
    const int tid = threadIdx.x;
    const int w = tid >> 6, lane = tid & 63, quad = lane >> 4, col = lane & 15;
    const int tok0 = blockIdx.x * 64;
    const int tokl = w * 16 + col;
    const size_t tokg = tok0 + tokl;
    for (int i = tid; i < 264; i += 256) b1s[i] = b1[i];
    for (int i = tid; i < 192; i += 256) { b2s[i] = b2[i]; lgs[i] = lng[i]; lbs[i] = lnb[i]; }
    for (int i = tid; i < 64 * 32; i += 256) {
        int tk = i >> 5, cc2 = i & 31;
        h1s[tk * HS + 264 + cc2] = (_Float16)0.f;
    }
    __syncthreads();
    floatx4 acc1[17];
#pragma unroll
    for (int t = 0; t < 17; ++t) acc1[t] = (floatx4){0.f, 0.f, 0.f, 0.f};
#pragma unroll
    for (int ks = 0; ks < 6; ++ks) {
        half8 bf = *(const half8*)&xh[tokg * 192 + ks * 32 + quad * 8];
#pragma unroll
        for (int t = 0; t < 17; ++t) {
            half8 af = *(const half8*)&w1p[((size_t)(ks * 17 + t) * 64 + lane) * 8];
            acc1[t] = __builtin_amdgcn_mfma_f32_16x16x32_f16(af, bf, acc1[t], 0, 0, 0);
        }
    }
#pragma unroll
    for (int t = 0; t < 17; ++t) {
        int jb = t * 16 + quad * 4;
        if (jb >= 264) continue;
        half4 hv;
#pragma unroll
        for (int r = 0; r < 4; ++r) {
            int j = jb + r;
            float v = acc1[t][r] + b1s[j];
            hv[r] = (_Float16)(0.5f * v * (1.f + erff(v * 0.70710678118654752f)));
        }
        *(half4*)&h1s[tokl * HS + jb] = hv;
    }
    __syncthreads();
    floatx4 acc2[12];
#pragma unroll
    for (int t = 0; t < 12; ++t) acc2[t] = (floatx4){0.f, 0.f, 0.f, 0.f};
#pragma unroll
    for (int ks = 0; ks < 9; ++ks) {
        half8 bf = *(const half8*)&h1s[tokl * HS + ks * 32 + quad * 8];
#pragma unroll
        for (int t = 0; t < 12; ++t) {
            half8 af = *(const half8*)&w2p[((size_t)(ks * 12 + t) * 64 + lane) * 8];
            acc2[t] = __builtin_amdgcn_mfma_f32_16x16x32_f16(af, bf, acc2[t], 0, 0, 0);
        }
    }
    const size_t base = tokg * 192;
    float psum = 0.f;
#pragma unroll
    for (int t = 0; t < 12; ++t) {
        float4 av = *(const float4*)&a[base + t * 16 + quad * 4];
#pragma unroll
        for (int r = 0; r < 4; ++r) {
            float v = acc2[t][r] + b2s[t * 16 + quad * 4 + r];
            v += (r == 0 ? av.x : r == 1 ? av.y : r == 2 ? av.z : av.w);
            acc2[t][r] = v;
            psum += v;
        }
    }
    psum += __shfl_xor(psum, 16);
    psum += __shfl_xor(psum, 32);
    float mean = psum * (1.f / 192.f);
    float pvar = 0.f;
#pragma unroll
    for (int t = 0; t < 12; ++t)
#pragma unroll
        for (int r = 0; r < 4; ++r) {
            float d = acc2[t][r] - mean;
            pvar = fmaf(d, d, pvar);
        }
    pvar += __shfl_xor(pvar, 16);
    pvar += __shfl_xor(pvar, 32);
    float rsd = rsqrtf(pvar * (1.f / 192.f) + 1e-5f);
#pragma unroll
    for (int t = 0; t < 12; ++t) {
        float4 ov;
#pragma unroll
        for (int r = 0; r < 4; ++r) {
            int c = t * 16 + quad * 4 + r;
            float o = (acc2[t][r] - mean) * rsd * lgs[c] + lbs[c];
            (r == 0 ? ov.x : r == 1 ? ov.y : r == 2 ? ov.z : ov.w) = o;
        }
        *(float4*)&out[base + t * 16 + quad * 4] = ov;
    }
}

// ---------------- mean + classifier head ----------------
__global__ __launch_bounds__(192) void head_kernel(
    const float* __restrict__ ln, const float* __restrict__ wcls,
    const float* __restrict__ bcls, float* __restrict__ out)
{
    __shared__ float mean[192];
    const int b = blockIdx.x;
    const int c = threadIdx.x;
    float s = 0.f;
    for (int n = 0; n < 128; ++n) s += ln[((size_t)b * 128 + n) * 192 + c];
    mean[c] = s * (1.f / 128.f);
    __syncthreads();
    if (c < 3) {
        float acc = bcls[c];
        for (int k = 0; k < 192; ++k) acc = fmaf(mean[k], wcls[k * 3 + c], acc);
        out[b * 3 + c] = acc;
    }
}

static const int SZ_DICT[41] = {
    920576, 3682304, 2048, 960, 64, 64, 64, 64, 64,
    73728, 128, 128, 128, 128, 128,
    81920, 128, 128, 128, 128, 128,
    73728, 192, 192, 192, 192, 192,
    393216, 192,
    73728, 384, 73728, 384,
    50688, 264, 50688, 192,
    192, 192, 576, 3};

extern "C" void kernel_launch(void* const* d_in, const int* in_sizes, int n_in,
                              void* d_out, int out_size, void* d_ws, size_t ws_size,
                              hipStream_t stream) {
    if (n_in != 41) {
        fill_const<<<(out_size + 255) / 256, 256, 0, stream>>>((float*)d_out, out_size, 200.f);
        return;
    }
    bool mA = true;
    for (int i = 0; i < 41; ++i) mA = mA && (in_sizes[i] == SZ_DICT[i]);
    if (!mA) {
        fill_const<<<(out_size + 255) / 256, 256, 0, stream>>>((float*)d_out, out_size, 100.f);
        return;
    }
    const float* P[41];
    for (int i = 0; i < 41; ++i) P[i] = (const float*)d_in[i];

    // layout: [peb 50.3][tokA 50.3][tokB 50.3][pebh 25.2][wpack 2][adjfull 2.1]
    const size_t TOK = (size_t)512 * 128 * 192 * 4;
    const size_t TOKH = (size_t)512 * 128 * 192 * 2;
    const size_t WPACK = 2097152;
    const size_t ADJF = (size_t)512 * 2048 * 2;
    if (3 * TOK + TOKH + WPACK + ADJF > ws_size) {
        fill_const<<<(out_size + 255) / 256, 256, 0, stream>>>((float*)d_out, out_size, 50.f);
        return;
    }
    char* ws = (char*)d_ws;
    float* peb = (float*)ws;
    char*  tokA = ws + TOK;
    char*  tokB = tokA + TOK;
    _Float16* pebh = (_Float16*)(tokB + TOK);
    char*  wpk = (char*)pebh + TOKH;
    _Float16* adjfull = (_Float16*)(wpk + WPACK);   // [512][2048] f16

    // transient (stream-ordered before pe writes peb): packed adj weights + padded x
    _Float16* wadjp = (_Float16*)peb;               // 3,735,552 halves = 7.47 MB
    _Float16* xpad  = wadjp + 3735552;              // 933,888 halves = 1.87 MB

    const int BcC = 128;
    _Float16* c0b = (_Float16*)tokA;
    char*     u1  = tokA + (size_t)BcC * 131072;
    char*     u2  = u1 + (size_t)BcC * 393216;
    _Float16* c1b  = (_Float16*)u1;
    _Float16* c2b  = (_Float16*)u2;
    _Float16* c3b  = (_Float16*)u1;
    float* t1b = (float*)tokA;
    float* t2b = (float*)tokB;
    float* lnbuf = (float*)tokA;

    _Float16* w1p  = (_Float16*)wpk;        // 73728
    _Float16* w2p  = w1p + 73728;           // 81920
    _Float16* w3p  = w2p + 81920;           // 73728
    _Float16* wpep = w3p + 73728;           // 393216
    _Float16* wq0p = wpep + 393216;         // 73728
    _Float16* wq1p = wq0p + 73728;          // 73728
    _Float16* wm1p = wq1p + 73728;          // 52224
    _Float16* wm2p = wm1p + 52224;          // 55296

    pack_w<<<288, 256, 0, stream>>>(P[9],  w1p, 64, 9, 128);
    pack_w<<<320, 256, 0, stream>>>(P[15], w2p, 128, 5, 128);
    pack_w<<<288, 256, 0, stream>>>(P[21], w3p, 128, 3, 192);
    pack_pe<<<1536, 256, 0, stream>>>(P[27], wpep);
    pack_qk<<<288, 256, 0, stream>>>(P[29], wq0p);
    pack_qk<<<288, 256, 0, stream>>>(P[31], wq1p);
    pack_mlp1<<<204, 256, 0, stream>>>(P[33], wm1p);
    pack_mlp2<<<216, 256, 0, stream>>>(P[35], wm2p);
    pack_adjw<<<14592, 256, 0, stream>>>(P[1], wadjp);
    pad_x<<<3648, 256, 0, stream>>>(P[0], xpad);

    adj_mfma<<<128, 256, 0, stream>>>(xpad, wadjp, P[2], adjfull);

    for (int c = 0; c < 4; ++c) {
        const size_t b0 = (size_t)c * BcC;
        c0_tiled<<<BcC * 4, 256, 0, stream>>>(adjfull + b0 * 2048, P[3], P[4],
                                              P[5], P[6], P[7], P[8], c0b);
        conv_mfma<64, 9, 4, 128><<<BcC * 16, 256, 0, stream>>>(c0b, w1p, P[10],
                                                 P[11], P[12], P[13], P[14], c1b);
        conv_mfma<128, 5, 2, 128><<<BcC * 16, 256, 0, stream>>>(c1b, w2p, P[16],
                                                 P[17], P[18], P[19], P[20], c2b);
        conv_mfma<128, 3, 1, 192><<<BcC * 16, 256, 0, stream>>>(c2b, w3p, P[22],
                                                 P[23], P[24], P[25], P[26], c3b);
        pe_mfma<<<BcC * 2, 256, 0, stream>>>(c0b, c3b, wpep, P[28],
                                             peb + b0 * 128 * 192,
                                             pebh + b0 * 128 * 192);
    }
    transformer_mfma<<<512, 256, 0, stream>>>(peb, wq0p, P[30], t1b);
    transformer_mfma<<<512, 256, 0, stream>>>(t1b, wq1p, P[32], t2b);
    mlp_mfma<<<1024, 256, 0, stream>>>(pebh, t2b, P[34], P[36],
                                       P[37], P[38], wm1p, wm2p, lnbuf);
    head_kernel<<<512, 192, 0, stream>>>(lnbuf, P[39], P[40], (float*)d_out);
}

// Round 15
// 1371.673 us; speedup vs baseline: 52.8585x; 1.6618x over previous
//
#include <hip/hip_runtime.h>
#include <hip/hip_bf16.h>
#include <hip/hip_fp16.h>
#include <cstddef>

typedef _Float16 half8 __attribute__((ext_vector_type(8)));
typedef _Float16 half4 __attribute__((ext_vector_type(4)));
typedef float floatx4 __attribute__((ext_vector_type(4)));

__global__ __launch_bounds__(256) void fill_const(float* out, int n, float v) {
    int i = blockIdx.x * 256 + threadIdx.x;
    if (i < n) out[i] = v;
}

// ---------------- pack conv weights into MFMA A-frag order ----------------
__global__ __launch_bounds__(256) void pack_w(
    const float* __restrict__ w, _Float16* __restrict__ out,
    int CIN, int K, int COUT)
{
    int NT = COUT >> 4, NCC = CIN >> 5;
    int total = K * CIN * COUT;
    int idx = blockIdx.x * 256 + threadIdx.x;
    if (idx >= total) return;
    int j = idx & 7, lane = (idx >> 3) & 63, f = idx >> 9;
    int t = f % NT, cc = (f / NT) % NCC, k = f / (NT * NCC);
    int co = t * 16 + (lane & 15);
    int ci = cc * 32 + (lane >> 4) * 8 + j;
    out[idx] = (_Float16)w[(co * CIN + ci) * K + k];
}

// ---------------- pack pe weights: K ordered ktap*256+ci (token-major source) ----------------
__global__ __launch_bounds__(256) void pack_pe(
    const float* __restrict__ w, _Float16* __restrict__ out)
{
    int idx = blockIdx.x * 256 + threadIdx.x;
    if (idx >= 393216) return;
    int j = idx & 7, lane = (idx >> 3) & 63, f = idx >> 9;
    int t = f % 12, cc = f / 12;
    int co = t * 16 + (lane & 15);
    int rr = cc * 32 + (lane >> 4) * 8 + j;   // rr = ktap*256 + ci
    int ktap = rr >> 8, ci = rr & 255;
    out[idx] = (_Float16)w[co * 2048 + ci * 8 + ktap];
}

// ---------------- pack wqk [192][384] -> B-frags f = ks*24 + ntile ----------------
__global__ __launch_bounds__(256) void pack_qk(
    const float* __restrict__ w, _Float16* __restrict__ out)
{
    int idx = blockIdx.x * 256 + threadIdx.x;
    if (idx >= 73728) return;
    int j = idx & 7, lane = (idx >> 3) & 63, f = idx >> 9;
    int nt = f % 24, ks = f / 24;
    int c = ks * 32 + (lane >> 4) * 8 + j;
    int jcol = nt * 16 + (lane & 15);
    out[idx] = (_Float16)w[c * 384 + jcol];
}

// ---------------- pack w_fc1 [192][264] -> A-frags (N pad 272) ----------------
__global__ __launch_bounds__(256) void pack_mlp1(
    const float* __restrict__ w, _Float16* __restrict__ out)
{
    int idx = blockIdx.x * 256 + threadIdx.x;
    if (idx >= 52224) return;
    int j = idx & 7, lane = (idx >> 3) & 63, f = idx >> 9;
    int t = f % 17, ks = f / 17;
    int jcol = t * 16 + (lane & 15);
    int c = ks * 32 + (lane >> 4) * 8 + j;
    out[idx] = (jcol < 264) ? (_Float16)w[c * 264 + jcol] : (_Float16)0.f;
}

// ---------------- pack w_fc2 [264][192] -> A-frags (K pad 288) ----------------
__global__ __launch_bounds__(256) void pack_mlp2(
    const float* __restrict__ w, _Float16* __restrict__ out)
{
    int idx = blockIdx.x * 256 + threadIdx.x;
    if (idx >= 55296) return;
    int j = idx & 7, lane = (idx >> 3) & 63, f = idx >> 9;
    int t = f % 12, ks = f / 12;
    int co = t * 16 + (lane & 15);
    int k = ks * 32 + (lane >> 4) * 8 + j;
    out[idx] = (k < 264) ? (_Float16)w[k * 192 + co] : (_Float16)0.f;
}

// ---------------- pack w_adj [1798][2048] -> A-frags, K pad 1824 ----------------
__global__ __launch_bounds__(256) void pack_adjw(
    const float* __restrict__ w, _Float16* __restrict__ out)
{
    int idx = blockIdx.x * 256 + threadIdx.x;
    if (idx >= 3735552) return;
    int j = idx & 7, lane = (idx >> 3) & 63, f = idx >> 9;
    int t = f & 127, ks = f >> 7;
    int jcol = t * 16 + (lane & 15);
    int k = ks * 32 + (lane >> 4) * 8 + j;
    out[idx] = (k < 1798) ? (_Float16)w[(size_t)k * 2048 + jcol] : (_Float16)0.f;
}

// ---------------- x f32 -> padded f16 ----------------
__global__ __launch_bounds__(256) void pad_x(
    const float* __restrict__ x, _Float16* __restrict__ xh)
{
    int idx = blockIdx.x * 256 + threadIdx.x;
    if (idx >= 512 * 1824) return;
    int b = idx / 1824, k = idx - b * 1824;
    xh[idx] = (k < 1798) ? (_Float16)x[(size_t)b * 1798 + k] : (_Float16)0.f;
}

// ---------------- adj via MFMA: 256 blocks (8m x 32n), 4 n-tiles each ----------------
__global__ __launch_bounds__(256) void adj_mfma(
    const _Float16* __restrict__ xh, const _Float16* __restrict__ wp,
    const float* __restrict__ bias, _Float16* __restrict__ out)
{
    const int tid = threadIdx.x;
    const int w = tid >> 6, lane = tid & 63, quad = lane >> 4, col = lane & 15;
    const int bm = blockIdx.x >> 5;
    const int bn = blockIdx.x & 31;
    const int sample = bm * 64 + w * 16 + col;
    floatx4 acc[4];
#pragma unroll
    for (int t = 0; t < 4; ++t) acc[t] = (floatx4){0.f, 0.f, 0.f, 0.f};
    for (int ks = 0; ks < 57; ++ks) {
        half8 bf = *(const half8*)&xh[(size_t)sample * 1824 + ks * 32 + quad * 8];
#pragma unroll
        for (int tt = 0; tt < 4; ++tt) {
            int f = ks * 128 + bn * 4 + tt;
            half8 af = *(const half8*)&wp[((size_t)f * 64 + lane) * 8];
            acc[tt] = __builtin_amdgcn_mfma_f32_16x16x32_f16(af, bf, acc[tt], 0, 0, 0);
        }
    }
#pragma unroll
    for (int tt = 0; tt < 4; ++tt) {
        int jb = (bn * 4 + tt) * 16 + quad * 4;
        half4 hv;
#pragma unroll
        for (int r = 0; r < 4; ++r)
            hv[r] = (_Float16)(acc[tt][r] + bias[jb + r]);
        *(half4*)&out[(size_t)sample * 2048 + jb] = hv;
    }
}

// ---------------- c0 -> token-major [l][64] ----------------
__global__ __launch_bounds__(256) void c0_tiled(
    const _Float16* __restrict__ in, const float* __restrict__ w,
    const float* __restrict__ cb, const float* __restrict__ g,
    const float* __restrict__ bb, const float* __restrict__ m,
    const float* __restrict__ vv, _Float16* __restrict__ out)  // [Bc][1024][64]
{
    __shared__ _Float16 sin[544];
    __shared__ float wf[960], sc[64], sh[64];
    const int tid = threadIdx.x;
    const int bl = blockIdx.x >> 2;
    const int l0 = (blockIdx.x & 3) * 256;
    for (int i = tid; i < 960; i += 256) wf[i] = w[i];
    if (tid < 64) {
        float s = g[tid] * rsqrtf(vv[tid] + 1e-5f);
        sc[tid] = s;
        sh[tid] = (cb[tid] - m[tid]) * s + bb[tid];
    }
    const int base = 2 * l0 - 7;
    for (int i = tid; i < 528; i += 256) {
        int pos = base + i;
        sin[i] = (pos >= 0 && pos < 2048) ? in[(size_t)bl * 2048 + pos] : (_Float16)0.f;
    }
    __syncthreads();
    const int l = l0 + tid;
    const int s0 = 2 * tid;
    float xv[15];
#pragma unroll
    for (int k = 0; k < 15; ++k) xv[k] = (float)sin[s0 + k];
    for (int gq = 0; gq < 8; ++gq) {
        half8 ov;
#pragma unroll
        for (int r = 0; r < 8; ++r) {
            int co = gq * 8 + r;
            float acc = 0.f;
#pragma unroll
            for (int k = 0; k < 15; ++k)
                acc = fmaf(xv[k], wf[co * 15 + k], acc);
            ov[r] = (_Float16)fmaxf(fmaf(acc, sc[co], sh[co]), 0.f);
        }
        *(half8*)&out[((size_t)bl * 1024 + l) * 64 + gq * 8] = ov;
    }
}

// ---------------- conv via MFMA, token-major io ----------------
template <int CIN, int K, int PAD, int COUT>
__global__ __launch_bounds__(256) void conv_mfma(
    const _Float16* __restrict__ in,   // [Bc][1024][CIN]
    const _Float16* __restrict__ wp,
    const float* __restrict__ cb, const float* __restrict__ g,
    const float* __restrict__ bb, const float* __restrict__ m,
    const float* __restrict__ vv, _Float16* __restrict__ out)  // [Bc][1024][COUT]
{
    constexpr int STRIDE = (CIN == 64) ? 72 : 152;
    constexpr int SPAN = 64 + K - 1;
    constexpr int NCC = CIN / 32, NT = COUT / 16, CH8 = CIN / 8;
    __shared__ _Float16 tin[SPAN * STRIDE];
    __shared__ float sc[COUT], sh[COUT];
    const int tid = threadIdx.x;
    const int b = blockIdx.x >> 4;
    const int l0b = (blockIdx.x & 15) * 64;
    for (int c = tid; c < COUT; c += 256) {
        float s = g[c] * rsqrtf(vv[c] + 1e-5f);
        sc[c] = s;
        sh[c] = (cb[c] - m[c]) * s + bb[c];
    }
    // vectorized row-copy staging: global [l][ci] -> LDS [p][ci] (stride STRIDE)
    for (int idx = tid; idx < SPAN * CH8; idx += 256) {
        int p = idx / CH8, ch = idx - p * CH8;
        int pos = l0b + p - PAD;
        half8 v = {0, 0, 0, 0, 0, 0, 0, 0};
        if (pos >= 0 && pos < 1024)
            v = *(const half8*)&in[((size_t)b * 1024 + pos) * CIN + ch * 8];
        *(half8*)&tin[p * STRIDE + ch * 8] = v;
    }
    __syncthreads();
    const int lane = tid & 63, wave = tid >> 6;
    const int quad = lane >> 4, n = lane & 15;
    const int lrow0 = wave * 16 + n;
    floatx4 acc[NT];
#pragma unroll
    for (int t = 0; t < NT; ++t) acc[t] = (floatx4){0.f, 0.f, 0.f, 0.f};
#pragma unroll
    for (int k = 0; k < K; ++k) {
#pragma unroll
        for (int cc = 0; cc < NCC; ++cc) {
            half8 bfrag = *(const half8*)&tin[(lrow0 + k) * STRIDE + cc * 32 + quad * 8];
#pragma unroll
            for (int t = 0; t < NT; ++t) {
                int f = (k * NCC + cc) * NT + t;
                half8 afrag = *(const half8*)&wp[((size_t)f * 64 + lane) * 8];
                acc[t] = __builtin_amdgcn_mfma_f32_16x16x32_f16(afrag, bfrag, acc[t], 0, 0, 0);
            }
        }
    }
    const int lg = l0b + wave * 16 + n;
#pragma unroll
    for (int t = 0; t < NT; ++t) {
        half4 hv;
#pragma unroll
        for (int r = 0; r < 4; ++r) {
            int co = t * 16 + quad * 4 + r;
            hv[r] = (_Float16)fmaxf(fmaf(acc[t][r], sc[co], sh[co]), 0.f);
        }
        *(half4*)&out[((size_t)b * 1024 + lg) * COUT + t * 16 + quad * 4] = hv;
    }
}

// ---------------- pe via MFMA (token-major sources); emits f32 + f16 mirror ----------------
__global__ __launch_bounds__(256) void pe_mfma(
    const _Float16* __restrict__ c0b,  // [Bc][1024][64]
    const _Float16* __restrict__ c3b,  // [Bc][1024][192]
    const _Float16* __restrict__ wp, const float* __restrict__ bias,
    float* __restrict__ out, _Float16* __restrict__ outh)
{
    const int tid = threadIdx.x;
    const int w = tid >> 6, lane = tid & 63, quad = lane >> 4, col = lane & 15;
    const int s = blockIdx.x >> 1;
    const int n0 = (blockIdx.x & 1) * 64;
    const int token = n0 + w * 16 + col;
    floatx4 acc[12];
#pragma unroll
    for (int t = 0; t < 12; ++t) acc[t] = (floatx4){0.f, 0.f, 0.f, 0.f};
    for (int cc = 0; cc < 64; ++cc) {
        int rr = cc * 32 + quad * 8;
        int ktap = rr >> 8, ci = rr & 255;
        const _Float16* src = (ci < 64)
            ? c0b + ((size_t)s * 1024 + token * 8 + ktap) * 64 + ci
            : c3b + ((size_t)s * 1024 + token * 8 + ktap) * 192 + (ci - 64);
        half8 bf = *(const half8*)src;
#pragma unroll
        for (int t = 0; t < 12; ++t) {
            half8 af = *(const half8*)&wp[((size_t)(cc * 12 + t) * 64 + lane) * 8];
            acc[t] = __builtin_amdgcn_mfma_f32_16x16x32_f16(af, bf, acc[t], 0, 0, 0);
        }
    }
    const size_t tb = ((size_t)s * 128 + token) * 192;
#pragma unroll
    for (int t = 0; t < 12; ++t) {
        half4 hv;
#pragma unroll
        for (int r = 0; r < 4; ++r) {
            int co = t * 16 + quad * 4 + r;
            float v = acc[t][r] + bias[co];
            out[tb + co] = v;
            hv[r] = (_Float16)v;
        }
        *(half4*)&outh[tb + t * 16 + quad * 4] = hv;
    }
}

// ---------------- transformer: register feat + f16 LDS mirror, 3 blocks/CU ----------------
__global__ __launch_bounds__(256) void transformer_mfma(
    const float* __restrict__ src, const _Float16* __restrict__ wqkp,
    const float* __restrict__ bqk, float* __restrict__ dst)
{
    __shared__ _Float16 uA[6400];      // featH [32][200]
    __shared__ _Float16 uB[12544];     // qks [32][392] | attnS [4][32][40]
    __shared__ _Float16 sS[4608];      // S16 [4][32][36]
    __shared__ _Float16 zerobuf[16];
    const int b = blockIdx.x;
    const int tid = threadIdx.x;
    const int w = tid >> 6, lane = tid & 63, quad = lane >> 4, col = lane & 15;
    const int tok_t = tid >> 3;            // owned token (phase1/5/6)
    const int cc0_t = (tid & 7) * 24;      // owned channel run
    const int h_t = (tid & 7) >> 1;        // head for phase5
    if (tid < 16) zerobuf[tid] = (_Float16)0.f;
    float fr[24];
    for (int i = 0; i < 4; ++i) {
        // phase1: residual accumulate in regs + f16 mirror to LDS
        const float* srow = src + ((size_t)b * 128 + i * 32 + tok_t) * 192 + cc0_t;
#pragma unroll
        for (int q = 0; q < 24; ++q) {
            float v = srow[q];
            fr[q] = (i == 0) ? v : fr[q] + v;
        }
#pragma unroll
        for (int q8 = 0; q8 < 3; ++q8) {
            half8 hv;
#pragma unroll
            for (int r = 0; r < 8; ++r) hv[r] = (_Float16)fr[q8 * 8 + r];
            *(half8*)&uA[tok_t * 200 + cc0_t + q8 * 8] = hv;
        }
        __syncthreads();
        // phase2: qk = feat @ wqk (M=32,N=384,K=192), wave w -> ntiles 6w..6w+5
        {
            floatx4 acc2[12];
#pragma unroll
            for (int t = 0; t < 12; ++t) acc2[t] = (floatx4){0.f, 0.f, 0.f, 0.f};
#pragma unroll
            for (int ks = 0; ks < 6; ++ks) {
                half8 a0 = *(const half8*)&uA[(col) * 200 + ks * 32 + quad * 8];
                half8 a1 = *(const half8*)&uA[(16 + col) * 200 + ks * 32 + quad * 8];
#pragma unroll
                for (int nl = 0; nl < 6; ++nl) {
                    int ntile = w * 6 + nl;
                    half8 bf = *(const half8*)&wqkp[((size_t)(ks * 24 + ntile) * 64 + lane) * 8];
                    acc2[nl] = __builtin_amdgcn_mfma_f32_16x16x32_f16(a0, bf, acc2[nl], 0, 0, 0);
                    acc2[6 + nl] = __builtin_amdgcn_mfma_f32_16x16x32_f16(a1, bf, acc2[6 + nl], 0, 0, 0);
                }
            }
#pragma unroll
            for (int mt = 0; mt < 2; ++mt)
#pragma unroll
                for (int nl = 0; nl < 6; ++nl) {
                    int j = (w * 6 + nl) * 16 + col;
                    float bv = bqk[j];
#pragma unroll
                    for (int r = 0; r < 4; ++r) {
                        int tok = mt * 16 + quad * 4 + r;
                        uB[tok * 392 + j] = (_Float16)(acc2[mt * 6 + nl][r] + bv);
                    }
                }
            __syncthreads();
        }
        // phase3: S = q.k per head (wave=h), K=48 pad 64
        {
            const int h = w;
            floatx4 acc3[4];
#pragma unroll
            for (int t = 0; t < 4; ++t) acc3[t] = (floatx4){0.f, 0.f, 0.f, 0.f};
#pragma unroll
            for (int ks = 0; ks < 2; ++ks) {
                bool z = (ks == 1 && quad >= 2);
                const _Float16* pq0 = z ? zerobuf : &uB[(col) * 392 + h * 48 + ks * 32 + quad * 8];
                const _Float16* pq1 = z ? zerobuf : &uB[(16 + col) * 392 + h * 48 + ks * 32 + quad * 8];
                const _Float16* pk0 = z ? zerobuf : &uB[(col) * 392 + 192 + h * 48 + ks * 32 + quad * 8];
                const _Float16* pk1 = z ? zerobuf : &uB[(16 + col) * 392 + 192 + h * 48 + ks * 32 + quad * 8];
                half8 q0 = *(const half8*)pq0, q1 = *(const half8*)pq1;
                half8 k0 = *(const half8*)pk0, k1 = *(const half8*)pk1;
                acc3[0] = __builtin_amdgcn_mfma_f32_16x16x32_f16(q0, k0, acc3[0], 0, 0, 0);
                acc3[1] = __builtin_amdgcn_mfma_f32_16x16x32_f16(q0, k1, acc3[1], 0, 0, 0);
                acc3[2] = __builtin_amdgcn_mfma_f32_16x16x32_f16(q1, k0, acc3[2], 0, 0, 0);
                acc3[3] = __builtin_amdgcn_mfma_f32_16x16x32_f16(q1, k1, acc3[3], 0, 0, 0);
            }
#pragma unroll
            for (int mt = 0; mt < 2; ++mt)
#pragma unroll
                for (int nt = 0; nt < 2; ++nt)
#pragma unroll
                    for (int r = 0; r < 4; ++r) {
                        int q = mt * 16 + quad * 4 + r;
                        int k = nt * 16 + col;
                        sS[(h * 32 + q) * 36 + k] =
                            (_Float16)(acc3[mt * 2 + nt][r] * 0.14433756729740643f);
                    }
            __syncthreads();
        }
        // phase4: softmax (reads sS, writes attnS in uB)
        if (tid < 128) {
            int h = tid >> 5, qi = tid & 31;
            const _Float16* row = &sS[(h * 32 + qi) * 36];
            float lg[32];
            float mx = -1e30f;
#pragma unroll
            for (int k = 0; k < 32; ++k) { lg[k] = (float)row[k]; mx = fmaxf(mx, lg[k]); }
            float sum = 0.f;
#pragma unroll
            for (int k = 0; k < 32; ++k) { lg[k] = __expf(lg[k] - mx); sum += lg[k]; }
            float inv = 1.f / sum;
            _Float16* arow = &uB[(h * 32 + qi) * 40];
#pragma unroll
            for (int k = 0; k < 32; ++k) arow[k] = (_Float16)(lg[k] * inv);
        }
        __syncthreads();
        // phase5: out = attn @ v  (contiguous 24-run per thread, vector featH reads)
        {
            float accq[24];
#pragma unroll
            for (int q = 0; q < 24; ++q) accq[q] = 0.f;
            const _Float16* arow = &uB[(h_t * 32 + tok_t) * 40];
            for (int j = 0; j < 32; ++j) {
                float av = (float)arow[j];
                const half8* fp = (const half8*)&uA[j * 200 + cc0_t];
                half8 f0 = fp[0], f1 = fp[1], f2 = fp[2];
#pragma unroll
                for (int r = 0; r < 8; ++r) {
                    accq[r] = fmaf(av, (float)f0[r], accq[r]);
                    accq[8 + r] = fmaf(av, (float)f1[r], accq[8 + r]);
                    accq[16 + r] = fmaf(av, (float)f2[r], accq[16 + r]);
                }
            }
#pragma unroll
            for (int q = 0; q < 24; ++q) fr[q] = accq[q];
        }
        __syncthreads();
        // phase6: write dst
        float* drow = dst + ((size_t)b * 128 + i * 32 + tok_t) * 192 + cc0_t;
#pragma unroll
        for (int q = 0; q < 24; ++q) drow[q] = fr[q];
    }
}

// ---------------- MLP via MFMA + residual + LayerNorm ----------------
__global__ __launch_bounds__(256) void mlp_mfma(
    const _Float16* __restrict__ xh, const float* __restrict__ a,
    const float* __restrict__ b1, const float* __restrict__ b2,
    const float* __restrict__ lng, const float* __restrict__ lnb,
    const _Float16* __restrict__ w1p, const _Float16* __restrict__ w2p,
    float* __restrict__ out)
{
    constexpr int HS = 296;
    __shared__ _Float16 h1s[64 * HS];
    __shared__ float b1s[264], b2s[192], lgs[192], lbs[192];
    const int tid = threadIdx.x;
    const int w = tid >> 6, lane = tid & 63, quad = lane >> 4, col = lane & 15;
    const int tok0 = blockIdx.x * 64;
    const int tokl = w * 16 + col;
    const size_t tokg = tok0 + tokl;
    for (int i = tid; i < 264; i += 256) b1s[i] = b1[i];
    for (int i = tid; i < 192; i += 256) { b2s[i] = b2[i]; lgs[i] = lng[i]; lbs[i] = lnb[i]; }
    for (int i = tid; i < 64 * 32; i += 256) {
        int tk = i >> 5, cc2 = i & 31;
        h1s[tk * HS + 264 + cc2] = (_Float16)0.f;
    }
    __syncthreads();
    floatx4 acc1[17];
#pragma unroll
    for (int t = 0; t < 17; ++t) acc1[t] = (floatx4){0.f, 0.f, 0.f, 0.f};
#pragma unroll
    for (int ks = 0; ks < 6; ++ks) {
        half8 bf = *(const half8*)&xh[tokg * 192 + ks * 32 + quad * 8];
#pragma unroll
        for (int t = 0; t < 17; ++t) {
            half8 af = *(const half8*)&w1p[((size_t)(ks * 17 + t) * 64 + lane) * 8];
            acc1[t] = __builtin_amdgcn_mfma_f32_16x16x32_f16(af, bf, acc1[t], 0, 0, 0);
        }
    }
#pragma unroll
    for (int t = 0; t < 17; ++t) {
        int jb = t * 16 + quad * 4;
        if (jb >= 264) continue;
        half4 hv;
#pragma unroll
        for (int r = 0; r < 4; ++r) {
            int j = jb + r;
            float v = acc1[t][r] + b1s[j];
            hv[r] = (_Float16)(0.5f * v * (1.f + erff(v * 0.70710678118654752f)));
        }
        *(half4*)&h1s[tokl * HS + jb] = hv;
    }
    __syncthreads();
    floatx4 acc2[12];
#pragma unroll
    for (int t = 0; t < 12; ++t) acc2[t] = (floatx4){0.f, 0.f, 0.f, 0.f};
#pragma unroll
    for (int ks = 0; ks < 9; ++ks) {
        half8 bf = *(const half8*)&h1s[tokl * HS + ks * 32 + quad * 8];
#pragma unroll
        for (int t = 0; t < 12; ++t) {
            half8 af = *(const half8*)&w2p[((size_t)(ks * 12 + t) * 64 + lane) * 8];
            acc2[t] = __builtin_amdgcn_mfma_f32_16x16x32_f16(af, bf, acc2[t], 0, 0, 0);
        }
    }
    const size_t base = tokg * 192;
    float psum = 0.f;
#pragma unroll
    for (int t = 0; t < 12; ++t) {
        float4 av = *(const float4*)&a[base + t * 16 + quad * 4];
#pragma unroll
        for (int r = 0; r < 4; ++r) {
            float v = acc2[t][r] + b2s[t * 16 + quad * 4 + r];
            v += (r == 0 ? av.x : r == 1 ? av.y : r == 2 ? av.z : av.w);
            acc2[t][r] = v;
            psum += v;
        }
    }
    psum += __shfl_xor(psum, 16);
    psum += __shfl_xor(psum, 32);
    float mean = psum * (1.f / 192.f);
    float pvar = 0.f;
#pragma unroll
    for (int t = 0; t < 12; ++t)
#pragma unroll
        for (int r = 0; r < 4; ++r) {
            float d = acc2[t][r] - mean;
            pvar = fmaf(d, d, pvar);
        }
    pvar += __shfl_xor(pvar, 16);
    pvar += __shfl_xor(pvar, 32);
    float rsd = rsqrtf(pvar * (1.f / 192.f) + 1e-5f);
#pragma unroll
    for (int t = 0; t < 12; ++t) {
        float4 ov;
#pragma unroll
        for (int r = 0; r < 4; ++r) {
            int c = t * 16 + quad * 4 + r;
            float o = (acc2[t][r] - mean) * rsd * lgs[c] + lbs[c];
            (r == 0 ? ov.x : r == 1 ? ov.y : r == 2 ? ov.z : ov.w) = o;
        }
        *(float4*)&out[base + t * 16 + quad * 4] = ov;
    }
}

// ---------------- mean + classifier head ----------------
__global__ __launch_bounds__(192) void head_kernel(
    const float* __restrict__ ln, const float* __restrict__ wcls,
    const float* __restrict__ bcls, float* __restrict__ out)
{
    __shared__ float mean[192];
    const int b = blockIdx.x;
    const int c = threadIdx.x;
    float s = 0.f;
    for (int n = 0; n < 128; ++n) s += ln[((size_t)b * 128 + n) * 192 + c];
    mean[c] = s * (1.f / 128.f);
    __syncthreads();
    if (c < 3) {
        float acc = bcls[c];
        for (int k = 0; k < 192; ++k) acc = fmaf(mean[k], wcls[k * 3 + c], acc);
        out[b * 3 + c] = acc;
    }
}

static const int SZ_DICT[41] = {
    920576, 3682304, 2048, 960, 64, 64, 64, 64, 64,
    73728, 128, 128, 128, 128, 128,
    81920, 128, 128, 128, 128, 128,
    73728, 192, 192, 192, 192, 192,
    393216, 192,
    73728, 384, 73728, 384,
    50688, 264, 50688, 192,
    192, 192, 576, 3};

extern "C" void kernel_launch(void* const* d_in, const int* in_sizes, int n_in,
                              void* d_out, int out_size, void* d_ws, size_t ws_size,
                              hipStream_t stream) {
    if (n_in != 41) {
        fill_const<<<(out_size + 255) / 256, 256, 0, stream>>>((float*)d_out, out_size, 200.f);
        return;
    }
    bool mA = true;
    for (int i = 0; i < 41; ++i) mA = mA && (in_sizes[i] == SZ_DICT[i]);
    if (!mA) {
        fill_const<<<(out_size + 255) / 256, 256, 0, stream>>>((float*)d_out, out_size, 100.f);
        return;
    }
    const float* P[41];
    for (int i = 0; i < 41; ++i) P[i] = (const float*)d_in[i];

    const size_t TOK = (size_t)512 * 128 * 192 * 4;
    const size_t TOKH = (size_t)512 * 128 * 192 * 2;
    const size_t WPACK = 2097152;
    const size_t ADJF = (size_t)512 * 2048 * 2;
    if (3 * TOK + TOKH + WPACK + ADJF > ws_size) {
        fill_const<<<(out_size + 255) / 256, 256, 0, stream>>>((float*)d_out, out_size, 50.f);
        return;
    }
    char* ws = (char*)d_ws;
    float* peb = (float*)ws;
    char*  tokA = ws + TOK;
    char*  tokB = tokA + TOK;
    _Float16* pebh = (_Float16*)(tokB + TOK);
    char*  wpk = (char*)pebh + TOKH;
    _Float16* adjfull = (_Float16*)(wpk + WPACK);

    // transient in peb (dead before pe writes): packed adj weights + padded x
    _Float16* wadjp = (_Float16*)peb;
    _Float16* xpad  = wadjp + 3735552;

    const int BcC = 128;
    _Float16* c0b = (_Float16*)tokA;                 // [128][1024][64]
    char*     u1  = tokA + (size_t)BcC * 131072;
    char*     u2  = u1 + (size_t)BcC * 393216;
    _Float16* c1b  = (_Float16*)u1;                  // [128][1024][128]
    _Float16* c2b  = (_Float16*)u2;                  // [128][1024][128]
    _Float16* c3b  = (_Float16*)u1;                  // [128][1024][192]
    float* t1b = (float*)tokA;
    float* t2b = (float*)tokB;
    float* lnbuf = (float*)tokA;

    _Float16* w1p  = (_Float16*)wpk;
    _Float16* w2p  = w1p + 73728;
    _Float16* w3p  = w2p + 81920;
    _Float16* wpep = w3p + 73728;
    _Float16* wq0p = wpep + 393216;
    _Float16* wq1p = wq0p + 73728;
    _Float16* wm1p = wq1p + 73728;
    _Float16* wm2p = wm1p + 52224;

    pack_w<<<288, 256, 0, stream>>>(P[9],  w1p, 64, 9, 128);
    pack_w<<<320, 256, 0, stream>>>(P[15], w2p, 128, 5, 128);
    pack_w<<<288, 256, 0, stream>>>(P[21], w3p, 128, 3, 192);
    pack_pe<<<1536, 256, 0, stream>>>(P[27], wpep);
    pack_qk<<<288, 256, 0, stream>>>(P[29], wq0p);
    pack_qk<<<288, 256, 0, stream>>>(P[31], wq1p);
    pack_mlp1<<<204, 256, 0, stream>>>(P[33], wm1p);
    pack_mlp2<<<216, 256, 0, stream>>>(P[35], wm2p);
    pack_adjw<<<14592, 256, 0, stream>>>(P[1], wadjp);
    pad_x<<<3648, 256, 0, stream>>>(P[0], xpad);

    adj_mfma<<<256, 256, 0, stream>>>(xpad, wadjp, P[2], adjfull);

    for (int c = 0; c < 4; ++c) {
        const size_t b0 = (size_t)c * BcC;
        c0_tiled<<<BcC * 4, 256, 0, stream>>>(adjfull + b0 * 2048, P[3], P[4],
                                              P[5], P[6], P[7], P[8], c0b);
        conv_mfma<64, 9, 4, 128><<<BcC * 16, 256, 0, stream>>>(c0b, w1p, P[10],
                                                 P[11], P[12], P[13], P[14], c1b);
        conv_mfma<128, 5, 2, 128><<<BcC * 16, 256, 0, stream>>>(c1b, w2p, P[16],
                                                 P[17], P[18], P[19], P[20], c2b);
        conv_mfma<128, 3, 1, 192><<<BcC * 16, 256, 0, stream>>>(c2b, w3p, P[22],
                                                 P[23], P[24], P[25], P[26], c3b);
        pe_mfma<<<BcC * 2, 256, 0, stream>>>(c0b, c3b, wpep, P[28],
                                             peb + b0 * 128 * 192,
                                             pebh + b0 * 128 * 192);
    }
    transformer_mfma<<<512, 256, 0, stream>>>(peb, wq0p, P[30], t1b);
    transformer_mfma<<<512, 256, 0, stream>>>(t1b, wq1p, P[32], t2b);
    mlp_mfma<<<1024, 256, 0, stream>>>(pebh, t2b, P[34], P[36],
                                       P[37], P[38], wm1p, wm2p, lnbuf);
    head_kernel<<<512, 192, 0, stream>>>(lnbuf, P[39], P[40], (float*)d_out);
}

// Round 16
// 1322.079 us; speedup vs baseline: 54.8413x; 1.0375x over previous
//
#include <hip/hip_runtime.h>
#include <hip/hip_bf16.h>
#include <hip/hip_fp16.h>
#include <cstddef>

typedef _Float16 half8 __attribute__((ext_vector_type(8)));
typedef _Float16 half4 __attribute__((ext_vector_type(4)));
typedef float floatx4 __attribute__((ext_vector_type(4)));

__global__ __launch_bounds__(256) void fill_const(float* out, int n, float v) {
    int i = blockIdx.x * 256 + threadIdx.x;
    if (i < n) out[i] = v;
}

// ---------------- pack conv weights into MFMA A-frag order ----------------
__global__ __launch_bounds__(256) void pack_w(
    const float* __restrict__ w, _Float16* __restrict__ out,
    int CIN, int K, int COUT)
{
    int NT = COUT >> 4, NCC = CIN >> 5;
    int total = K * CIN * COUT;
    int idx = blockIdx.x * 256 + threadIdx.x;
    if (idx >= total) return;
    int j = idx & 7, lane = (idx >> 3) & 63, f = idx >> 9;
    int t = f % NT, cc = (f / NT) % NCC, k = f / (NT * NCC);
    int co = t * 16 + (lane & 15);
    int ci = cc * 32 + (lane >> 4) * 8 + j;
    out[idx] = (_Float16)w[(co * CIN + ci) * K + k];
}

// ---------------- pack pe weights: K ordered ktap*256+ci ----------------
__global__ __launch_bounds__(256) void pack_pe(
    const float* __restrict__ w, _Float16* __restrict__ out)
{
    int idx = blockIdx.x * 256 + threadIdx.x;
    if (idx >= 393216) return;
    int j = idx & 7, lane = (idx >> 3) & 63, f = idx >> 9;
    int t = f % 12, cc = f / 12;
    int co = t * 16 + (lane & 15);
    int rr = cc * 32 + (lane >> 4) * 8 + j;
    int ktap = rr >> 8, ci = rr & 255;
    out[idx] = (_Float16)w[co * 2048 + ci * 8 + ktap];
}

// ---------------- pack wqk -> B-frags ----------------
__global__ __launch_bounds__(256) void pack_qk(
    const float* __restrict__ w, _Float16* __restrict__ out)
{
    int idx = blockIdx.x * 256 + threadIdx.x;
    if (idx >= 73728) return;
    int j = idx & 7, lane = (idx >> 3) & 63, f = idx >> 9;
    int nt = f % 24, ks = f / 24;
    int c = ks * 32 + (lane >> 4) * 8 + j;
    int jcol = nt * 16 + (lane & 15);
    out[idx] = (_Float16)w[c * 384 + jcol];
}

// ---------------- pack w_fc1 (N pad 272) ----------------
__global__ __launch_bounds__(256) void pack_mlp1(
    const float* __restrict__ w, _Float16* __restrict__ out)
{
    int idx = blockIdx.x * 256 + threadIdx.x;
    if (idx >= 52224) return;
    int j = idx & 7, lane = (idx >> 3) & 63, f = idx >> 9;
    int t = f % 17, ks = f / 17;
    int jcol = t * 16 + (lane & 15);
    int c = ks * 32 + (lane >> 4) * 8 + j;
    out[idx] = (jcol < 264) ? (_Float16)w[c * 264 + jcol] : (_Float16)0.f;
}

// ---------------- pack w_fc2 (K pad 288) ----------------
__global__ __launch_bounds__(256) void pack_mlp2(
    const float* __restrict__ w, _Float16* __restrict__ out)
{
    int idx = blockIdx.x * 256 + threadIdx.x;
    if (idx >= 55296) return;
    int j = idx & 7, lane = (idx >> 3) & 63, f = idx >> 9;
    int t = f % 12, ks = f / 12;
    int co = t * 16 + (lane & 15);
    int k = ks * 32 + (lane >> 4) * 8 + j;
    out[idx] = (k < 264) ? (_Float16)w[k * 192 + co] : (_Float16)0.f;
}

// ---------------- pack w_adj (K pad 1824) ----------------
__global__ __launch_bounds__(256) void pack_adjw(
    const float* __restrict__ w, _Float16* __restrict__ out)
{
    int idx = blockIdx.x * 256 + threadIdx.x;
    if (idx >= 3735552) return;
    int j = idx & 7, lane = (idx >> 3) & 63, f = idx >> 9;
    int t = f & 127, ks = f >> 7;
    int jcol = t * 16 + (lane & 15);
    int k = ks * 32 + (lane >> 4) * 8 + j;
    out[idx] = (k < 1798) ? (_Float16)w[(size_t)k * 2048 + jcol] : (_Float16)0.f;
}

// ---------------- x f32 -> padded f16 ----------------
__global__ __launch_bounds__(256) void pad_x(
    const float* __restrict__ x, _Float16* __restrict__ xh)
{
    int idx = blockIdx.x * 256 + threadIdx.x;
    if (idx >= 512 * 1824) return;
    int b = idx / 1824, k = idx - b * 1824;
    xh[idx] = (k < 1798) ? (_Float16)x[(size_t)b * 1798 + k] : (_Float16)0.f;
}

// ---------------- adj via MFMA ----------------
__global__ __launch_bounds__(256) void adj_mfma(
    const _Float16* __restrict__ xh, const _Float16* __restrict__ wp,
    const float* __restrict__ bias, _Float16* __restrict__ out)
{
    const int tid = threadIdx.x;
    const int w = tid >> 6, lane = tid & 63, quad = lane >> 4, col = lane & 15;
    const int bm = blockIdx.x >> 5;
    const int bn = blockIdx.x & 31;
    const int sample = bm * 64 + w * 16 + col;
    floatx4 acc[4];
#pragma unroll
    for (int t = 0; t < 4; ++t) acc[t] = (floatx4){0.f, 0.f, 0.f, 0.f};
    for (int ks = 0; ks < 57; ++ks) {
        half8 bf = *(const half8*)&xh[(size_t)sample * 1824 + ks * 32 + quad * 8];
#pragma unroll
        for (int tt = 0; tt < 4; ++tt) {
            int f = ks * 128 + bn * 4 + tt;
            half8 af = *(const half8*)&wp[((size_t)f * 64 + lane) * 8];
            acc[tt] = __builtin_amdgcn_mfma_f32_16x16x32_f16(af, bf, acc[tt], 0, 0, 0);
        }
    }
#pragma unroll
    for (int tt = 0; tt < 4; ++tt) {
        int jb = (bn * 4 + tt) * 16 + quad * 4;
        half4 hv;
#pragma unroll
        for (int r = 0; r < 4; ++r)
            hv[r] = (_Float16)(acc[tt][r] + bias[jb + r]);
        *(half4*)&out[(size_t)sample * 2048 + jb] = hv;
    }
}

// ---------------- c0 -> token-major [l][64] ----------------
__global__ __launch_bounds__(256) void c0_tiled(
    const _Float16* __restrict__ in, const float* __restrict__ w,
    const float* __restrict__ cb, const float* __restrict__ g,
    const float* __restrict__ bb, const float* __restrict__ m,
    const float* __restrict__ vv, _Float16* __restrict__ out)
{
    __shared__ _Float16 sin[544];
    __shared__ float wf[960], sc[64], sh[64];
    const int tid = threadIdx.x;
    const int bl = blockIdx.x >> 2;
    const int l0 = (blockIdx.x & 3) * 256;
    for (int i = tid; i < 960; i += 256) wf[i] = w[i];
    if (tid < 64) {
        float s = g[tid] * rsqrtf(vv[tid] + 1e-5f);
        sc[tid] = s;
        sh[tid] = (cb[tid] - m[tid]) * s + bb[tid];
    }
    const int base = 2 * l0 - 7;
    for (int i = tid; i < 528; i += 256) {
        int pos = base + i;
        sin[i] = (pos >= 0 && pos < 2048) ? in[(size_t)bl * 2048 + pos] : (_Float16)0.f;
    }
    __syncthreads();
    const int l = l0 + tid;
    const int s0 = 2 * tid;
    float xv[15];
#pragma unroll
    for (int k = 0; k < 15; ++k) xv[k] = (float)sin[s0 + k];
    for (int gq = 0; gq < 8; ++gq) {
        half8 ov;
#pragma unroll
        for (int r = 0; r < 8; ++r) {
            int co = gq * 8 + r;
            float acc = 0.f;
#pragma unroll
            for (int k = 0; k < 15; ++k)
                acc = fmaf(xv[k], wf[co * 15 + k], acc);
            ov[r] = (_Float16)fmaxf(fmaf(acc, sc[co], sh[co]), 0.f);
        }
        *(half8*)&out[((size_t)bl * 1024 + l) * 64 + gq * 8] = ov;
    }
}

// ---------------- conv via MFMA, token-major io ----------------
template <int CIN, int K, int PAD, int COUT>
__global__ __launch_bounds__(256) void conv_mfma(
    const _Float16* __restrict__ in, const _Float16* __restrict__ wp,
    const float* __restrict__ cb, const float* __restrict__ g,
    const float* __restrict__ bb, const float* __restrict__ m,
    const float* __restrict__ vv, _Float16* __restrict__ out)
{
    constexpr int STRIDE = (CIN == 64) ? 72 : 152;
    constexpr int SPAN = 64 + K - 1;
    constexpr int NCC = CIN / 32, NT = COUT / 16, CH8 = CIN / 8;
    __shared__ _Float16 tin[SPAN * STRIDE];
    __shared__ float sc[COUT], sh[COUT];
    const int tid = threadIdx.x;
    const int b = blockIdx.x >> 4;
    const int l0b = (blockIdx.x & 15) * 64;
    for (int c = tid; c < COUT; c += 256) {
        float s = g[c] * rsqrtf(vv[c] + 1e-5f);
        sc[c] = s;
        sh[c] = (cb[c] - m[c]) * s + bb[c];
    }
    for (int idx = tid; idx < SPAN * CH8; idx += 256) {
        int p = idx / CH8, ch = idx - p * CH8;
        int pos = l0b + p - PAD;
        half8 v = {0, 0, 0, 0, 0, 0, 0, 0};
        if (pos >= 0 && pos < 1024)
            v = *(const half8*)&in[((size_t)b * 1024 + pos) * CIN + ch * 8];
        *(half8*)&tin[p * STRIDE + ch * 8] = v;
    }
    __syncthreads();
    const int lane = tid & 63, wave = tid >> 6;
    const int quad = lane >> 4, n = lane & 15;
    const int lrow0 = wave * 16 + n;
    floatx4 acc[NT];
#pragma unroll
    for (int t = 0; t < NT; ++t) acc[t] = (floatx4){0.f, 0.f, 0.f, 0.f};
#pragma unroll
    for (int k = 0; k < K; ++k) {
#pragma unroll
        for (int cc = 0; cc < NCC; ++cc) {
            half8 bfrag = *(const half8*)&tin[(lrow0 + k) * STRIDE + cc * 32 + quad * 8];
#pragma unroll
            for (int t = 0; t < NT; ++t) {
                int f = (k * NCC + cc) * NT + t;
                half8 afrag = *(const half8*)&wp[((size_t)f * 64 + lane) * 8];
                acc[t] = __builtin_amdgcn_mfma_f32_16x16x32_f16(afrag, bfrag, acc[t], 0, 0, 0);
            }
        }
    }
    const int lg = l0b + wave * 16 + n;
#pragma unroll
    for (int t = 0; t < NT; ++t) {
        half4 hv;
#pragma unroll
        for (int r = 0; r < 4; ++r) {
            int co = t * 16 + quad * 4 + r;
            hv[r] = (_Float16)fmaxf(fmaf(acc[t][r], sc[co], sh[co]), 0.f);
        }
        *(half4*)&out[((size_t)b * 1024 + lg) * COUT + t * 16 + quad * 4] = hv;
    }
}

// ---------------- pe via MFMA -> f16 tokens only ----------------
__global__ __launch_bounds__(256) void pe_mfma(
    const _Float16* __restrict__ c0b, const _Float16* __restrict__ c3b,
    const _Float16* __restrict__ wp, const float* __restrict__ bias,
    _Float16* __restrict__ outh)
{
    const int tid = threadIdx.x;
    const int w = tid >> 6, lane = tid & 63, quad = lane >> 4, col = lane & 15;
    const int s = blockIdx.x >> 1;
    const int n0 = (blockIdx.x & 1) * 64;
    const int token = n0 + w * 16 + col;
    floatx4 acc[12];
#pragma unroll
    for (int t = 0; t < 12; ++t) acc[t] = (floatx4){0.f, 0.f, 0.f, 0.f};
    for (int cc = 0; cc < 64; ++cc) {
        int rr = cc * 32 + quad * 8;
        int ktap = rr >> 8, ci = rr & 255;
        const _Float16* src = (ci < 64)
            ? c0b + ((size_t)s * 1024 + token * 8 + ktap) * 64 + ci
            : c3b + ((size_t)s * 1024 + token * 8 + ktap) * 192 + (ci - 64);
        half8 bf = *(const half8*)src;
#pragma unroll
        for (int t = 0; t < 12; ++t) {
            half8 af = *(const half8*)&wp[((size_t)(cc * 12 + t) * 64 + lane) * 8];
            acc[t] = __builtin_amdgcn_mfma_f32_16x16x32_f16(af, bf, acc[t], 0, 0, 0);
        }
    }
    const size_t tb = ((size_t)s * 128 + token) * 192;
#pragma unroll
    for (int t = 0; t < 12; ++t) {
        half4 hv;
#pragma unroll
        for (int r = 0; r < 4; ++r)
            hv[r] = (_Float16)(acc[t][r] + bias[t * 16 + quad * 4 + r]);
        *(half4*)&outh[tb + t * 16 + quad * 4] = hv;
    }
}

// ---------------- transformer: f16 io, register feat ----------------
__global__ __launch_bounds__(256) void transformer_mfma(
    const _Float16* __restrict__ src, const _Float16* __restrict__ wqkp,
    const float* __restrict__ bqk, _Float16* __restrict__ dst)
{
    __shared__ _Float16 uA[6400];      // featH [32][200]
    __shared__ _Float16 uB[12544];     // qks [32][392] | attnS [4][32][40]
    __shared__ _Float16 sS[4608];      // S16 [4][32][36]
    __shared__ _Float16 zerobuf[16];
    const int b = blockIdx.x;
    const int tid = threadIdx.x;
    const int w = tid >> 6, lane = tid & 63, quad = lane >> 4, col = lane & 15;
    const int tok_t = tid >> 3;
    const int cc0_t = (tid & 7) * 24;
    const int h_t = (tid & 7) >> 1;
    if (tid < 16) zerobuf[tid] = (_Float16)0.f;
    float fr[24];
    for (int i = 0; i < 4; ++i) {
        const _Float16* srow = src + ((size_t)b * 128 + i * 32 + tok_t) * 192 + cc0_t;
        {
            half8 s0 = *(const half8*)&srow[0];
            half8 s1 = *(const half8*)&srow[8];
            half8 s2 = *(const half8*)&srow[16];
#pragma unroll
            for (int r = 0; r < 8; ++r) {
                float v0 = (float)s0[r], v1 = (float)s1[r], v2 = (float)s2[r];
                if (i == 0) { fr[r] = v0; fr[8 + r] = v1; fr[16 + r] = v2; }
                else { fr[r] += v0; fr[8 + r] += v1; fr[16 + r] += v2; }
            }
        }
#pragma unroll
        for (int q8 = 0; q8 < 3; ++q8) {
            half8 hv;
#pragma unroll
            for (int r = 0; r < 8; ++r) hv[r] = (_Float16)fr[q8 * 8 + r];
            *(half8*)&uA[tok_t * 200 + cc0_t + q8 * 8] = hv;
        }
        __syncthreads();
        // qk = feat @ wqk
        {
            floatx4 acc2[12];
#pragma unroll
            for (int t = 0; t < 12; ++t) acc2[t] = (floatx4){0.f, 0.f, 0.f, 0.f};
#pragma unroll
            for (int ks = 0; ks < 6; ++ks) {
                half8 a0 = *(const half8*)&uA[(col) * 200 + ks * 32 + quad * 8];
                half8 a1 = *(const half8*)&uA[(16 + col) * 200 + ks * 32 + quad * 8];
#pragma unroll
                for (int nl = 0; nl < 6; ++nl) {
                    int ntile = w * 6 + nl;
                    half8 bf = *(const half8*)&wqkp[((size_t)(ks * 24 + ntile) * 64 + lane) * 8];
                    acc2[nl] = __builtin_amdgcn_mfma_f32_16x16x32_f16(a0, bf, acc2[nl], 0, 0, 0);
                    acc2[6 + nl] = __builtin_amdgcn_mfma_f32_16x16x32_f16(a1, bf, acc2[6 + nl], 0, 0, 0);
                }
            }
#pragma unroll
            for (int mt = 0; mt < 2; ++mt)
#pragma unroll
                for (int nl = 0; nl < 6; ++nl) {
                    int j = (w * 6 + nl) * 16 + col;
                    float bv = bqk[j];
#pragma unroll
                    for (int r = 0; r < 4; ++r) {
                        int tok = mt * 16 + quad * 4 + r;
                        uB[tok * 392 + j] = (_Float16)(acc2[mt * 6 + nl][r] + bv);
                    }
                }
            __syncthreads();
        }
        // S = q.k per head (wave=h)
        {
            const int h = w;
            floatx4 acc3[4];
#pragma unroll
            for (int t = 0; t < 4; ++t) acc3[t] = (floatx4){0.f, 0.f, 0.f, 0.f};
#pragma unroll
            for (int ks = 0; ks < 2; ++ks) {
                bool z = (ks == 1 && quad >= 2);
                const _Float16* pq0 = z ? zerobuf : &uB[(col) * 392 + h * 48 + ks * 32 + quad * 8];
                const _Float16* pq1 = z ? zerobuf : &uB[(16 + col) * 392 + h * 48 + ks * 32 + quad * 8];
                const _Float16* pk0 = z ? zerobuf : &uB[(col) * 392 + 192 + h * 48 + ks * 32 + quad * 8];
                const _Float16* pk1 = z ? zerobuf : &uB[(16 + col) * 392 + 192 + h * 48 + ks * 32 + quad * 8];
                half8 q0 = *(const half8*)pq0, q1 = *(const half8*)pq1;
                half8 k0 = *(const half8*)pk0, k1 = *(const half8*)pk1;
                acc3[0] = __builtin_amdgcn_mfma_f32_16x16x32_f16(q0, k0, acc3[0], 0, 0, 0);
                acc3[1] = __builtin_amdgcn_mfma_f32_16x16x32_f16(q0, k1, acc3[1], 0, 0, 0);
                acc3[2] = __builtin_amdgcn_mfma_f32_16x16x32_f16(q1, k0, acc3[2], 0, 0, 0);
                acc3[3] = __builtin_amdgcn_mfma_f32_16x16x32_f16(q1, k1, acc3[3], 0, 0, 0);
            }
#pragma unroll
            for (int mt = 0; mt < 2; ++mt)
#pragma unroll
                for (int nt = 0; nt < 2; ++nt)
#pragma unroll
                    for (int r = 0; r < 4; ++r) {
                        int q = mt * 16 + quad * 4 + r;
                        int k = nt * 16 + col;
                        sS[(h * 32 + q) * 36 + k] =
                            (_Float16)(acc3[mt * 2 + nt][r] * 0.14433756729740643f);
                    }
            __syncthreads();
        }
        // softmax
        if (tid < 128) {
            int h = tid >> 5, qi = tid & 31;
            const _Float16* row = &sS[(h * 32 + qi) * 36];
            float lg[32];
            float mx = -1e30f;
#pragma unroll
            for (int k = 0; k < 32; ++k) { lg[k] = (float)row[k]; mx = fmaxf(mx, lg[k]); }
            float sum = 0.f;
#pragma unroll
            for (int k = 0; k < 32; ++k) { lg[k] = __expf(lg[k] - mx); sum += lg[k]; }
            float inv = 1.f / sum;
            _Float16* arow = &uB[(h * 32 + qi) * 40];
#pragma unroll
            for (int k = 0; k < 32; ++k) arow[k] = (_Float16)(lg[k] * inv);
        }
        __syncthreads();
        // out = attn @ v
        {
            float accq[24];
#pragma unroll
            for (int q = 0; q < 24; ++q) accq[q] = 0.f;
            const _Float16* arow = &uB[(h_t * 32 + tok_t) * 40];
            for (int j = 0; j < 32; ++j) {
                float av = (float)arow[j];
                const half8* fp = (const half8*)&uA[j * 200 + cc0_t];
                half8 f0 = fp[0], f1 = fp[1], f2 = fp[2];
#pragma unroll
                for (int r = 0; r < 8; ++r) {
                    accq[r] = fmaf(av, (float)f0[r], accq[r]);
                    accq[8 + r] = fmaf(av, (float)f1[r], accq[8 + r]);
                    accq[16 + r] = fmaf(av, (float)f2[r], accq[16 + r]);
                }
            }
#pragma unroll
            for (int q = 0; q < 24; ++q) fr[q] = accq[q];
        }
        __syncthreads();
        _Float16* drow = dst + ((size_t)b * 128 + i * 32 + tok_t) * 192 + cc0_t;
#pragma unroll
        for (int q8 = 0; q8 < 3; ++q8) {
            half8 hv;
#pragma unroll
            for (int r = 0; r < 8; ++r) hv[r] = (_Float16)fr[q8 * 8 + r];
            *(half8*)&drow[q8 * 8] = hv;
        }
    }
}

// ---------------- MLP via MFMA + residual + LN -> per-block token-sum partials ----------------
__global__ __launch_bounds__(256) void mlp_mfma(
    const _Float16* __restrict__ xh, const _Float16* __restrict__ a,
    const float* __restrict__ b1, const float* __restrict__ b2,
    const float* __restrict__ lng, const float* __restrict__ lnb,
    const _Float16* __restrict__ w1p, const _Float16* __restrict__ w2p,
    float* __restrict__ bsum)          // [gridDim][192]
{
    constexpr int HS = 296;
    __shared__ _Float16 h1s[64 * HS];
    __shared__ float b1s[264], b2s[192], lgs[192], lbs[192];
    __shared__ float ps[4 * 192];
    const int tid = threadIdx.x;
    const int w = tid >> 6, lane = tid & 63, quad = lane >> 4, col = lane & 15;
    const int tok0 = blockIdx.x * 64;
    const int tokl = w * 16 + col;
    const size_t tokg = tok0 + tokl;
    for (int i = tid; i < 264; i += 256) b1s[i] = b1[i];
    for (int i = tid; i < 192; i += 256) { b2s[i] = b2[i]; lgs[i] = lng[i]; lbs[i] = lnb[i]; }
    for (int i = tid; i < 64 * 32; i += 256) {
        int tk = i >> 5, cc2 = i & 31;
        h1s[tk * HS + 264 + cc2] = (_Float16)0.f;
    }
    __syncthreads();
    floatx4 acc1[17];
#pragma unroll
    for (int t = 0; t < 17; ++t) acc1[t] = (floatx4){0.f, 0.f, 0.f, 0.f};
#pragma unroll
    for (int ks = 0; ks < 6; ++ks) {
        half8 bf = *(const half8*)&xh[tokg * 192 + ks * 32 + quad * 8];
#pragma unroll
        for (int t = 0; t < 17; ++t) {
            half8 af = *(const half8*)&w1p[((size_t)(ks * 17 + t) * 64 + lane) * 8];
            acc1[t] = __builtin_amdgcn_mfma_f32_16x16x32_f16(af, bf, acc1[t], 0, 0, 0);
        }
    }
#pragma unroll
    for (int t = 0; t < 17; ++t) {
        int jb = t * 16 + quad * 4;
        if (jb >= 264) continue;
        half4 hv;
#pragma unroll
        for (int r = 0; r < 4; ++r) {
            int j = jb + r;
            float v = acc1[t][r] + b1s[j];
            hv[r] = (_Float16)(0.5f * v * (1.f + erff(v * 0.70710678118654752f)));
        }
        *(half4*)&h1s[tokl * HS + jb] = hv;
    }
    __syncthreads();
    floatx4 acc2[12];
#pragma unroll
    for (int t = 0; t < 12; ++t) acc2[t] = (floatx4){0.f, 0.f, 0.f, 0.f};
#pragma unroll
    for (int ks = 0; ks < 9; ++ks) {
        half8 bf = *(const half8*)&h1s[tokl * HS + ks * 32 + quad * 8];
#pragma unroll
        for (int t = 0; t < 12; ++t) {
            half8 af = *(const half8*)&w2p[((size_t)(ks * 12 + t) * 64 + lane) * 8];
            acc2[t] = __builtin_amdgcn_mfma_f32_16x16x32_f16(af, bf, acc2[t], 0, 0, 0);
        }
    }
    const size_t base = tokg * 192;
    float psum = 0.f;
#pragma unroll
    for (int t = 0; t < 12; ++t) {
        half4 av = *(const half4*)&a[base + t * 16 + quad * 4];
#pragma unroll
        for (int r = 0; r < 4; ++r) {
            float v = acc2[t][r] + b2s[t * 16 + quad * 4 + r] + (float)av[r];
            acc2[t][r] = v;
            psum += v;
        }
    }
    psum += __shfl_xor(psum, 16);
    psum += __shfl_xor(psum, 32);
    float mean = psum * (1.f / 192.f);
    float pvar = 0.f;
#pragma unroll
    for (int t = 0; t < 12; ++t)
#pragma unroll
        for (int r = 0; r < 4; ++r) {
            float d = acc2[t][r] - mean;
            pvar = fmaf(d, d, pvar);
        }
    pvar += __shfl_xor(pvar, 16);
    pvar += __shfl_xor(pvar, 32);
    float rsd = rsqrtf(pvar * (1.f / 192.f) + 1e-5f);
    // LN + token-sum reduction (sum over the wave's 16 tokens via quad-group shfl)
#pragma unroll
    for (int t = 0; t < 12; ++t) {
#pragma unroll
        for (int r = 0; r < 4; ++r) {
            float o = (acc2[t][r] - mean) * rsd * lgs[t * 16 + quad * 4 + r] + lbs[t * 16 + quad * 4 + r];
            o += __shfl_xor(o, 1);
            o += __shfl_xor(o, 2);
            o += __shfl_xor(o, 4);
            o += __shfl_xor(o, 8);
            acc2[t][r] = o;   // token-sum, replicated across the 16-lane group
        }
    }
    if (col == 0) {
#pragma unroll
        for (int t = 0; t < 12; ++t)
#pragma unroll
            for (int r = 0; r < 4; ++r)
                ps[w * 192 + t * 16 + quad * 4 + r] = acc2[t][r];
    }
    __syncthreads();
    if (tid < 192)
        bsum[(size_t)blockIdx.x * 192 + tid] =
            ps[tid] + ps[192 + tid] + ps[384 + tid] + ps[576 + tid];
}

// ---------------- head: combine 2 block-partials per sample + classifier ----------------
__global__ __launch_bounds__(192) void head2_kernel(
    const float* __restrict__ bsum, const float* __restrict__ wcls,
    const float* __restrict__ bcls, float* __restrict__ out)
{
    __shared__ float mean[192];
    const int b = blockIdx.x;
    const int c = threadIdx.x;
    mean[c] = (bsum[(size_t)(2 * b) * 192 + c] + bsum[(size_t)(2 * b + 1) * 192 + c]) * (1.f / 128.f);
    __syncthreads();
    if (c < 3) {
        float acc = bcls[c];
        for (int k = 0; k < 192; ++k) acc = fmaf(mean[k], wcls[k * 3 + c], acc);
        out[b * 3 + c] = acc;
    }
}

static const int SZ_DICT[41] = {
    920576, 3682304, 2048, 960, 64, 64, 64, 64, 64,
    73728, 128, 128, 128, 128, 128,
    81920, 128, 128, 128, 128, 128,
    73728, 192, 192, 192, 192, 192,
    393216, 192,
    73728, 384, 73728, 384,
    50688, 264, 50688, 192,
    192, 192, 576, 3};

extern "C" void kernel_launch(void* const* d_in, const int* in_sizes, int n_in,
                              void* d_out, int out_size, void* d_ws, size_t ws_size,
                              hipStream_t stream) {
    if (n_in != 41) {
        fill_const<<<(out_size + 255) / 256, 256, 0, stream>>>((float*)d_out, out_size, 200.f);
        return;
    }
    bool mA = true;
    for (int i = 0; i < 41; ++i) mA = mA && (in_sizes[i] == SZ_DICT[i]);
    if (!mA) {
        fill_const<<<(out_size + 255) / 256, 256, 0, stream>>>((float*)d_out, out_size, 100.f);
        return;
    }
    const float* P[41];
    for (int i = 0; i < 41; ++i) P[i] = (const float*)d_in[i];

    // layout: [convS 100.66M][pebh 25.2M][t1h 25.2M][t2h 25.2M][wpk 2M][adjfull 2M]
    // total = 180,355,072 B (== round-14-proven size). bsum + adj transients alias convS.
    const size_t CONVS = 100663296;
    const size_t TOKH = (size_t)512 * 128 * 192 * 2;
    const size_t WPACK = 2097152;
    const size_t ADJF = (size_t)512 * 2048 * 2;
    if (CONVS + 3 * TOKH + WPACK + ADJF > ws_size) {
        fill_const<<<(out_size + 255) / 256, 256, 0, stream>>>((float*)d_out, out_size, 50.f);
        return;
    }
    char* ws = (char*)d_ws;
    char* convS = ws;
    _Float16* pebh = (_Float16*)(ws + CONVS);
    _Float16* t1h  = (_Float16*)(ws + CONVS + TOKH);
    _Float16* t2h  = (_Float16*)(ws + CONVS + 2 * TOKH);
    char* wpk = ws + CONVS + 3 * TOKH;
    _Float16* adjfull = (_Float16*)(wpk + WPACK);

    // transients in convS (dead before their region is reused):
    _Float16* wadjp = (_Float16*)convS;              // used only by adj_mfma (before chunk loop)
    _Float16* xpad  = wadjp + 3735552;
    float* bsum = (float*)convS;                     // written by mlp (after conv chain dead)

    const int BcC = 128;
    _Float16* c0b = (_Float16*)convS;                // [128][1024][64]
    char* u1 = convS + (size_t)BcC * 131072;
    char* u2 = u1 + (size_t)BcC * 393216;
    _Float16* c1b = (_Float16*)u1;
    _Float16* c2b = (_Float16*)u2;
    _Float16* c3b = (_Float16*)u1;

    _Float16* w1p  = (_Float16*)wpk;
    _Float16* w2p  = w1p + 73728;
    _Float16* w3p  = w2p + 81920;
    _Float16* wpep = w3p + 73728;
    _Float16* wq0p = wpep + 393216;
    _Float16* wq1p = wq0p + 73728;
    _Float16* wm1p = wq1p + 73728;
    _Float16* wm2p = wm1p + 52224;

    pack_w<<<288, 256, 0, stream>>>(P[9],  w1p, 64, 9, 128);
    pack_w<<<320, 256, 0, stream>>>(P[15], w2p, 128, 5, 128);
    pack_w<<<288, 256, 0, stream>>>(P[21], w3p, 128, 3, 192);
    pack_pe<<<1536, 256, 0, stream>>>(P[27], wpep);
    pack_qk<<<288, 256, 0, stream>>>(P[29], wq0p);
    pack_qk<<<288, 256, 0, stream>>>(P[31], wq1p);
    pack_mlp1<<<204, 256, 0, stream>>>(P[33], wm1p);
    pack_mlp2<<<216, 256, 0, stream>>>(P[35], wm2p);
    pack_adjw<<<14592, 256, 0, stream>>>(P[1], wadjp);
    pad_x<<<3648, 256, 0, stream>>>(P[0], xpad);

    adj_mfma<<<256, 256, 0, stream>>>(xpad, wadjp, P[2], adjfull);

    for (int c = 0; c < 4; ++c) {
        const size_t b0 = (size_t)c * BcC;
        c0_tiled<<<BcC * 4, 256, 0, stream>>>(adjfull + b0 * 2048, P[3], P[4],
                                              P[5], P[6], P[7], P[8], c0b);
        conv_mfma<64, 9, 4, 128><<<BcC * 16, 256, 0, stream>>>(c0b, w1p, P[10],
                                                 P[11], P[12], P[13], P[14], c1b);
        conv_mfma<128, 5, 2, 128><<<BcC * 16, 256, 0, stream>>>(c1b, w2p, P[16],
                                                 P[17], P[18], P[19], P[20], c2b);
        conv_mfma<128, 3, 1, 192><<<BcC * 16, 256, 0, stream>>>(c2b, w3p, P[22],
                                                 P[23], P[24], P[25], P[26], c3b);
        pe_mfma<<<BcC * 2, 256, 0, stream>>>(c0b, c3b, wpep, P[28],
                                             pebh + b0 * 128 * 192);
    }
    transformer_mfma<<<512, 256, 0, stream>>>(pebh, wq0p, P[30], t1h);
    transformer_mfma<<<512, 256, 0, stream>>>(t1h, wq1p, P[32], t2h);
    mlp_mfma<<<1024, 256, 0, stream>>>(pebh, t2h, P[34], P[36],
                                       P[37], P[38], wm1p, wm2p, bsum);
    head2_kernel<<<512, 192, 0, stream>>>(bsum, P[39], P[40], (float*)d_out);
}